// Round 12
// baseline (1653.053 us; speedup 1.0000x reference)
//
#include <hip/hip_runtime.h>
#include <hip/hip_bf16.h>
#include <cstddef>

typedef __hip_bfloat16 bf16;
typedef unsigned short u16;
typedef unsigned int u32;
typedef short s16x8 __attribute__((ext_vector_type(8)));
typedef float f32x4 __attribute__((ext_vector_type(4)));

// ---------------- problem constants ----------------
#define BATCH 8
#define HR 128
#define WR 128
#define CCH 192
#define HW (HR*WR)            // 16384
#define MTOK (BATCH*HW)       // 131072
#define SPH 6
#define SPC 432               // spatial qkv channels (heads 0..5)
#define CHC 144               // channel-head qkv channels (heads 6,7)
#define NWIN 256
#define MIDC 48
#define PH 130                // padded conv H/W
#define PHW (PH*PH)           // 16900
#define LOGMAX 4.6051701859880914f

// ---------------- ws layout (BYTE offsets; peak ~193 MB) ----------------
static const size_t OFF_A0    = 0;
static const size_t OFF_B0    = 113246208;
static const size_t OFF_C0    = 150994944;
static const size_t OFF_SMALL = 188743680;
static const size_t SO_STATS  = 0;          // fp32 2*M
static const size_t SO_PGRAM  = 1048576;    // fp32 [8][2][16][576]
static const size_t SO_PSS    = 1638400;    // fp32 [8][2][16][48]
static const size_t SO_ATTNB  = 1687552;    // fp32 [8][2][24][24]
static const size_t SO_MEANSP = 1724416;
static const size_t SO_MEANCH = 1732608;
static const size_t SO_GATES  = 1740800;
static const size_t SO_GATEC  = 1748992;
static const size_t SO_BCSP   = 1757184;    // fp32 192
static const size_t SO_WCCH   = 1758208;    // fp32 192*48
static const size_t SO_BCCH   = 1795072;    // fp32 192
static const size_t SO_WFUSE  = 1796096;    // bf16 [8][192][48]
static const size_t SO_WCSPB  = 1943552;    // bf16 192*144
static const size_t SO_WQB    = 1998848;    // bf16 576*192
static const size_t SO_WS2C1B = 2220032;    // bf16 48*192
static const size_t SO_WC2S1B = 2238464;
static const size_t SO_WS2C2B = 2256896;    // bf16 192*48
static const size_t SO_WC2S2B = 2275328;
static const size_t SO_WF1B   = 2293760;    // bf16 192*384
static const size_t SO_WF2CB  = 2441216;    // bf16 192*1728
static const size_t SO_WSG1CB = 3104768;    // bf16 96*1728
static const size_t SO_WFC1B  = 3436544;    // bf16 768*192
static const size_t SO_WFC2B  = 3731456;    // bf16 192*768

__device__ __forceinline__ float b2f(bf16 x) { return __bfloat162float(x); }
__device__ __forceinline__ bf16  f2b(float x){ return __float2bfloat16(x); }
__device__ __forceinline__ u16   f2u(float x){
    bf16 h = __float2bfloat16(x);
    union { bf16 b; u16 u; } c; c.b = h; return c.u;
}
__device__ __forceinline__ float s2f(short s){
    union { u16 u; bf16 b; } c; c.u = (u16)s; return b2f(c.b);
}
__device__ __forceinline__ float u2f(u16 u){
    union { u16 u; bf16 b; } c; c.u = u; return b2f(c.b);
}
// bijective XCD-aware remap (m204 variant)
__device__ __forceinline__ int xcdswz(int b, int n){
    const int q = n >> 3, r = n & 7, x = b & 7, o = b >> 3;
    return (x < r) ? (x * (q + 1) + o) : (r * (q + 1) + (x - r) * q + o);
}
// direct global->LDS DMA, 16B per lane (dest = wave-uniform base + lane*16)
__device__ __forceinline__ void gload16(const void* g, u16* l) {
    __builtin_amdgcn_global_load_lds(
        (const __attribute__((address_space(1))) void*)g,
        (__attribute__((address_space(3))) void*)l, 16, 0, 0);
}

// =====================================================================
// MFMA bf16 GEMM: double-buffered LDS, staging via global_load_lds
// (linear [rows][32] layout; reg-staging only for LN-fused A and K-tails),
// LDS-staged vectorized epilogues in 64-row halves, XCD-swizzled M-blocks.
// block 256 thr = 4 waves (2x2), tile 128 x BNT, BK=32.
// AMODE: 0 plain bf16, 1 LN-fused (A fp32 + stats), 2 concat(A|A2 bf16),
//        3 implicit 3x3 conv over PADDED input, 4 V-extract from chqkv
// EPI: 0 bias, 1 relu, 2 roll-store, 3 BN+relu, 4 gated residual,
//      5 gelu, 6 residual add (fp32 ep0, CBF=0, N==BNT), 7 qkv split store
// =====================================================================
#define GBM 128
#define GBK 32
#define LDA 32   // linear LDS row length in ushorts (64 B) - gload_lds layout

struct SegRaw { union { uint4 v; struct { float4 lo, hi; } f; } d; };

template<int AMODE, int EPI, int CBF, int BNT, int CPAD, int WPB>
__global__ __launch_bounds__(256)
void gemm_k(const void* __restrict__ A, const u16* __restrict__ W,
            const float* __restrict__ bias, void* __restrict__ Cv,
            int M, int N, int K,
            const float* __restrict__ stats, const float* __restrict__ lng,
            const float* __restrict__ lnb, const void* __restrict__ A2,
            const float* __restrict__ ep0, const float* __restrict__ ep1,
            const float* __restrict__ ep2, const float* __restrict__ ep3)
{
    constexpr int NF = BNT / 32;
    constexpr int NB = (BNT * 4 + 255) / 256;
    constexpr int ATILE = GBM * LDA;      // u16 units (4096)
    constexpr int BTILE = BNT * LDA;
    constexpr int BUFSZ = ATILE + BTILE;
    constexpr int CST   = BNT + 8;        // padded bf16 C-staging stride (u16)
    constexpr int CSTG  = 64 * CST;
    constexpr int FSTG  = 32 * (BNT + 16) * 2;  // fp32 quarter, u16 units
    constexpr int SM1 = (2*BUFSZ > CSTG) ? 2*BUFSZ : CSTG;
    constexpr int SMEMSZ = (SM1 > FSTG) ? SM1 : FSTG;
    __shared__ __align__(16) u16 smem[SMEMSZ];

    const int tid  = threadIdx.x;
    const int lane = tid & 63;
    const int wid  = tid >> 6;
    const int wm   = (wid >> 1) * 64;
    const int wn   = (wid & 1) * (BNT / 2);
    const int m0   = xcdswz(blockIdx.y, gridDim.y) * GBM;
    const int n0   = blockIdx.x * BNT;
    const int row16 = lane & 15;
    const int hi    = lane >> 4;
    const int koff  = hi * 8;

    const int arow[2] = { tid >> 2, (tid + 256) >> 2 };
    const int akk     = (tid & 3) * 8;

    const u16* Wb = W;
    if constexpr (WPB) Wb = W + (size_t)(m0 >> 14) * 9216;

    float meanA[2], rstdA[2];
    if constexpr (AMODE == 1) {
        #pragma unroll
        for (int it = 0; it < 2; ++it) {
            const int m = m0 + arow[it];
            meanA[it] = stats[2*m]; rstdA[it] = stats[2*m+1];
        }
    }

    f32x4 acc[4][NF];
    #pragma unroll
    for (int mf = 0; mf < 4; ++mf)
        #pragma unroll
        for (int nf = 0; nf < NF; ++nf)
            acc[mf][nf] = (f32x4){0.f, 0.f, 0.f, 0.f};

    const int nsteps = (K + GBK - 1) / GBK;

    // ---- per-lane A global address for segment s at K-step ----
    auto aAddr = [&](int s, int k0) -> const void* {
        const int m = m0 + (s >> 2);
        const int k = k0 + (s & 3) * 8;
        if constexpr (AMODE == 0) {
            return (const u16*)A + (size_t)m * K + k;
        } else if constexpr (AMODE == 2) {
            return (k < CCH) ? (const void*)((const u16*)A  + (size_t)m * CCH + k)
                             : (const void*)((const u16*)A2 + (size_t)m * CCH + (k - CCH));
        } else if constexpr (AMODE == 3) {
            const int tap = k / CCH, c = k - tap * CCH;
            const int ky = tap / 3, kx = tap - ky * 3;
            const int b = m >> 14, pix = m & 16383;
            const int h = pix >> 7, w = pix & 127;
            return (const u16*)A + ((size_t)b * PHW + (size_t)(h + ky) * PH + (w + kx)) * CCH + c;
        } else { // AMODE 4
            const int col = (k < 24) ? (48 + k) : (96 + k);
            return (const u16*)A + (size_t)m * CHC + col;
        }
    };

    // ---- async staging (full steps only) ----
    auto gstageA = [&](int step, u16* Ab) {
        const int k0 = step * GBK;
        #pragma unroll
        for (int it = 0; it < 2; ++it) {
            const int s = tid + it * 256;
            gload16(aAddr(s, k0), &Ab[(it*256 + wid*64) * 8]);
        }
    };
    auto gstageB = [&](int step, u16* Bb) {
        const int k0 = step * GBK;
        #pragma unroll
        for (int it = 0; it < NB; ++it) {
            const int s = tid + it * 256;
            if (s < BNT*4) {
                int n = n0 + (s >> 2);
                if (n >= N) n = N - 1;   // clamp; results for n>=N discarded
                gload16(Wb + (size_t)n * K + (k0 + (s & 3) * 8),
                        &Bb[(it*256 + wid*64) * 8]);
            }
        }
    };

    // ---- reg staging (LN-fused A, and K-tail steps) ----
    auto loadA = [&](int step, SegRaw seg[2]) {
        const int k0 = step * GBK;
        #pragma unroll
        for (int it = 0; it < 2; ++it) {
            const int k = k0 + akk;
            SegRaw& s = seg[it];
            if (k >= K) { s.d.v = (uint4){0u,0u,0u,0u}; continue; }
            if constexpr (AMODE == 1) {
                const float* p = (const float*)A + (size_t)(m0 + arow[it]) * K + k;
                s.d.f.lo = *(const float4*)p; s.d.f.hi = *(const float4*)(p+4);
            } else {
                s.d.v = *(const uint4*)aAddr(it*256 + tid, k0);
            }
        }
    };
    auto writeA = [&](int step, SegRaw seg[2], u16* Ab) {
        const int k0 = step * GBK;
        #pragma unroll
        for (int it = 0; it < 2; ++it) {
            if constexpr (AMODE == 1) {
                const int k = k0 + akk;
                union { u16 u[8]; uint4 v; } pk;
                #pragma unroll
                for (int j = 0; j < 8; ++j) {
                    float xx = (j < 4) ? seg[it].d.f.lo[j] : seg[it].d.f.hi[j-4];
                    xx = (xx - meanA[it]) * rstdA[it] * lng[k+j] + lnb[k+j];
                    pk.u[j] = f2u(xx);
                }
                *(uint4*)&Ab[arow[it] * LDA + akk] = pk.v;
            } else {
                *(uint4*)&Ab[arow[it] * LDA + akk] = seg[it].d.v;
            }
        }
    };
    auto loadB = [&](int step, SegRaw seg[NB]) {
        const int k0 = step * GBK;
        #pragma unroll
        for (int it = 0; it < NB; ++it) {
            const int s = tid + it * 256;
            const int n = n0 + (s >> 2);
            const int k = k0 + (s & 3) * 8;
            seg[it].d.v = (uint4){0u,0u,0u,0u};
            if (s < BNT*4 && k < K && n < N)
                seg[it].d.v = *(const uint4*)(Wb + (size_t)n * K + k);
        }
    };
    auto writeB = [&](SegRaw seg[NB], u16* Bb) {
        #pragma unroll
        for (int it = 0; it < NB; ++it) {
            const int s = tid + it * 256;
            if (s < BNT*4)
                *(uint4*)&Bb[(s >> 2) * LDA + (s & 3) * 8] = seg[it].d.v;
        }
    };

    SegRaw segA[2], segB[NB];

    // ---- prologue: stage step 0 into buffer 0 ----
    {
        u16* Ab = smem; u16* Bb = smem + ATILE;
        const bool full0 = (GBK <= K);
        if constexpr (AMODE == 1) {
            loadA(0, segA); writeA(0, segA, Ab);
        } else {
            if (full0) gstageA(0, Ab);
            else { loadA(0, segA); writeA(0, segA, Ab); }
        }
        if (full0) gstageB(0, Bb);
        else { loadB(0, segB); writeB(segB, Bb); }
    }
    __syncthreads();

    int cur = 0;
    for (int step = 0; step < nsteps; ++step) {
        const bool more = (step + 1 < nsteps);
        u16* An = smem + (cur ^ 1) * BUFSZ;
        u16* Bn = An + ATILE;
        if (more) {
            const bool fullN = ((step + 1) * GBK + GBK <= K);
            if constexpr (AMODE == 1) {
                loadA(step + 1, segA);              // reg prefetch; write after MFMA
            } else {
                if (fullN) gstageA(step + 1, An);
                else { loadA(step + 1, segA); writeA(step + 1, segA, An); }
            }
            if (fullN) gstageB(step + 1, Bn);
            else { loadB(step + 1, segB); writeB(segB, Bn); }
        }
        u16* Ab = smem + cur * BUFSZ;
        u16* Bb = Ab + ATILE;
        s16x8 af[4], bfr[NF];
        #pragma unroll
        for (int mf = 0; mf < 4; ++mf)
            af[mf] = *(const s16x8*)&Ab[(wm + mf*16 + row16) * LDA + koff];
        #pragma unroll
        for (int nf = 0; nf < NF; ++nf)
            bfr[nf] = *(const s16x8*)&Bb[(wn + nf*16 + row16) * LDA + koff];
        __builtin_amdgcn_s_setprio(1);
        #pragma unroll
        for (int mf = 0; mf < 4; ++mf)
            #pragma unroll
            for (int nf = 0; nf < NF; ++nf)
                acc[mf][nf] = __builtin_amdgcn_mfma_f32_16x16x32_bf16(
                    af[mf], bfr[nf], acc[mf][nf], 0, 0, 0);
        __builtin_amdgcn_s_setprio(0);
        if (more) {
            if constexpr (AMODE == 1) writeA(step + 1, segA, An);
        }
        __syncthreads();
        cur ^= 1;
    }

    // ================= epilogue =================
    if constexpr (CBF == 1) {
        constexpr int CHUNKS = BNT / 8;
        #pragma unroll
        for (int hh = 0; hh < 2; ++hh) {
            __syncthreads();
            if ((wid >> 1) == hh) {
                #pragma unroll
                for (int mf = 0; mf < 4; ++mf) {
                    #pragma unroll
                    for (int nf = 0; nf < NF; ++nf) {
                        const int n = n0 + wn + nf*16 + row16;
                        #pragma unroll
                        for (int r = 0; r < 4; ++r) {
                            const int mloc = mf*16 + hi*4 + r;   // 0..63
                            float v = acc[mf][nf][r];
                            if (n < N) {
                                v += (bias ? bias[n] : 0.f);
                                if constexpr (EPI == 1) {
                                    v = fmaxf(v, 0.f);
                                } else if constexpr (EPI == 3) {
                                    v = (v - ep2[n]) * rsqrtf(ep3[n] + 1e-5f) * ep0[n] + ep1[n];
                                    v = fmaxf(v, 0.f);
                                } else if constexpr (EPI == 4) {
                                    const int b = (m0 + hh*64 + mloc) >> 14;
                                    v = v * ep0[b * N + n];
                                } else if constexpr (EPI == 5) {
                                    v = 0.5f * v * (1.f + erff(v * 0.70710678118654752f));
                                }
                            }
                            smem[mloc * CST + (wn + nf*16 + row16)] = f2u(v);
                        }
                    }
                }
            }
            __syncthreads();
            const int TOT = 64 * CHUNKS;
            for (int task = tid; task < TOT; task += 256) {
                const int rloc  = task / CHUNKS;
                const int chunk = task - rloc * CHUNKS;
                const int m  = m0 + hh*64 + rloc;
                const int nn = n0 + chunk * 8;
                if (nn >= N) continue;
                uint4 val = *(const uint4*)&smem[rloc * CST + chunk * 8];
                if constexpr (EPI == 7) {
                    if (nn < SPC) {
                        *(uint4*)((u16*)Cv + (size_t)m * SPC + nn) = val;
                    } else {
                        u16* chq = (u16*)ep0;
                        *(uint4*)(chq + (size_t)m * CHC + (nn - SPC)) = val;
                    }
                    continue;
                }
                size_t outIdx;
                if constexpr (CPAD == 1) {
                    const int b = m >> 14, pix = m & 16383;
                    const int h = pix >> 7, w = pix & 127;
                    outIdx = ((size_t)b * PHW + (size_t)(h+1) * PH + (w+1)) * (size_t)N + nn;
                } else if constexpr (EPI == 2) {
                    const int b = m >> 14, pix = m & 16383;
                    const int h2 = ((pix >> 7) + 4) & 127;
                    const int w2 = ((pix & 127) + 4) & 127;
                    outIdx = ((size_t)(b * HW) + h2 * WR + w2) * (size_t)N + nn;
                } else {
                    outIdx = (size_t)m * N + nn;
                }
                if constexpr (EPI == 4) {
                    union { uint4 v; u16 u[8]; } sv, ov;
                    sv.v = val;
                    ov.v = *(const uint4*)((const u16*)Cv + outIdx);
                    #pragma unroll
                    for (int j = 0; j < 8; ++j)
                        sv.u[j] = f2u(u2f(ov.u[j]) + u2f(sv.u[j]));
                    *(uint4*)((u16*)Cv + outIdx) = sv.v;
                } else {
                    *(uint4*)((u16*)Cv + outIdx) = val;
                }
            }
        }
    } else {
        // ---- fp32 path (fc2, EPI6, N==BNT): LDS-staged float4 stores ----
        float* fs = (float*)smem;
        constexpr int FST = BNT + 16;
        #pragma unroll
        for (int q = 0; q < 4; ++q) {
            __syncthreads();
            if ((wid >> 1) == (q >> 1)) {
                #pragma unroll
                for (int mfi = 0; mfi < 2; ++mfi) {
                    const int mf = (q & 1) * 2 + mfi;
                    #pragma unroll
                    for (int nf = 0; nf < NF; ++nf) {
                        const int n = wn + nf*16 + row16;
                        #pragma unroll
                        for (int r = 0; r < 4; ++r) {
                            const int mloc = mfi*16 + hi*4 + r;   // 0..31
                            fs[mloc * FST + n] = acc[mf][nf][r] + (bias ? bias[n0 + n] : 0.f);
                        }
                    }
                }
            }
            __syncthreads();
            const int TOT = 32 * (BNT/4);
            for (int task = tid; task < TOT; task += 256) {
                const int rloc = task / (BNT/4);
                const int cc = (task - rloc*(BNT/4)) * 4;
                const int m = m0 + q*32 + rloc;
                const int nn = n0 + cc;
                if (nn >= N) continue;
                float4 v4 = *(const float4*)&fs[rloc*FST + cc];
                const size_t oi = (size_t)m * N + nn;
                if constexpr (EPI == 6) {
                    const float4 o4 = *(const float4*)&ep0[oi];
                    v4.x += o4.x; v4.y += o4.y; v4.z += o4.z; v4.w += o4.w;
                }
                *(float4*)&((float*)Cv)[oi] = v4;
            }
        }
    }
}

// =====================================================================
// weight prep
// =====================================================================
__global__ __launch_bounds__(256)
void wprep_lin_k(const float* __restrict__ in, bf16* __restrict__ outb, int n)
{
    const int i = blockIdx.x * 256 + threadIdx.x;
    if (i < n) outb[i] = f2b(in[i]);
}

__global__ __launch_bounds__(256)
void wprep_conv_k(const float* __restrict__ in, bf16* __restrict__ outb, int total)
{
    const int i = blockIdx.x * 256 + threadIdx.x;
    if (i >= total) return;
    const int n = i / 1728, r = i - n * 1728;
    const int tap = r / CCH, c = r - tap * CCH;
    outb[i] = f2b(in[((size_t)n * CCH + c) * 9 + tap]);
}

__global__ __launch_bounds__(256)
void zb_k(bf16* __restrict__ buf)
{
    const int i = blockIdx.x * 256 + threadIdx.x;
    if (i >= 8 * 516 * 24) return;
    const int chunk = i % 24;
    const int p = (i / 24) % 516;
    const int b = i / (24 * 516);
    int h, w;
    if (p < 130)      { h = 0;   w = p; }
    else if (p < 260) { h = 129; w = p - 130; }
    else { const int q = p - 260; h = 1 + (q >> 1); w = (q & 1) ? 129 : 0; }
    *(uint4*)((u16*)buf + ((size_t)b * PHW + (size_t)h * PH + w) * CCH + chunk * 8)
        = (uint4){0u,0u,0u,0u};
}

__global__ __launch_bounds__(256)
void zerof_k(float* __restrict__ p, int n)
{
    const int i = blockIdx.x * 256 + threadIdx.x;
    if (i < n) p[i] = 0.f;
}

// =====================================================================
// LN stats
// =====================================================================
__global__ __launch_bounds__(256)
void ln_stats_k(const float* __restrict__ x, float* __restrict__ stats)
{
    const int tok = blockIdx.x * 4 + (threadIdx.x >> 6);
    const int lane = threadIdx.x & 63;
    const float* r = x + (size_t)tok * CCH;
    float s = 0.f, sq = 0.f;
    for (int c = lane; c < CCH; c += 64) { float v = r[c]; s += v; sq += v*v; }
    for (int m = 1; m < 64; m <<= 1) { s += __shfl_xor(s, m); sq += __shfl_xor(sq, m); }
    if (lane == 0) {
        const float mean = s / (float)CCH;
        const float var = sq / (float)CCH - mean * mean;
        stats[(size_t)tok*2]   = mean;
        stats[(size_t)tok*2+1] = rsqrtf(var + 1e-5f);
    }
}

// =====================================================================
// MFMA spatial shifted-window cosine attention (6 waves = 6 heads/window)
// =====================================================================
__global__ __launch_bounds__(384)
void sp_attn_k(const bf16* __restrict__ spqkv, const float* __restrict__ rpb,
               const float* __restrict__ logit_sp, bf16* __restrict__ osp)
{
    const int b    = blockIdx.x >> 8;
    const int win  = blockIdx.x & 255;
    const int wh = win >> 4, ww = win & 15;
    const int head = threadIdx.x >> 6;
    const int lane = threadIdx.x & 63;
    const int row16 = lane & 15;
    const int hi   = lane >> 4;
    const int koff = hi * 8;

    __shared__ float rpbS[1350];
    __shared__ u16 vT[SPH][32][72];

    for (int i = threadIdx.x; i < 1350; i += 384) rpbS[i] = rpb[i];

    const u16* base = (const u16*)spqkv + (size_t)b * HW * SPC;

    s16x8 qf[4], kf[4];
    const int wcol = (ww*8 + (row16 & 7) + 4) & 127;
    #pragma unroll
    for (int t = 0; t < 4; ++t) {
        const int pos = t*16 + row16;
        const int h = (wh*8 + (pos >> 3) + 4) & 127;
        const u16* rowp = base + ((size_t)(h * WR + wcol)) * SPC + head * 72;
        if (koff < 24) {
            qf[t] = *(const s16x8*)(rowp + koff);
            kf[t] = *(const s16x8*)(rowp + 24 + koff);
        } else {
            qf[t] = (s16x8){0,0,0,0,0,0,0,0};
            kf[t] = (s16x8){0,0,0,0,0,0,0,0};
        }
    }

    {
        const int h = (wh*8 + (lane >> 3) + 4) & 127;
        const int w = (ww*8 + (lane & 7) + 4) & 127;
        const u16* vrow = base + ((size_t)(h * WR + w)) * SPC + head * 72 + 48;
        union { uint4 v; u16 u[8]; } seg[3];
        seg[0].v = *(const uint4*)(vrow);
        seg[1].v = *(const uint4*)(vrow + 8);
        seg[2].v = *(const uint4*)(vrow + 16);
        #pragma unroll
        for (int d = 0; d < 24; ++d) vT[head][d][lane] = seg[d>>3].u[d&7];
        #pragma unroll
        for (int d = 24; d < 32; ++d) vT[head][d][lane] = 0;
    }
    __syncthreads();

    float rq[4], rk[4];
    #pragma unroll
    for (int t = 0; t < 4; ++t) {
        float sq = 0.f, sk = 0.f;
        #pragma unroll
        for (int e = 0; e < 8; ++e) {
            const float a = s2f(qf[t][e]); sq += a*a;
            const float c = s2f(kf[t][e]); sk += c*c;
        }
        sq += __shfl_xor(sq, 16); sq += __shfl_xor(sq, 32);
        sk += __shfl_xor(sk, 16); sk += __shfl_xor(sk, 32);
        rq[t] = 1.f / fmaxf(sqrtf(sq), 1e-12f);
        rk[t] = 1.f / fmaxf(sqrtf(sk), 1e-12f);
    }
    const float scale_h = __expf(fminf(logit_sp[head], LOGMAX));

    f32x4 acc[4][4];
    #pragma unroll
    for (int mfk = 0; mfk < 4; ++mfk)
        #pragma unroll
        for (int nfq = 0; nfq < 4; ++nfq)
            acc[mfk][nfq] = (f32x4){0.f,0.f,0.f,0.f};
    #pragma unroll
    for (int mfk = 0; mfk < 4; ++mfk)
        #pragma unroll
        for (int nfq = 0; nfq < 4; ++nfq)
            acc[mfk][nfq] = __builtin_amdgcn_mfma_f32_16x16x32_bf16(
                kf[mfk], qf[nfq], acc[mfk][nfq], 0, 0, 0);

    f32x4 rkj[4];
    #pragma unroll
    for (int mfk = 0; mfk < 4; ++mfk)
        #pragma unroll
        for (int r = 0; r < 4; ++r)
            rkj[mfk][r] = __shfl(rk[mfk], hi*4 + r);

    int ip3[4], iw7[4], labi[4];
    #pragma unroll
    for (int t = 0; t < 4; ++t) {
        const int pos = t*16 + row16;
        ip3[t] = pos >> 3; iw7[t] = pos & 7;
        const int hh = wh*8 + ip3[t], w0 = ww*8 + iw7[t];
        const int rh = hh < 120 ? 0 : (hh < 124 ? 1 : 2);
        const int rw = w0 < 120 ? 0 : (w0 < 124 ? 1 : 2);
        labi[t] = rh*3 + rw;
    }

    #pragma unroll
    for (int mfk = 0; mfk < 4; ++mfk) {
        #pragma unroll
        for (int r = 0; r < 4; ++r) {
            const int j = hi*4 + r + 16*mfk;
            const int jp3 = j >> 3, jw7 = j & 7;
            const int hh = wh*8 + jp3, w0 = ww*8 + jw7;
            const int rh = hh < 120 ? 0 : (hh < 124 ? 1 : 2);
            const int rw = w0 < 120 ? 0 : (w0 < 124 ? 1 : 2);
            const int labj = rh*3 + rw;
            const float rkv = rkj[mfk][r];
            #pragma unroll
            for (int nfq = 0; nfq < 4; ++nfq) {
                float s = acc[mfk][nfq][r] * rq[nfq] * rkv * scale_h;
                s += rpbS[((ip3[nfq]-jp3+7)*15 + (iw7[nfq]-jw7+7))*SPH + head];
                if (labi[nfq] != labj) s -= 100.f;
                acc[mfk][nfq][r] = s;
            }
        }
    }

    float inv[4];
    #pragma unroll
    for (int nfq = 0; nfq < 4; ++nfq) {
        float m = -1e30f;
        #pragma unroll
        for (int mfk = 0; mfk < 4; ++mfk)
            #pragma unroll
            for (int r = 0; r < 4; ++r)
                m = fmaxf(m, acc[mfk][nfq][r]);
        m = fmaxf(m, __shfl_xor(m, 16));
        m = fmaxf(m, __shfl_xor(m, 32));
        float s = 0.f;
        #pragma unroll
        for (int mfk = 0; mfk < 4; ++mfk)
            #pragma unroll
            for (int r = 0; r < 4; ++r) {
                const float p = __expf(acc[mfk][nfq][r] - m);
                acc[mfk][nfq][r] = p;
                s += p;
            }
        s += __shfl_xor(s, 16);
        s += __shfl_xor(s, 32);
        inv[nfq] = 1.f / s;
    }

    u32 pk01[4][4], pk23[4][4];
    #pragma unroll
    for (int mfk = 0; mfk < 4; ++mfk)
        #pragma unroll
        for (int nfq = 0; nfq < 4; ++nfq) {
            pk01[mfk][nfq] = (u32)f2u(acc[mfk][nfq][0] * inv[nfq])
                           | ((u32)f2u(acc[mfk][nfq][1] * inv[nfq]) << 16);
            pk23[mfk][nfq] = (u32)f2u(acc[mfk][nfq][2] * inv[nfq])
                           | ((u32)f2u(acc[mfk][nfq][3] * inv[nfq]) << 16);
        }

    s16x8 vf[2][2];
    #pragma unroll
    for (int nf = 0; nf < 2; ++nf)
        #pragma unroll
        for (int ks = 0; ks < 2; ++ks)
            vf[nf][ks] = *(const s16x8*)&vT[head][row16 + 16*nf][32*ks + koff];

    f32x4 accO[4][2];
    #pragma unroll
    for (int MF = 0; MF < 4; ++MF)
        #pragma unroll
        for (int nf = 0; nf < 2; ++nf)
            accO[MF][nf] = (f32x4){0.f,0.f,0.f,0.f};

    const int g0 = 2*(hi & 1);
    const int src0 = g0*16 + row16, src1 = src0 + 16;
    const bool selhi = (hi >> 1) != 0;
    #pragma unroll
    for (int ks = 0; ks < 2; ++ks) {
        #pragma unroll
        for (int MF = 0; MF < 4; ++MF) {
            const u32 e01a = __shfl(pk01[2*ks][MF],   src0);
            const u32 e01b = __shfl(pk01[2*ks+1][MF], src0);
            const u32 e23a = __shfl(pk23[2*ks][MF],   src0);
            const u32 e23b = __shfl(pk23[2*ks+1][MF], src0);
            const u32 e45a = __shfl(pk01[2*ks][MF],   src1);
            const u32 e45b = __shfl(pk01[2*ks+1][MF], src1);
            const u32 e67a = __shfl(pk23[2*ks][MF],   src1);
            const u32 e67b = __shfl(pk23[2*ks+1][MF], src1);
            union { u32 w[4]; s16x8 v; } af;
            af.w[0] = selhi ? e01b : e01a;
            af.w[1] = selhi ? e23b : e23a;
            af.w[2] = selhi ? e45b : e45a;
            af.w[3] = selhi ? e67b : e67a;
            accO[MF][0] = __builtin_amdgcn_mfma_f32_16x16x32_bf16(
                af.v, vf[0][ks], accO[MF][0], 0, 0, 0);
            accO[MF][1] = __builtin_amdgcn_mfma_f32_16x16x32_bf16(
                af.v, vf[1][ks], accO[MF][1], 0, 0, 0);
        }
    }

    #pragma unroll
    for (int MF = 0; MF < 4; ++MF) {
        #pragma unroll
        for (int nf = 0; nf < 2; ++nf) {
            const int d = row16 + 16*nf;
            if (d >= 24) continue;
            #pragma unroll
            for (int r = 0; r < 4; ++r) {
                const int qrow = hi*4 + r + 16*MF;
                const int h = wh*8 + (qrow >> 3);
                const int w = ww*8 + (qrow & 7);
                osp[((size_t)b*HW + h*WR + w)*144 + head*24 + d] = f2b(accO[MF][nf][r]);
            }
        }
    }
}

// =====================================================================
// Channel attention: partial gram + column sum-squares, softmax, W-fuse
// =====================================================================
__global__ __launch_bounds__(256)
void ch_part_k(const bf16* __restrict__ chqkv, float* __restrict__ pgram,
               float* __restrict__ pss)
{
    const int ci = blockIdx.x, head = blockIdx.y, b = blockIdx.z;
    const int tid = threadIdx.x;
    __shared__ u16 tile[256][48];
    float g[3] = {0.f, 0.f, 0.f};
    float ss = 0.f;
    const u16* src = (const u16*)chqkv + (size_t)b * HW * CHC + head * 72;
    const int rbase = ci * 1024;

    for (int t0 = 0; t0 < 1024; t0 += 256) {
        __syncthreads();
        for (int idx = tid; idx < 256*6; idx += 256) {
            const int row = idx / 6, seg = idx - (idx/6)*6;
            *(uint4*)&tile[row][seg*8] =
                *(const uint4*)(src + (size_t)(rbase + t0 + row) * CHC + seg*8);
        }
        __syncthreads();
        #pragma unroll
        for (int i = 0; i < 3; ++i) {
            const int e = tid + i*256;
            if (e < 576) {
                const int c = e / 24, d = e - (e/24)*24;
                float s = 0.f;
                for (int r = 0; r < 256; ++r)
                    s += b2f(*(const bf16*)&tile[r][c]) * b2f(*(const bf16*)&tile[r][24+d]);
                g[i] += s;
            }
        }
        if (tid < 48) {
            float s = 0.f;
            for (int r = 0; r < 256; ++r) { const float v = b2f(*(const bf16*)&tile[r][tid]); s += v*v; }
            ss += s;
        }
    }
    float* pg = pgram + ((size_t)(b*2+head)*16 + ci) * 576;
    #pragma unroll
    for (int i = 0; i < 3; ++i) { const int e = tid + i*256; if (e < 576) pg[e] = g[i]; }
    if (tid < 48) pss[((size_t)(b*2+head)*16 + ci) * 48 + tid] = ss;
}

__global__ __launch_bounds__(256)
void ch_soft_k(const float* __restrict__ pgram, const float* __restrict__ pss,
               const float* __restrict__ logit_ch, float* __restrict__ attn)
{
    const int head = blockIdx.x, b = blockIdx.y;
    const int tid = threadIdx.x;
    __shared__ float gs[576], rn[48];
    for (int e = tid; e < 576; e += 256) {
        float s = 0.f;
        const float* pg = pgram + (size_t)(b*2+head)*16*576 + e;
        for (int c = 0; c < 16; ++c) s += pg[c*576];
        gs[e] = s;
    }
    if (tid < 48) {
        float s = 0.f;
        const float* ps = pss + (size_t)(b*2+head)*16*48 + tid;
        for (int c = 0; c < 16; ++c) s += ps[c*48];
        rn[tid] = 1.f / fmaxf(sqrtf(s), 1e-12f);
    }
    __syncthreads();
    if (tid < 24) {
        const float scale = expf(fminf(logit_ch[head], LOGMAX));
        float vals[24], mx = -1e30f;
        #pragma unroll
        for (int d = 0; d < 24; ++d) {
            vals[d] = gs[tid*24+d] * rn[tid] * rn[24+d] * scale;
            mx = fmaxf(mx, vals[d]);
        }
        float sum = 0.f;
        #pragma unroll
        for (int d = 0; d < 24; ++d) { vals[d] = expf(vals[d]-mx); sum += vals[d]; }
        const float inv = 1.f / sum;
        float* o = attn + ((size_t)(b*2+head)*24 + tid)*24;
        #pragma unroll
        for (int d = 0; d < 24; ++d) o[d] = vals[d]*inv;
    }
}

__global__ __launch_bounds__(192)
void fuse_chw_k(const float* __restrict__ Wc, const float* __restrict__ attn,
                bf16* __restrict__ Wf)
{
    const int b = blockIdx.x;
    const int n = threadIdx.x;
    __shared__ float As_[2][24][24];
    for (int e = n; e < 1152; e += 192) {
        const int h = e / 576, r = e - h*576;
        As_[h][r/24][r%24] = attn[(size_t)b*1152 + e];
    }
    __syncthreads();
    const float* wr = Wc + n*48;
    bf16* o = Wf + ((size_t)b*192 + n) * 48;
    for (int h = 0; h < 2; ++h)
        for (int d = 0; d < 24; ++d) {
            float s = 0.f;
            #pragma unroll
            for (int cc = 0; cc < 24; ++cc) s += wr[h*24+cc] * As_[h][cc][d];
            o[h*24+d] = f2b(s);
        }
}

// =====================================================================
// weight combiners
// =====================================================================
__global__ void combine_sp_k(const float* __restrict__ w_sp_proj, const float* __restrict__ w_spp,
                             const float* __restrict__ b_spp, bf16* __restrict__ Wc, float* __restrict__ bc)
{
    const int n = blockIdx.x;
    for (int i = threadIdx.x; i < 144; i += blockDim.x) {
        float s = 0.f;
        for (int j = 0; j < 144; ++j) s += w_sp_proj[n*144 + j] * w_spp[j*144 + i];
        Wc[n*144 + i] = f2b(s);
    }
    if (threadIdx.x == 0) {
        float s = 0.f;
        for (int j = 0; j < 144; ++j) s += w_sp_proj[n*144 + j] * b_spp[j];
        bc[n] = s;
    }
}

__global__ void combine_ch_k(const float* __restrict__ w_ch_proj, const float* __restrict__ w_chp,
                             const float* __restrict__ b_chp, float* __restrict__ Wc, float* __restrict__ bc)
{
    const int n = blockIdx.x;
    for (int c = threadIdx.x; c < 48; c += blockDim.x) {
        float s = 0.f;
        for (int j = 0; j < 48; ++j) s += w_ch_proj[n*48 + j] * w_chp[j*48 + c];
        Wc[n*48 + c] = s;
    }
    if (threadIdx.x == 0) {
        float s = 0.f;
        for (int j = 0; j < 48; ++j) s += w_ch_proj[n*48 + j] * b_chp[j];
        bc[n] = s;
    }
}

// =====================================================================
// coalesced per-(b,c) SUM over H,W (bf16 src), atomic accumulate
// =====================================================================
__global__ __launch_bounds__(256)
void mean2_k(const bf16* __restrict__ src, float* __restrict__ dst)
{
    const int b = blockIdx.y;
    const int r0 = blockIdx.x * 256;
    const int t = threadIdx.x;
    const int chunk = t & 31;
    const int rg = t >> 5;
    float acc[8] = {0.f,0.f,0.f,0.f,0.f,0.f,0.f,0.f};
    if (chunk < 24) {
        for (int r = rg; r < 256; r += 8) {
            const u16* p = (const u16*)src + ((size_t)(b*HW) + r0 + r) * CCH + chunk*8;
            union { uint4 v; u16 u[8]; } s; s.v = *(const uint4*)p;
            #pragma unroll
            for (int j = 0; j < 8; ++j) acc[j] += u2f(s.u[j]);
        }
    }
    __shared__ float red[8][24][8];
    if (chunk < 24) {
        #pragma unroll
        for (int j = 0; j < 8; ++j) red[rg][chunk][j] = acc[j];
    }
    __syncthreads();
    if (t < 192) {
        const int ch = t >> 3, j = t & 7;
        float s = 0.f;
        #pragma unroll
        for (int g = 0; g < 8; ++g) s += red[g][ch][j];
        atomicAdd(&dst[b*CCH + ch*8 + j], s);
    }
}

// gate = sigmoid(relu((sum/HW) @ w1^T) @ w2^T + b2)
__global__ __launch_bounds__(192)
void gates_k(const float* __restrict__ sumv, const float* __restrict__ w1,
             const float* __restrict__ w2, const float* __restrict__ b2,
             float* __restrict__ gate)
{
    const int b = blockIdx.x;
    __shared__ float mv[192], hid[48];
    const int t = threadIdx.x;
    mv[t] = sumv[b*CCH + t] * (1.f / (float)HW);
    __syncthreads();
    if (t < 48) {
        float s = 0.f;
        for (int c = 0; c < 192; ++c) s += w1[t*192 + c] * mv[c];
        hid[t] = fmaxf(s, 0.f);
    }
    __syncthreads();
    float s = b2[t];
    for (int j = 0; j < 48; ++j) s += hid[j] * w2[t*48 + j];
    gate[b*CCH + t] = 1.f / (1.f + expf(-s));
}

// =====================================================================
// out = x + f2(padded) * (1 + sigmoid(relu(gpre)@w_sg2 + b))
// =====================================================================
__global__ __launch_bounds__(256)
void fuse_k(const float* __restrict__ x, const bf16* __restrict__ f2pad,
            const bf16* __restrict__ gpre, const float* __restrict__ w_sg2,
            const float* __restrict__ b_sg2, float* __restrict__ out)
{
    const int pix = blockIdx.x * 4 + (threadIdx.x >> 6);
    const int lane = threadIdx.x & 63;
    const bf16* gp = gpre + (size_t)pix * 96;
    float s = fmaxf(b2f(gp[lane]), 0.f) * w_sg2[lane];
    if (lane < 32) s += fmaxf(b2f(gp[lane + 64]), 0.f) * w_sg2[lane + 64];
    for (int m = 1; m < 64; m <<= 1) s += __shfl_xor(s, m);
    const float g1 = 1.f + 1.f / (1.f + expf(-(s + b_sg2[0])));
    const int b = pix >> 14, p = pix & 16383;
    const int h = p >> 7, w = p & 127;
    const bf16* fr = f2pad + ((size_t)b * PHW + (size_t)(h+1) * PH + (w+1)) * CCH;
    const float* xr = x + (size_t)pix * CCH;
    float* orow = out + (size_t)pix * CCH;
    for (int c = lane; c < CCH; c += 64) orow[c] = xr[c] + b2f(fr[c]) * g1;
}

// =====================================================================
// launcher
// =====================================================================
extern "C" void kernel_launch(void* const* d_in, const int* in_sizes, int n_in,
                              void* d_out, int out_size, void* d_ws, size_t ws_size,
                              hipStream_t stream)
{
    const float* x        = (const float*)d_in[0];
    const float* ln1_g    = (const float*)d_in[1];
    const float* ln1_b    = (const float*)d_in[2];
    const float* w_qkv    = (const float*)d_in[3];
    const float* b_qkv    = (const float*)d_in[4];
    const float* logit_sp = (const float*)d_in[5];
    const float* rpb      = (const float*)d_in[6];
    const float* w_spp    = (const float*)d_in[7];
    const float* b_spp    = (const float*)d_in[8];
    const float* logit_ch = (const float*)d_in[9];
    const float* w_chp    = (const float*)d_in[10];
    const float* b_chp    = (const float*)d_in[11];
    const float* w_sp_proj= (const float*)d_in[12];
    const float* w_ch_proj= (const float*)d_in[13];
    const float* w_s2c1   = (const float*)d_in[14];
    const float* w_s2c2   = (const float*)d_in[15];
    const float* b_s2c2   = (const float*)d_in[16];
    const float* w_c2s1   = (const float*)d_in[17];
    const float* w_c2s2   = (const float*)d_in[18];
    const float* b_c2s2   = (const float*)d_in[19];
    const float* w_gs1    = (const float*)d_in[20];
    const float* w_gs2    = (const float*)d_in[21];
    const float* b_gs2    = (const float*)d_in[22];
    const float* w_gc1    = (const float*)d_in[23];
    const float* w_gc2    = (const float*)d_in[24];
    const float* b_gc2    = (const float*)d_in[25];
    const float* w_f1     = (const float*)d_in[26];
    const float* bn1_g    = (const float*)d_in[27];
    const float* bn1_b    = (const float*)d_in[28];
    const float* bn1_m    = (const float*)d_in[29];
    const float* bn1_v    = (const float*)d_in[30];
    const float* w_f2     = (const float*)d_in[31];
    const float* bn2_g    = (const float*)d_in[32];
    const float* bn2_b    = (const float*)d_in[33];
    const float* bn2_m    = (const float*)d_in[34];
    const float* bn2_v    = (const float*)d_in[35];
    const float* w_sg1    = (const float*)d_in[36];
    const float* w_sg2    = (const float*)d_in[37];
    const float* b_sg2    = (const float*)d_in[38];
    const float* ln2_g    = (const float*)d_in[39];
    const float* ln2_b    = (const float*)d_in[40];
    const float* w_fc1    = (const float*)d_in[41];
    const float* b_fc1    = (const float*)d_in[42];
    const float* w_fc2    = (const float*)d_in[43];
    const float* b_fc2    = (const float*)d_in[44];

    char* wsb = (char*)d_ws;
    char* sm  = wsb + OFF_SMALL;
    float* out = (float*)d_out;

    bf16*  spqkv  = (bf16*)(wsb + OFF_A0);
    bf16*  sp_out = (bf16*)(wsb + OFF_A0);
    bf16*  ch_out = (bf16*)(wsb + OFF_A0 + 50331648);
    bf16*  f2pad  = (bf16*)(wsb + OFF_A0);
    bf16*  gpre   = (bf16*)(wsb + OFF_A0 + 51916800);
    bf16*  chqkv  = (bf16*)(wsb + OFF_B0);
    bf16*  hid_s  = (bf16*)(wsb + OFF_B0);
    bf16*  hid_c  = (bf16*)(wsb + OFF_B0 + 12582912);
    bf16*  fpad   = (bf16*)(wsb + OFF_B0);
    bf16*  hidden = (bf16*)(wsb + OFF_A0);   // fc1 out: A0 dead after fuse_k
    bf16*  osp    = (bf16*)(wsb + OFF_C0);

    float* stats  = (float*)(sm + SO_STATS);
    float* pgram  = (float*)(sm + SO_PGRAM);
    float* pss    = (float*)(sm + SO_PSS);
    float* attn_b = (float*)(sm + SO_ATTNB);
    float* mean_sp= (float*)(sm + SO_MEANSP);
    float* mean_ch= (float*)(sm + SO_MEANCH);
    float* gate_s = (float*)(sm + SO_GATES);
    float* gate_c = (float*)(sm + SO_GATEC);
    float* bc_sp  = (float*)(sm + SO_BCSP);
    float* Wc_ch  = (float*)(sm + SO_WCCH);
    float* bc_ch  = (float*)(sm + SO_BCCH);
    bf16*  Wfuse  = (bf16*)(sm + SO_WFUSE);
    bf16*  Wc_spB = (bf16*)(sm + SO_WCSPB);
    u16*   wqB    = (u16*)(sm + SO_WQB);
    u16*   ws2c1B = (u16*)(sm + SO_WS2C1B);
    u16*   wc2s1B = (u16*)(sm + SO_WC2S1B);
    u16*   ws2c2B = (u16*)(sm + SO_WS2C2B);
    u16*   wc2s2B = (u16*)(sm + SO_WC2S2B);
    u16*   wf1B   = (u16*)(sm + SO_WF1B);
    u16*   wf2cB  = (u16*)(sm + SO_WF2CB);
    u16*   wsg1cB = (u16*)(sm + SO_WSG1CB);
    u16*   wfc1B  = (u16*)(sm + SO_WFC1B);
    u16*   wfc2B  = (u16*)(sm + SO_WFC2B);

    const dim3 blk(256);

    // ---- weight prep ----
    wprep_lin_k<<<(110592+255)/256, blk, 0, stream>>>(w_qkv,  (bf16*)wqB,    110592);
    wprep_lin_k<<<(9216+255)/256,   blk, 0, stream>>>(w_s2c1, (bf16*)ws2c1B, 9216);
    wprep_lin_k<<<(9216+255)/256,   blk, 0, stream>>>(w_c2s1, (bf16*)wc2s1B, 9216);
    wprep_lin_k<<<(9216+255)/256,   blk, 0, stream>>>(w_s2c2, (bf16*)ws2c2B, 9216);
    wprep_lin_k<<<(9216+255)/256,   blk, 0, stream>>>(w_c2s2, (bf16*)wc2s2B, 9216);
    wprep_lin_k<<<(73728+255)/256,  blk, 0, stream>>>(w_f1,   (bf16*)wf1B,   73728);
    wprep_lin_k<<<(147456+255)/256, blk, 0, stream>>>(w_fc1,  (bf16*)wfc1B,  147456);
    wprep_lin_k<<<(147456+255)/256, blk, 0, stream>>>(w_fc2,  (bf16*)wfc2B,  147456);
    wprep_conv_k<<<(331776+255)/256, blk, 0, stream>>>(w_f2,  (bf16*)wf2cB,  331776);
    wprep_conv_k<<<(165888+255)/256, blk, 0, stream>>>(w_sg1, (bf16*)wsg1cB, 165888);
    combine_sp_k<<<192, 128, 0, stream>>>(w_sp_proj, w_spp, b_spp, Wc_spB, bc_sp);
    combine_ch_k<<<192, 64, 0, stream>>>(w_ch_proj, w_chp, b_chp, Wc_ch, bc_ch);
    zerof_k<<<6, blk, 0, stream>>>(mean_sp, 1536);
    zerof_k<<<6, blk, 0, stream>>>(mean_ch, 1536);

    // ---- LN1 stats + full-M qkv GEMM (split store) ----
    ln_stats_k<<<MTOK/4, blk, 0, stream>>>(x, stats);
    gemm_k<1,7,1,192,0,0><<<dim3(3, MTOK/GBM), blk, 0, stream>>>(
        x, wqB, b_qkv, spqkv, MTOK, 576, CCH,
        stats, ln1_g, ln1_b, nullptr,
        (const float*)chqkv, nullptr, nullptr, nullptr);

    // ---- MFMA spatial attention + sp proj (roll store) ----
    sp_attn_k<<<dim3(BATCH*NWIN), dim3(384), 0, stream>>>(spqkv, rpb, logit_sp, osp);
    gemm_k<0,2,1,192,0,0><<<dim3(1, MTOK/GBM), blk, 0, stream>>>(
        osp, (const u16*)Wc_spB, bc_sp, sp_out, MTOK, CCH, 144,
        nullptr, nullptr, nullptr, nullptr,
        nullptr, nullptr, nullptr, nullptr);

    // ---- channel attention: partial gram -> softmax -> fused W -> GEMM ----
    ch_part_k<<<dim3(16, 2, BATCH), blk, 0, stream>>>(chqkv, pgram, pss);
    ch_soft_k<<<dim3(2, BATCH), blk, 0, stream>>>(pgram, pss, logit_ch, attn_b);
    fuse_chw_k<<<BATCH, 192, 0, stream>>>(Wc_ch, attn_b, Wfuse);
    gemm_k<4,0,1,192,0,1><<<dim3(1, MTOK/GBM), blk, 0, stream>>>(
        chqkv, (const u16*)Wfuse, bc_ch, ch_out, MTOK, CCH, 48,
        nullptr, nullptr, nullptr, nullptr,
        nullptr, nullptr, nullptr, nullptr);

    // ---- CFCA means/gates ----
    mean2_k<<<dim3(HW/256, BATCH), blk, 0, stream>>>(sp_out, mean_sp);
    mean2_k<<<dim3(HW/256, BATCH), blk, 0, stream>>>(ch_out, mean_ch);
    gates_k<<<BATCH, 192, 0, stream>>>(mean_sp, w_gs1, w_gs2, b_gs2, gate_s);
    gates_k<<<BATCH, 192, 0, stream>>>(mean_ch, w_gc1, w_gc2, b_gc2, gate_c);

    // ---- CFCA hiddens + gated residual adds ----
    gemm_k<0,1,1,96,0,0><<<dim3(1, MTOK/GBM), blk, 0, stream>>>(
        sp_out, ws2c1B, nullptr, hid_s, MTOK, MIDC, CCH,
        nullptr, nullptr, nullptr, nullptr, nullptr, nullptr, nullptr, nullptr);
    gemm_k<0,1,1,96,0,0><<<dim3(1, MTOK/GBM), blk, 0, stream>>>(
        ch_out, wc2s1B, nullptr, hid_c, MTOK, MIDC, CCH,
        nullptr, nullptr, nullptr, nullptr, nullptr, nullptr, nullptr, nullptr);
    gemm_k<0,4,1,192,0,0><<<dim3(1, MTOK/GBM), blk, 0, stream>>>(
        hid_s, ws2c2B, b_s2c2, ch_out, MTOK, CCH, MIDC,
        nullptr, nullptr, nullptr, nullptr, gate_s, nullptr, nullptr, nullptr);
    gemm_k<0,4,1,192,0,0><<<dim3(1, MTOK/GBM), blk, 0, stream>>>(
        hid_c, wc2s2B, b_c2s2, sp_out, MTOK, CCH, MIDC,
        nullptr, nullptr, nullptr, nullptr, gate_c, nullptr, nullptr, nullptr);

    // ---- f = relu(bn1(concat @ w_f1^T)) -> PADDED fpad ----
    zb_k<<<(8*516*24+255)/256, blk, 0, stream>>>(fpad);
    gemm_k<2,3,1,192,1,0><<<dim3(1, MTOK/GBM), blk, 0, stream>>>(
        sp_out, wf1B, nullptr, fpad, MTOK, CCH, 2*CCH,
        nullptr, nullptr, nullptr, ch_out, bn1_g, bn1_b, bn1_m, bn1_v);

    // ---- f2 = relu(bn2(conv3x3(f))) -> PADDED f2pad ----
    zb_k<<<(8*516*24+255)/256, blk, 0, stream>>>(f2pad);
    gemm_k<3,3,1,192,1,0><<<dim3(1, MTOK/GBM), blk, 0, stream>>>(
        fpad, wf2cB, nullptr, f2pad, MTOK, CCH, 9*CCH,
        nullptr, nullptr, nullptr, nullptr, bn2_g, bn2_b, bn2_m, bn2_v);

    // ---- gpre = conv3x3(f2) (96 ch) ----
    gemm_k<3,0,1,96,0,0><<<dim3(1, MTOK/GBM), blk, 0, stream>>>(
        f2pad, wsg1cB, nullptr, gpre, MTOK, 96, 9*CCH,
        nullptr, nullptr, nullptr, nullptr, nullptr, nullptr, nullptr, nullptr);

    // ---- xnew = x + f2*(1+g) -> d_out ----
    fuse_k<<<MTOK/4, blk, 0, stream>>>(x, f2pad, gpre, w_sg2, b_sg2, out);

    // ---- LN2 + MLP (2 chunks; hidden over dead A0 region) ----
    ln_stats_k<<<MTOK/4, blk, 0, stream>>>(out, stats);
    const int CHM = MTOK / 2;
    for (int c0 = 0; c0 < MTOK; c0 += CHM) {
        gemm_k<1,5,1,192,0,0><<<dim3(4, CHM/GBM), blk, 0, stream>>>(
            out + (size_t)c0*CCH, wfc1B, b_fc1, hidden, CHM, 4*CCH, CCH,
            stats + (size_t)c0*2, ln2_g, ln2_b, nullptr,
            nullptr, nullptr, nullptr, nullptr);
        gemm_k<0,6,0,192,0,0><<<dim3(1, CHM/GBM), blk, 0, stream>>>(
            hidden, wfc2B, b_fc2, out + (size_t)c0*CCH, CHM, CCH, 4*CCH,
            nullptr, nullptr, nullptr, nullptr, out + (size_t)c0*CCH,
            nullptr, nullptr, nullptr);
    }
}

// Round 13
// 1335.817 us; speedup vs baseline: 1.2375x; 1.2375x over previous
//
#include <hip/hip_runtime.h>
#include <hip/hip_bf16.h>
#include <cstddef>

typedef __hip_bfloat16 bf16;
typedef unsigned short u16;
typedef unsigned int u32;
typedef short s16x8 __attribute__((ext_vector_type(8)));
typedef float f32x4 __attribute__((ext_vector_type(4)));

// ---------------- problem constants ----------------
#define BATCH 8
#define HR 128
#define WR 128
#define CCH 192
#define HW (HR*WR)            // 16384
#define MTOK (BATCH*HW)       // 131072
#define SPH 6
#define SPC 432               // spatial qkv channels (heads 0..5)
#define CHC 144               // channel-head qkv channels (heads 6,7)
#define NWIN 256
#define MIDC 48
#define PH 130                // padded conv H/W
#define PHW (PH*PH)           // 16900
#define LOGMAX 4.6051701859880914f

// ---------------- ws layout (BYTE offsets; peak ~193 MB) ----------------
static const size_t OFF_A0    = 0;
static const size_t OFF_B0    = 113246208;
static const size_t OFF_C0    = 150994944;
static const size_t OFF_SMALL = 188743680;
static const size_t SO_STATS  = 0;          // fp32 2*M
static const size_t SO_PGRAM  = 1048576;    // fp32 [8][2][16][576]
static const size_t SO_PSS    = 1638400;    // fp32 [8][2][16][48]
static const size_t SO_ATTNB  = 1687552;    // fp32 [8][2][24][24]
static const size_t SO_MEANSP = 1724416;
static const size_t SO_MEANCH = 1732608;
static const size_t SO_GATES  = 1740800;
static const size_t SO_GATEC  = 1748992;
static const size_t SO_BCSP   = 1757184;    // fp32 192
static const size_t SO_WCCH   = 1758208;    // fp32 192*48
static const size_t SO_BCCH   = 1795072;    // fp32 192
static const size_t SO_WFUSE  = 1796096;    // bf16 [8][192][48]
static const size_t SO_WCSPB  = 1943552;    // bf16 192*144
static const size_t SO_WQB    = 1998848;    // bf16 576*192
static const size_t SO_WS2C1B = 2220032;    // bf16 48*192
static const size_t SO_WC2S1B = 2238464;
static const size_t SO_WS2C2B = 2256896;    // bf16 192*48
static const size_t SO_WC2S2B = 2275328;
static const size_t SO_WF1B   = 2293760;    // bf16 192*384
static const size_t SO_WF2CB  = 2441216;    // bf16 192*1728
static const size_t SO_WSG1CB = 3104768;    // bf16 96*1728
static const size_t SO_WFC1B  = 3436544;    // bf16 768*192
static const size_t SO_WFC2B  = 3731456;    // bf16 192*768

__device__ __forceinline__ float b2f(bf16 x) { return __bfloat162float(x); }
__device__ __forceinline__ bf16  f2b(float x){ return __float2bfloat16(x); }
__device__ __forceinline__ u16   f2u(float x){
    bf16 h = __float2bfloat16(x);
    union { bf16 b; u16 u; } c; c.b = h; return c.u;
}
__device__ __forceinline__ float s2f(short s){
    union { u16 u; bf16 b; } c; c.u = (u16)s; return b2f(c.b);
}
__device__ __forceinline__ float u2f(u16 u){
    union { u16 u; bf16 b; } c; c.u = u; return b2f(c.b);
}
// bijective XCD-aware remap (m204 variant)
__device__ __forceinline__ int xcdswz(int b, int n){
    const int q = n >> 3, r = n & 7, x = b & 7, o = b >> 3;
    return (x < r) ? (x * (q + 1) + o) : (r * (q + 1) + (x - r) * q + o);
}

// =====================================================================
// MFMA bf16 GEMM: double-buffered LDS (1 barrier/K-step), register
// prefetch, LDS-staged vectorized epilogues, XCD-swizzled M-blocks.
// block 256 thr = 4 waves (2x2), tile 128 x BNT, BK=32.
// LDA=40 (80B row stride) -> fragment ds_read_b128 hits all 8 bank-groups.
// AMODE: 0 plain bf16, 1 LN-fused (A fp32 + stats), 2 concat(A|A2 bf16),
//        3 implicit 3x3 conv over PADDED input, 4 V-extract from chqkv
// EPI: 0 bias, 1 relu, 2 roll-store, 3 BN+relu, 4 gated residual,
//      5 gelu, 6 residual add (fp32 ep0, CBF=0, N==BNT), 7 qkv split store
// =====================================================================
#define GBM 128
#define GBK 32
#define LDA 40   // padded LDS row length in ushorts (80 B)

struct SegRaw { union { uint4 v; struct { float4 lo, hi; } f; } d; };

template<int AMODE, int EPI, int CBF, int BNT, int CPAD, int WPB>
__global__ __launch_bounds__(256)
void gemm_k(const void* __restrict__ A, const u16* __restrict__ W,
            const float* __restrict__ bias, void* __restrict__ Cv,
            int M, int N, int K,
            const float* __restrict__ stats, const float* __restrict__ lng,
            const float* __restrict__ lnb, const void* __restrict__ A2,
            const float* __restrict__ ep0, const float* __restrict__ ep1,
            const float* __restrict__ ep2, const float* __restrict__ ep3)
{
    constexpr int NF = BNT / 32;
    constexpr int NB = (BNT * 4 + 255) / 256;
    constexpr int ATILE = GBM * LDA;      // u16 units
    constexpr int BTILE = BNT * LDA;
    constexpr int BUFSZ = ATILE + BTILE;
    constexpr int CST   = BNT + 8;        // padded bf16 C-staging stride (u16)
    __shared__ __align__(16) u16 smem[2 * BUFSZ];  // reused for C staging

    const int tid  = threadIdx.x;
    const int lane = tid & 63;
    const int wid  = tid >> 6;
    const int wm   = (wid >> 1) * 64;
    const int wn   = (wid & 1) * (BNT / 2);
    const int m0   = xcdswz(blockIdx.y, gridDim.y) * GBM;
    const int n0   = blockIdx.x * BNT;
    const int row16 = lane & 15;
    const int hi    = lane >> 4;
    const int koff  = hi * 8;

    const int arow[2] = { tid >> 2, (tid + 256) >> 2 };
    const int akk     = (tid & 3) * 8;

    const u16* Wb = W;
    if constexpr (WPB) Wb = W + (size_t)(m0 >> 14) * 9216;

    float meanA[2], rstdA[2];
    if constexpr (AMODE == 1) {
        #pragma unroll
        for (int it = 0; it < 2; ++it) {
            const int m = m0 + arow[it];
            meanA[it] = stats[2*m]; rstdA[it] = stats[2*m+1];
        }
    }

    f32x4 acc[4][NF];
    #pragma unroll
    for (int mf = 0; mf < 4; ++mf)
        #pragma unroll
        for (int nf = 0; nf < NF; ++nf)
            acc[mf][nf] = (f32x4){0.f, 0.f, 0.f, 0.f};

    const int nsteps = (K + GBK - 1) / GBK;

    auto loadA = [&](int step, SegRaw seg[2]) {
        const int k0 = step * GBK;
        #pragma unroll
        for (int it = 0; it < 2; ++it) {
            const int m = m0 + arow[it];
            const int k = k0 + akk;
            SegRaw& s = seg[it];
            if (k >= K) { s.d.v = (uint4){0u,0u,0u,0u}; continue; }
            if constexpr (AMODE == 0) {
                s.d.v = *(const uint4*)((const u16*)A + (size_t)m * K + k);
            } else if constexpr (AMODE == 1) {
                const float* p = (const float*)A + (size_t)m * K + k;
                s.d.f.lo = *(const float4*)p; s.d.f.hi = *(const float4*)(p+4);
            } else if constexpr (AMODE == 2) {
                const u16* src = (k < CCH) ? (const u16*)A  + (size_t)m * CCH + k
                                           : (const u16*)A2 + (size_t)m * CCH + (k - CCH);
                s.d.v = *(const uint4*)src;
            } else if constexpr (AMODE == 3) {
                const int tap = k / CCH, c = k - tap * CCH;
                const int ky = tap / 3, kx = tap - ky * 3;
                const int b = m >> 14, pix = m & 16383;
                const int h = pix >> 7, w = pix & 127;
                s.d.v = *(const uint4*)((const u16*)A +
                        ((size_t)b * PHW + (size_t)(h + ky) * PH + (w + kx)) * CCH + c);
            } else {
                const int col = (k < 24) ? (48 + k) : (96 + k);
                s.d.v = *(const uint4*)((const u16*)A + (size_t)m * CHC + col);
            }
        }
    };
    auto loadB = [&](int step, SegRaw seg[NB]) {
        const int k0 = step * GBK;
        #pragma unroll
        for (int it = 0; it < NB; ++it) {
            const int s = tid + it * 256;
            const int n = n0 + (s >> 2);
            const int k = k0 + (s & 3) * 8;
            seg[it].d.v = (uint4){0u,0u,0u,0u};
            if (s < BNT*4 && k < K && n < N)
                seg[it].d.v = *(const uint4*)(Wb + (size_t)n * K + k);
        }
    };
    auto writeA = [&](int step, SegRaw seg[2], u16* Ab) {
        const int k0 = step * GBK;
        #pragma unroll
        for (int it = 0; it < 2; ++it) {
            if constexpr (AMODE == 1) {
                const int k = k0 + akk;
                union { u16 u[8]; uint4 v; } pk;
                #pragma unroll
                for (int j = 0; j < 8; ++j) {
                    float xx = (j < 4) ? seg[it].d.f.lo[j] : seg[it].d.f.hi[j-4];
                    xx = (xx - meanA[it]) * rstdA[it] * lng[k+j] + lnb[k+j];
                    pk.u[j] = f2u(xx);
                }
                *(uint4*)&Ab[arow[it] * LDA + akk] = pk.v;
            } else {
                *(uint4*)&Ab[arow[it] * LDA + akk] = seg[it].d.v;
            }
        }
    };
    auto writeB = [&](SegRaw seg[NB], u16* Bb) {
        #pragma unroll
        for (int it = 0; it < NB; ++it) {
            const int s = tid + it * 256;
            if (s < BNT*4)
                *(uint4*)&Bb[(s >> 2) * LDA + (s & 3) * 8] = seg[it].d.v;
        }
    };

    SegRaw segA[2], segB[NB];
    loadA(0, segA); loadB(0, segB);
    writeA(0, segA, smem); writeB(segB, smem + ATILE);
    __syncthreads();

    int cur = 0;
    for (int step = 0; step < nsteps; ++step) {
        const bool more = (step + 1 < nsteps);
        if (more) { loadA(step+1, segA); loadB(step+1, segB); }
        u16* Ab = smem + cur * BUFSZ;
        u16* Bb = Ab + ATILE;
        s16x8 af[4], bfr[NF];
        #pragma unroll
        for (int mf = 0; mf < 4; ++mf)
            af[mf] = *(const s16x8*)&Ab[(wm + mf*16 + row16) * LDA + koff];
        #pragma unroll
        for (int nf = 0; nf < NF; ++nf)
            bfr[nf] = *(const s16x8*)&Bb[(wn + nf*16 + row16) * LDA + koff];
        __builtin_amdgcn_s_setprio(1);
        #pragma unroll
        for (int mf = 0; mf < 4; ++mf)
            #pragma unroll
            for (int nf = 0; nf < NF; ++nf)
                acc[mf][nf] = __builtin_amdgcn_mfma_f32_16x16x32_bf16(
                    af[mf], bfr[nf], acc[mf][nf], 0, 0, 0);
        __builtin_amdgcn_s_setprio(0);
        if (more) {
            u16* An = smem + (cur ^ 1) * BUFSZ;
            writeA(step+1, segA, An); writeB(segB, An + ATILE);
        }
        __syncthreads();
        cur ^= 1;
    }

    // ================= epilogue =================
    if constexpr (CBF == 1) {
        // ---- stage bf16 C tile into LDS (padded stride CST) ----
        #pragma unroll
        for (int mf = 0; mf < 4; ++mf) {
            #pragma unroll
            for (int nf = 0; nf < NF; ++nf) {
                const int n = n0 + wn + nf*16 + row16;
                #pragma unroll
                for (int r = 0; r < 4; ++r) {
                    const int m_loc = wm + mf*16 + hi*4 + r;
                    float v = acc[mf][nf][r];
                    if (n < N) {
                        v += (bias ? bias[n] : 0.f);
                        if constexpr (EPI == 1) {
                            v = fmaxf(v, 0.f);
                        } else if constexpr (EPI == 3) {
                            v = (v - ep2[n]) * rsqrtf(ep3[n] + 1e-5f) * ep0[n] + ep1[n];
                            v = fmaxf(v, 0.f);
                        } else if constexpr (EPI == 4) {
                            const int b = (m0 + m_loc) >> 14;
                            v = v * ep0[b * N + n];
                        } else if constexpr (EPI == 5) {
                            v = 0.5f * v * (1.f + erff(v * 0.70710678118654752f));
                        }
                    }
                    smem[m_loc * CST + (wn + nf*16 + row16)] = f2u(v);
                }
            }
        }
        __syncthreads();
        // ---- vectorized store: 8 bf16 (16B) per task ----
        constexpr int CHUNKS = BNT / 8;
        constexpr int TASKS  = GBM * CHUNKS / 256;
        #pragma unroll
        for (int t2 = 0; t2 < TASKS; ++t2) {
            const int task  = tid + t2 * 256;
            const int rloc  = task / CHUNKS;
            const int chunk = task - rloc * CHUNKS;
            const int m  = m0 + rloc;
            const int nn = n0 + chunk * 8;
            if (nn >= N) continue;
            uint4 val = *(const uint4*)&smem[rloc * CST + chunk * 8];
            if constexpr (EPI == 7) {
                if (nn < SPC) {
                    *(uint4*)((u16*)Cv + (size_t)m * SPC + nn) = val;
                } else {
                    u16* chq = (u16*)ep0;
                    *(uint4*)(chq + (size_t)m * CHC + (nn - SPC)) = val;
                }
                continue;
            }
            size_t outIdx;
            if constexpr (CPAD == 1) {
                const int b = m >> 14, pix = m & 16383;
                const int h = pix >> 7, w = pix & 127;
                outIdx = ((size_t)b * PHW + (size_t)(h+1) * PH + (w+1)) * (size_t)N + nn;
            } else if constexpr (EPI == 2) {
                const int b = m >> 14, pix = m & 16383;
                const int h2 = ((pix >> 7) + 4) & 127;
                const int w2 = ((pix & 127) + 4) & 127;
                outIdx = ((size_t)(b * HW) + h2 * WR + w2) * (size_t)N + nn;
            } else {
                outIdx = (size_t)m * N + nn;
            }
            if constexpr (EPI == 4) {
                union { uint4 v; u16 u[8]; } sv, ov;
                sv.v = val;
                ov.v = *(const uint4*)((const u16*)Cv + outIdx);
                #pragma unroll
                for (int j = 0; j < 8; ++j)
                    sv.u[j] = f2u(u2f(ov.u[j]) + u2f(sv.u[j]));
                *(uint4*)((u16*)Cv + outIdx) = sv.v;
            } else {
                *(uint4*)((u16*)Cv + outIdx) = val;
            }
        }
    } else {
        // ---- fp32 path (fc2, EPI6, N==BNT): LDS-staged float4 stores,
        //      32-row quarters, stride BNT+16 (2-way-free banks) ----
        float* fs = (float*)smem;
        constexpr int FST = BNT + 16;
        #pragma unroll
        for (int q = 0; q < 4; ++q) {
            __syncthreads();
            if ((wid >> 1) == (q >> 1)) {
                #pragma unroll
                for (int mfi = 0; mfi < 2; ++mfi) {
                    const int mf = (q & 1) * 2 + mfi;
                    #pragma unroll
                    for (int nf = 0; nf < NF; ++nf) {
                        const int n = wn + nf*16 + row16;
                        #pragma unroll
                        for (int r = 0; r < 4; ++r) {
                            const int mloc = mfi*16 + hi*4 + r;   // 0..31
                            fs[mloc * FST + n] = acc[mf][nf][r] + (bias ? bias[n0 + n] : 0.f);
                        }
                    }
                }
            }
            __syncthreads();
            const int TOT = 32 * (BNT/4);
            for (int task = tid; task < TOT; task += 256) {
                const int rloc = task / (BNT/4);
                const int cc = (task - rloc*(BNT/4)) * 4;
                const int m = m0 + q*32 + rloc;
                const int nn = n0 + cc;
                if (nn >= N) continue;
                float4 v4 = *(const float4*)&fs[rloc*FST + cc];
                const size_t oi = (size_t)m * N + nn;
                if constexpr (EPI == 6) {
                    const float4 o4 = *(const float4*)&ep0[oi];
                    v4.x += o4.x; v4.y += o4.y; v4.z += o4.z; v4.w += o4.w;
                }
                *(float4*)&((float*)Cv)[oi] = v4;
            }
        }
    }
}

// =====================================================================
// weight prep
// =====================================================================
__global__ __launch_bounds__(256)
void wprep_lin_k(const float* __restrict__ in, bf16* __restrict__ outb, int n)
{
    const int i = blockIdx.x * 256 + threadIdx.x;
    if (i < n) outb[i] = f2b(in[i]);
}

__global__ __launch_bounds__(256)
void wprep_conv_k(const float* __restrict__ in, bf16* __restrict__ outb, int total)
{
    const int i = blockIdx.x * 256 + threadIdx.x;
    if (i >= total) return;
    const int n = i / 1728, r = i - n * 1728;
    const int tap = r / CCH, c = r - tap * CCH;
    outb[i] = f2b(in[((size_t)n * CCH + c) * 9 + tap]);
}

__global__ __launch_bounds__(256)
void zb_k(bf16* __restrict__ buf)
{
    const int i = blockIdx.x * 256 + threadIdx.x;
    if (i >= 8 * 516 * 24) return;
    const int chunk = i % 24;
    const int p = (i / 24) % 516;
    const int b = i / (24 * 516);
    int h, w;
    if (p < 130)      { h = 0;   w = p; }
    else if (p < 260) { h = 129; w = p - 130; }
    else { const int q = p - 260; h = 1 + (q >> 1); w = (q & 1) ? 129 : 0; }
    *(uint4*)((u16*)buf + ((size_t)b * PHW + (size_t)h * PH + w) * CCH + chunk * 8)
        = (uint4){0u,0u,0u,0u};
}

__global__ __launch_bounds__(256)
void zerof_k(float* __restrict__ p, int n)
{
    const int i = blockIdx.x * 256 + threadIdx.x;
    if (i < n) p[i] = 0.f;
}

// =====================================================================
// LN stats
// =====================================================================
__global__ __launch_bounds__(256)
void ln_stats_k(const float* __restrict__ x, float* __restrict__ stats)
{
    const int tok = blockIdx.x * 4 + (threadIdx.x >> 6);
    const int lane = threadIdx.x & 63;
    const float* r = x + (size_t)tok * CCH;
    float s = 0.f, sq = 0.f;
    for (int c = lane; c < CCH; c += 64) { float v = r[c]; s += v; sq += v*v; }
    for (int m = 1; m < 64; m <<= 1) { s += __shfl_xor(s, m); sq += __shfl_xor(sq, m); }
    if (lane == 0) {
        const float mean = s / (float)CCH;
        const float var = sq / (float)CCH - mean * mean;
        stats[(size_t)tok*2]   = mean;
        stats[(size_t)tok*2+1] = rsqrtf(var + 1e-5f);
    }
}

// =====================================================================
// MFMA spatial shifted-window cosine attention (6 waves = 6 heads/window)
// =====================================================================
__global__ __launch_bounds__(384)
void sp_attn_k(const bf16* __restrict__ spqkv, const float* __restrict__ rpb,
               const float* __restrict__ logit_sp, bf16* __restrict__ osp)
{
    const int b    = blockIdx.x >> 8;
    const int win  = blockIdx.x & 255;
    const int wh = win >> 4, ww = win & 15;
    const int head = threadIdx.x >> 6;
    const int lane = threadIdx.x & 63;
    const int row16 = lane & 15;
    const int hi   = lane >> 4;
    const int koff = hi * 8;

    __shared__ float rpbS[1350];
    __shared__ u16 vT[SPH][32][72];

    for (int i = threadIdx.x; i < 1350; i += 384) rpbS[i] = rpb[i];

    const u16* base = (const u16*)spqkv + (size_t)b * HW * SPC;

    s16x8 qf[4], kf[4];
    const int wcol = (ww*8 + (row16 & 7) + 4) & 127;
    #pragma unroll
    for (int t = 0; t < 4; ++t) {
        const int pos = t*16 + row16;
        const int h = (wh*8 + (pos >> 3) + 4) & 127;
        const u16* rowp = base + ((size_t)(h * WR + wcol)) * SPC + head * 72;
        if (koff < 24) {
            qf[t] = *(const s16x8*)(rowp + koff);
            kf[t] = *(const s16x8*)(rowp + 24 + koff);
        } else {
            qf[t] = (s16x8){0,0,0,0,0,0,0,0};
            kf[t] = (s16x8){0,0,0,0,0,0,0,0};
        }
    }

    {
        const int h = (wh*8 + (lane >> 3) + 4) & 127;
        const int w = (ww*8 + (lane & 7) + 4) & 127;
        const u16* vrow = base + ((size_t)(h * WR + w)) * SPC + head * 72 + 48;
        union { uint4 v; u16 u[8]; } seg[3];
        seg[0].v = *(const uint4*)(vrow);
        seg[1].v = *(const uint4*)(vrow + 8);
        seg[2].v = *(const uint4*)(vrow + 16);
        #pragma unroll
        for (int d = 0; d < 24; ++d) vT[head][d][lane] = seg[d>>3].u[d&7];
        #pragma unroll
        for (int d = 24; d < 32; ++d) vT[head][d][lane] = 0;
    }
    __syncthreads();

    float rq[4], rk[4];
    #pragma unroll
    for (int t = 0; t < 4; ++t) {
        float sq = 0.f, sk = 0.f;
        #pragma unroll
        for (int e = 0; e < 8; ++e) {
            const float a = s2f(qf[t][e]); sq += a*a;
            const float c = s2f(kf[t][e]); sk += c*c;
        }
        sq += __shfl_xor(sq, 16); sq += __shfl_xor(sq, 32);
        sk += __shfl_xor(sk, 16); sk += __shfl_xor(sk, 32);
        rq[t] = 1.f / fmaxf(sqrtf(sq), 1e-12f);
        rk[t] = 1.f / fmaxf(sqrtf(sk), 1e-12f);
    }
    const float scale_h = __expf(fminf(logit_sp[head], LOGMAX));

    f32x4 acc[4][4];
    #pragma unroll
    for (int mfk = 0; mfk < 4; ++mfk)
        #pragma unroll
        for (int nfq = 0; nfq < 4; ++nfq)
            acc[mfk][nfq] = (f32x4){0.f,0.f,0.f,0.f};
    #pragma unroll
    for (int mfk = 0; mfk < 4; ++mfk)
        #pragma unroll
        for (int nfq = 0; nfq < 4; ++nfq)
            acc[mfk][nfq] = __builtin_amdgcn_mfma_f32_16x16x32_bf16(
                kf[mfk], qf[nfq], acc[mfk][nfq], 0, 0, 0);

    f32x4 rkj[4];
    #pragma unroll
    for (int mfk = 0; mfk < 4; ++mfk)
        #pragma unroll
        for (int r = 0; r < 4; ++r)
            rkj[mfk][r] = __shfl(rk[mfk], hi*4 + r);

    int ip3[4], iw7[4], labi[4];
    #pragma unroll
    for (int t = 0; t < 4; ++t) {
        const int pos = t*16 + row16;
        ip3[t] = pos >> 3; iw7[t] = pos & 7;
        const int hh = wh*8 + ip3[t], w0 = ww*8 + iw7[t];
        const int rh = hh < 120 ? 0 : (hh < 124 ? 1 : 2);
        const int rw = w0 < 120 ? 0 : (w0 < 124 ? 1 : 2);
        labi[t] = rh*3 + rw;
    }

    #pragma unroll
    for (int mfk = 0; mfk < 4; ++mfk) {
        #pragma unroll
        for (int r = 0; r < 4; ++r) {
            const int j = hi*4 + r + 16*mfk;
            const int jp3 = j >> 3, jw7 = j & 7;
            const int hh = wh*8 + jp3, w0 = ww*8 + jw7;
            const int rh = hh < 120 ? 0 : (hh < 124 ? 1 : 2);
            const int rw = w0 < 120 ? 0 : (w0 < 124 ? 1 : 2);
            const int labj = rh*3 + rw;
            const float rkv = rkj[mfk][r];
            #pragma unroll
            for (int nfq = 0; nfq < 4; ++nfq) {
                float s = acc[mfk][nfq][r] * rq[nfq] * rkv * scale_h;
                s += rpbS[((ip3[nfq]-jp3+7)*15 + (iw7[nfq]-jw7+7))*SPH + head];
                if (labi[nfq] != labj) s -= 100.f;
                acc[mfk][nfq][r] = s;
            }
        }
    }

    float inv[4];
    #pragma unroll
    for (int nfq = 0; nfq < 4; ++nfq) {
        float m = -1e30f;
        #pragma unroll
        for (int mfk = 0; mfk < 4; ++mfk)
            #pragma unroll
            for (int r = 0; r < 4; ++r)
                m = fmaxf(m, acc[mfk][nfq][r]);
        m = fmaxf(m, __shfl_xor(m, 16));
        m = fmaxf(m, __shfl_xor(m, 32));
        float s = 0.f;
        #pragma unroll
        for (int mfk = 0; mfk < 4; ++mfk)
            #pragma unroll
            for (int r = 0; r < 4; ++r) {
                const float p = __expf(acc[mfk][nfq][r] - m);
                acc[mfk][nfq][r] = p;
                s += p;
            }
        s += __shfl_xor(s, 16);
        s += __shfl_xor(s, 32);
        inv[nfq] = 1.f / s;
    }

    u32 pk01[4][4], pk23[4][4];
    #pragma unroll
    for (int mfk = 0; mfk < 4; ++mfk)
        #pragma unroll
        for (int nfq = 0; nfq < 4; ++nfq) {
            pk01[mfk][nfq] = (u32)f2u(acc[mfk][nfq][0] * inv[nfq])
                           | ((u32)f2u(acc[mfk][nfq][1] * inv[nfq]) << 16);
            pk23[mfk][nfq] = (u32)f2u(acc[mfk][nfq][2] * inv[nfq])
                           | ((u32)f2u(acc[mfk][nfq][3] * inv[nfq]) << 16);
        }

    s16x8 vf[2][2];
    #pragma unroll
    for (int nf = 0; nf < 2; ++nf)
        #pragma unroll
        for (int ks = 0; ks < 2; ++ks)
            vf[nf][ks] = *(const s16x8*)&vT[head][row16 + 16*nf][32*ks + koff];

    f32x4 accO[4][2];
    #pragma unroll
    for (int MF = 0; MF < 4; ++MF)
        #pragma unroll
        for (int nf = 0; nf < 2; ++nf)
            accO[MF][nf] = (f32x4){0.f,0.f,0.f,0.f};

    const int g0 = 2*(hi & 1);
    const int src0 = g0*16 + row16, src1 = src0 + 16;
    const bool selhi = (hi >> 1) != 0;
    #pragma unroll
    for (int ks = 0; ks < 2; ++ks) {
        #pragma unroll
        for (int MF = 0; MF < 4; ++MF) {
            const u32 e01a = __shfl(pk01[2*ks][MF],   src0);
            const u32 e01b = __shfl(pk01[2*ks+1][MF], src0);
            const u32 e23a = __shfl(pk23[2*ks][MF],   src0);
            const u32 e23b = __shfl(pk23[2*ks+1][MF], src0);
            const u32 e45a = __shfl(pk01[2*ks][MF],   src1);
            const u32 e45b = __shfl(pk01[2*ks+1][MF], src1);
            const u32 e67a = __shfl(pk23[2*ks][MF],   src1);
            const u32 e67b = __shfl(pk23[2*ks+1][MF], src1);
            union { u32 w[4]; s16x8 v; } af;
            af.w[0] = selhi ? e01b : e01a;
            af.w[1] = selhi ? e23b : e23a;
            af.w[2] = selhi ? e45b : e45a;
            af.w[3] = selhi ? e67b : e67a;
            accO[MF][0] = __builtin_amdgcn_mfma_f32_16x16x32_bf16(
                af.v, vf[0][ks], accO[MF][0], 0, 0, 0);
            accO[MF][1] = __builtin_amdgcn_mfma_f32_16x16x32_bf16(
                af.v, vf[1][ks], accO[MF][1], 0, 0, 0);
        }
    }

    #pragma unroll
    for (int MF = 0; MF < 4; ++MF) {
        #pragma unroll
        for (int nf = 0; nf < 2; ++nf) {
            const int d = row16 + 16*nf;
            if (d >= 24) continue;
            #pragma unroll
            for (int r = 0; r < 4; ++r) {
                const int qrow = hi*4 + r + 16*MF;
                const int h = wh*8 + (qrow >> 3);
                const int w = ww*8 + (qrow & 7);
                osp[((size_t)b*HW + h*WR + w)*144 + head*24 + d] = f2b(accO[MF][nf][r]);
            }
        }
    }
}

// =====================================================================
// Channel attention: partial gram + column sum-squares, softmax, W-fuse
// =====================================================================
__global__ __launch_bounds__(256)
void ch_part_k(const bf16* __restrict__ chqkv, float* __restrict__ pgram,
               float* __restrict__ pss)
{
    const int ci = blockIdx.x, head = blockIdx.y, b = blockIdx.z;
    const int tid = threadIdx.x;
    __shared__ u16 tile[256][48];
    float g[3] = {0.f, 0.f, 0.f};
    float ss = 0.f;
    const u16* src = (const u16*)chqkv + (size_t)b * HW * CHC + head * 72;
    const int rbase = ci * 1024;

    for (int t0 = 0; t0 < 1024; t0 += 256) {
        __syncthreads();
        for (int idx = tid; idx < 256*6; idx += 256) {
            const int row = idx / 6, seg = idx - (idx/6)*6;
            *(uint4*)&tile[row][seg*8] =
                *(const uint4*)(src + (size_t)(rbase + t0 + row) * CHC + seg*8);
        }
        __syncthreads();
        #pragma unroll
        for (int i = 0; i < 3; ++i) {
            const int e = tid + i*256;
            if (e < 576) {
                const int c = e / 24, d = e - (e/24)*24;
                float s = 0.f;
                for (int r = 0; r < 256; ++r)
                    s += b2f(*(const bf16*)&tile[r][c]) * b2f(*(const bf16*)&tile[r][24+d]);
                g[i] += s;
            }
        }
        if (tid < 48) {
            float s = 0.f;
            for (int r = 0; r < 256; ++r) { const float v = b2f(*(const bf16*)&tile[r][tid]); s += v*v; }
            ss += s;
        }
    }
    float* pg = pgram + ((size_t)(b*2+head)*16 + ci) * 576;
    #pragma unroll
    for (int i = 0; i < 3; ++i) { const int e = tid + i*256; if (e < 576) pg[e] = g[i]; }
    if (tid < 48) pss[((size_t)(b*2+head)*16 + ci) * 48 + tid] = ss;
}

__global__ __launch_bounds__(256)
void ch_soft_k(const float* __restrict__ pgram, const float* __restrict__ pss,
               const float* __restrict__ logit_ch, float* __restrict__ attn)
{
    const int head = blockIdx.x, b = blockIdx.y;
    const int tid = threadIdx.x;
    __shared__ float gs[576], rn[48];
    for (int e = tid; e < 576; e += 256) {
        float s = 0.f;
        const float* pg = pgram + (size_t)(b*2+head)*16*576 + e;
        for (int c = 0; c < 16; ++c) s += pg[c*576];
        gs[e] = s;
    }
    if (tid < 48) {
        float s = 0.f;
        const float* ps = pss + (size_t)(b*2+head)*16*48 + tid;
        for (int c = 0; c < 16; ++c) s += ps[c*48];
        rn[tid] = 1.f / fmaxf(sqrtf(s), 1e-12f);
    }
    __syncthreads();
    if (tid < 24) {
        const float scale = expf(fminf(logit_ch[head], LOGMAX));
        float vals[24], mx = -1e30f;
        #pragma unroll
        for (int d = 0; d < 24; ++d) {
            vals[d] = gs[tid*24+d] * rn[tid] * rn[24+d] * scale;
            mx = fmaxf(mx, vals[d]);
        }
        float sum = 0.f;
        #pragma unroll
        for (int d = 0; d < 24; ++d) { vals[d] = expf(vals[d]-mx); sum += vals[d]; }
        const float inv = 1.f / sum;
        float* o = attn + ((size_t)(b*2+head)*24 + tid)*24;
        #pragma unroll
        for (int d = 0; d < 24; ++d) o[d] = vals[d]*inv;
    }
}

__global__ __launch_bounds__(192)
void fuse_chw_k(const float* __restrict__ Wc, const float* __restrict__ attn,
                bf16* __restrict__ Wf)
{
    const int b = blockIdx.x;
    const int n = threadIdx.x;
    __shared__ float As_[2][24][24];
    for (int e = n; e < 1152; e += 192) {
        const int h = e / 576, r = e - h*576;
        As_[h][r/24][r%24] = attn[(size_t)b*1152 + e];
    }
    __syncthreads();
    const float* wr = Wc + n*48;
    bf16* o = Wf + ((size_t)b*192 + n) * 48;
    for (int h = 0; h < 2; ++h)
        for (int d = 0; d < 24; ++d) {
            float s = 0.f;
            #pragma unroll
            for (int cc = 0; cc < 24; ++cc) s += wr[h*24+cc] * As_[h][cc][d];
            o[h*24+d] = f2b(s);
        }
}

// =====================================================================
// weight combiners
// =====================================================================
__global__ void combine_sp_k(const float* __restrict__ w_sp_proj, const float* __restrict__ w_spp,
                             const float* __restrict__ b_spp, bf16* __restrict__ Wc, float* __restrict__ bc)
{
    const int n = blockIdx.x;
    for (int i = threadIdx.x; i < 144; i += blockDim.x) {
        float s = 0.f;
        for (int j = 0; j < 144; ++j) s += w_sp_proj[n*144 + j] * w_spp[j*144 + i];
        Wc[n*144 + i] = f2b(s);
    }
    if (threadIdx.x == 0) {
        float s = 0.f;
        for (int j = 0; j < 144; ++j) s += w_sp_proj[n*144 + j] * b_spp[j];
        bc[n] = s;
    }
}

__global__ void combine_ch_k(const float* __restrict__ w_ch_proj, const float* __restrict__ w_chp,
                             const float* __restrict__ b_chp, float* __restrict__ Wc, float* __restrict__ bc)
{
    const int n = blockIdx.x;
    for (int c = threadIdx.x; c < 48; c += blockDim.x) {
        float s = 0.f;
        for (int j = 0; j < 48; ++j) s += w_ch_proj[n*48 + j] * w_chp[j*48 + c];
        Wc[n*48 + c] = s;
    }
    if (threadIdx.x == 0) {
        float s = 0.f;
        for (int j = 0; j < 48; ++j) s += w_ch_proj[n*48 + j] * b_chp[j];
        bc[n] = s;
    }
}

// =====================================================================
// coalesced per-(b,c) SUM over H,W (bf16 src), atomic accumulate
// =====================================================================
__global__ __launch_bounds__(256)
void mean2_k(const bf16* __restrict__ src, float* __restrict__ dst)
{
    const int b = blockIdx.y;
    const int r0 = blockIdx.x * 256;
    const int t = threadIdx.x;
    const int chunk = t & 31;
    const int rg = t >> 5;
    float acc[8] = {0.f,0.f,0.f,0.f,0.f,0.f,0.f,0.f};
    if (chunk < 24) {
        for (int r = rg; r < 256; r += 8) {
            const u16* p = (const u16*)src + ((size_t)(b*HW) + r0 + r) * CCH + chunk*8;
            union { uint4 v; u16 u[8]; } s; s.v = *(const uint4*)p;
            #pragma unroll
            for (int j = 0; j < 8; ++j) acc[j] += u2f(s.u[j]);
        }
    }
    __shared__ float red[8][24][8];
    if (chunk < 24) {
        #pragma unroll
        for (int j = 0; j < 8; ++j) red[rg][chunk][j] = acc[j];
    }
    __syncthreads();
    if (t < 192) {
        const int ch = t >> 3, j = t & 7;
        float s = 0.f;
        #pragma unroll
        for (int g = 0; g < 8; ++g) s += red[g][ch][j];
        atomicAdd(&dst[b*CCH + ch*8 + j], s);
    }
}

// gate = sigmoid(relu((sum/HW) @ w1^T) @ w2^T + b2)
__global__ __launch_bounds__(192)
void gates_k(const float* __restrict__ sumv, const float* __restrict__ w1,
             const float* __restrict__ w2, const float* __restrict__ b2,
             float* __restrict__ gate)
{
    const int b = blockIdx.x;
    __shared__ float mv[192], hid[48];
    const int t = threadIdx.x;
    mv[t] = sumv[b*CCH + t] * (1.f / (float)HW);
    __syncthreads();
    if (t < 48) {
        float s = 0.f;
        for (int c = 0; c < 192; ++c) s += w1[t*192 + c] * mv[c];
        hid[t] = fmaxf(s, 0.f);
    }
    __syncthreads();
    float s = b2[t];
    for (int j = 0; j < 48; ++j) s += hid[j] * w2[t*48 + j];
    gate[b*CCH + t] = 1.f / (1.f + expf(-s));
}

// =====================================================================
// out = x + f2(padded) * (1 + sigmoid(relu(gpre)@w_sg2 + b))
// =====================================================================
__global__ __launch_bounds__(256)
void fuse_k(const float* __restrict__ x, const bf16* __restrict__ f2pad,
            const bf16* __restrict__ gpre, const float* __restrict__ w_sg2,
            const float* __restrict__ b_sg2, float* __restrict__ out)
{
    const int pix = blockIdx.x * 4 + (threadIdx.x >> 6);
    const int lane = threadIdx.x & 63;
    const bf16* gp = gpre + (size_t)pix * 96;
    float s = fmaxf(b2f(gp[lane]), 0.f) * w_sg2[lane];
    if (lane < 32) s += fmaxf(b2f(gp[lane + 64]), 0.f) * w_sg2[lane + 64];
    for (int m = 1; m < 64; m <<= 1) s += __shfl_xor(s, m);
    const float g1 = 1.f + 1.f / (1.f + expf(-(s + b_sg2[0])));
    const int b = pix >> 14, p = pix & 16383;
    const int h = p >> 7, w = p & 127;
    const bf16* fr = f2pad + ((size_t)b * PHW + (size_t)(h+1) * PH + (w+1)) * CCH;
    const float* xr = x + (size_t)pix * CCH;
    float* orow = out + (size_t)pix * CCH;
    for (int c = lane; c < CCH; c += 64) orow[c] = xr[c] + b2f(fr[c]) * g1;
}

// =====================================================================
// launcher
// =====================================================================
extern "C" void kernel_launch(void* const* d_in, const int* in_sizes, int n_in,
                              void* d_out, int out_size, void* d_ws, size_t ws_size,
                              hipStream_t stream)
{
    const float* x        = (const float*)d_in[0];
    const float* ln1_g    = (const float*)d_in[1];
    const float* ln1_b    = (const float*)d_in[2];
    const float* w_qkv    = (const float*)d_in[3];
    const float* b_qkv    = (const float*)d_in[4];
    const float* logit_sp = (const float*)d_in[5];
    const float* rpb      = (const float*)d_in[6];
    const float* w_spp    = (const float*)d_in[7];
    const float* b_spp    = (const float*)d_in[8];
    const float* logit_ch = (const float*)d_in[9];
    const float* w_chp    = (const float*)d_in[10];
    const float* b_chp    = (const float*)d_in[11];
    const float* w_sp_proj= (const float*)d_in[12];
    const float* w_ch_proj= (const float*)d_in[13];
    const float* w_s2c1   = (const float*)d_in[14];
    const float* w_s2c2   = (const float*)d_in[15];
    const float* b_s2c2   = (const float*)d_in[16];
    const float* w_c2s1   = (const float*)d_in[17];
    const float* w_c2s2   = (const float*)d_in[18];
    const float* b_c2s2   = (const float*)d_in[19];
    const float* w_gs1    = (const float*)d_in[20];
    const float* w_gs2    = (const float*)d_in[21];
    const float* b_gs2    = (const float*)d_in[22];
    const float* w_gc1    = (const float*)d_in[23];
    const float* w_gc2    = (const float*)d_in[24];
    const float* b_gc2    = (const float*)d_in[25];
    const float* w_f1     = (const float*)d_in[26];
    const float* bn1_g    = (const float*)d_in[27];
    const float* bn1_b    = (const float*)d_in[28];
    const float* bn1_m    = (const float*)d_in[29];
    const float* bn1_v    = (const float*)d_in[30];
    const float* w_f2     = (const float*)d_in[31];
    const float* bn2_g    = (const float*)d_in[32];
    const float* bn2_b    = (const float*)d_in[33];
    const float* bn2_m    = (const float*)d_in[34];
    const float* bn2_v    = (const float*)d_in[35];
    const float* w_sg1    = (const float*)d_in[36];
    const float* w_sg2    = (const float*)d_in[37];
    const float* b_sg2    = (const float*)d_in[38];
    const float* ln2_g    = (const float*)d_in[39];
    const float* ln2_b    = (const float*)d_in[40];
    const float* w_fc1    = (const float*)d_in[41];
    const float* b_fc1    = (const float*)d_in[42];
    const float* w_fc2    = (const float*)d_in[43];
    const float* b_fc2    = (const float*)d_in[44];

    char* wsb = (char*)d_ws;
    char* sm  = wsb + OFF_SMALL;
    float* out = (float*)d_out;

    bf16*  spqkv  = (bf16*)(wsb + OFF_A0);
    bf16*  sp_out = (bf16*)(wsb + OFF_A0);
    bf16*  ch_out = (bf16*)(wsb + OFF_A0 + 50331648);
    bf16*  f2pad  = (bf16*)(wsb + OFF_A0);
    bf16*  gpre   = (bf16*)(wsb + OFF_A0 + 51916800);
    bf16*  chqkv  = (bf16*)(wsb + OFF_B0);
    bf16*  hid_s  = (bf16*)(wsb + OFF_B0);
    bf16*  hid_c  = (bf16*)(wsb + OFF_B0 + 12582912);
    bf16*  fpad   = (bf16*)(wsb + OFF_B0);
    bf16*  hidden = (bf16*)(wsb + OFF_A0);   // fc1 out: A0 dead after fuse_k
    bf16*  osp    = (bf16*)(wsb + OFF_C0);

    float* stats  = (float*)(sm + SO_STATS);
    float* pgram  = (float*)(sm + SO_PGRAM);
    float* pss    = (float*)(sm + SO_PSS);
    float* attn_b = (float*)(sm + SO_ATTNB);
    float* mean_sp= (float*)(sm + SO_MEANSP);
    float* mean_ch= (float*)(sm + SO_MEANCH);
    float* gate_s = (float*)(sm + SO_GATES);
    float* gate_c = (float*)(sm + SO_GATEC);
    float* bc_sp  = (float*)(sm + SO_BCSP);
    float* Wc_ch  = (float*)(sm + SO_WCCH);
    float* bc_ch  = (float*)(sm + SO_BCCH);
    bf16*  Wfuse  = (bf16*)(sm + SO_WFUSE);
    bf16*  Wc_spB = (bf16*)(sm + SO_WCSPB);
    u16*   wqB    = (u16*)(sm + SO_WQB);
    u16*   ws2c1B = (u16*)(sm + SO_WS2C1B);
    u16*   wc2s1B = (u16*)(sm + SO_WC2S1B);
    u16*   ws2c2B = (u16*)(sm + SO_WS2C2B);
    u16*   wc2s2B = (u16*)(sm + SO_WC2S2B);
    u16*   wf1B   = (u16*)(sm + SO_WF1B);
    u16*   wf2cB  = (u16*)(sm + SO_WF2CB);
    u16*   wsg1cB = (u16*)(sm + SO_WSG1CB);
    u16*   wfc1B  = (u16*)(sm + SO_WFC1B);
    u16*   wfc2B  = (u16*)(sm + SO_WFC2B);

    const dim3 blk(256);

    // ---- weight prep ----
    wprep_lin_k<<<(110592+255)/256, blk, 0, stream>>>(w_qkv,  (bf16*)wqB,    110592);
    wprep_lin_k<<<(9216+255)/256,   blk, 0, stream>>>(w_s2c1, (bf16*)ws2c1B, 9216);
    wprep_lin_k<<<(9216+255)/256,   blk, 0, stream>>>(w_c2s1, (bf16*)wc2s1B, 9216);
    wprep_lin_k<<<(9216+255)/256,   blk, 0, stream>>>(w_s2c2, (bf16*)ws2c2B, 9216);
    wprep_lin_k<<<(9216+255)/256,   blk, 0, stream>>>(w_c2s2, (bf16*)wc2s2B, 9216);
    wprep_lin_k<<<(73728+255)/256,  blk, 0, stream>>>(w_f1,   (bf16*)wf1B,   73728);
    wprep_lin_k<<<(147456+255)/256, blk, 0, stream>>>(w_fc1,  (bf16*)wfc1B,  147456);
    wprep_lin_k<<<(147456+255)/256, blk, 0, stream>>>(w_fc2,  (bf16*)wfc2B,  147456);
    wprep_conv_k<<<(331776+255)/256, blk, 0, stream>>>(w_f2,  (bf16*)wf2cB,  331776);
    wprep_conv_k<<<(165888+255)/256, blk, 0, stream>>>(w_sg1, (bf16*)wsg1cB, 165888);
    combine_sp_k<<<192, 128, 0, stream>>>(w_sp_proj, w_spp, b_spp, Wc_spB, bc_sp);
    combine_ch_k<<<192, 64, 0, stream>>>(w_ch_proj, w_chp, b_chp, Wc_ch, bc_ch);
    zerof_k<<<6, blk, 0, stream>>>(mean_sp, 1536);
    zerof_k<<<6, blk, 0, stream>>>(mean_ch, 1536);

    // ---- LN1 stats + full-M qkv GEMM (split store) ----
    ln_stats_k<<<MTOK/4, blk, 0, stream>>>(x, stats);
    gemm_k<1,7,1,192,0,0><<<dim3(3, MTOK/GBM), blk, 0, stream>>>(
        x, wqB, b_qkv, spqkv, MTOK, 576, CCH,
        stats, ln1_g, ln1_b, nullptr,
        (const float*)chqkv, nullptr, nullptr, nullptr);

    // ---- MFMA spatial attention + sp proj (roll store) ----
    sp_attn_k<<<dim3(BATCH*NWIN), dim3(384), 0, stream>>>(spqkv, rpb, logit_sp, osp);
    gemm_k<0,2,1,192,0,0><<<dim3(1, MTOK/GBM), blk, 0, stream>>>(
        osp, (const u16*)Wc_spB, bc_sp, sp_out, MTOK, CCH, 144,
        nullptr, nullptr, nullptr, nullptr,
        nullptr, nullptr, nullptr, nullptr);

    // ---- channel attention: partial gram -> softmax -> fused W -> GEMM ----
    ch_part_k<<<dim3(16, 2, BATCH), blk, 0, stream>>>(chqkv, pgram, pss);
    ch_soft_k<<<dim3(2, BATCH), blk, 0, stream>>>(pgram, pss, logit_ch, attn_b);
    fuse_chw_k<<<BATCH, 192, 0, stream>>>(Wc_ch, attn_b, Wfuse);
    gemm_k<4,0,1,192,0,1><<<dim3(1, MTOK/GBM), blk, 0, stream>>>(
        chqkv, (const u16*)Wfuse, bc_ch, ch_out, MTOK, CCH, 48,
        nullptr, nullptr, nullptr, nullptr,
        nullptr, nullptr, nullptr, nullptr);

    // ---- CFCA means/gates ----
    mean2_k<<<dim3(HW/256, BATCH), blk, 0, stream>>>(sp_out, mean_sp);
    mean2_k<<<dim3(HW/256, BATCH), blk, 0, stream>>>(ch_out, mean_ch);
    gates_k<<<BATCH, 192, 0, stream>>>(mean_sp, w_gs1, w_gs2, b_gs2, gate_s);
    gates_k<<<BATCH, 192, 0, stream>>>(mean_ch, w_gc1, w_gc2, b_gc2, gate_c);

    // ---- CFCA hiddens + gated residual adds ----
    gemm_k<0,1,1,96,0,0><<<dim3(1, MTOK/GBM), blk, 0, stream>>>(
        sp_out, ws2c1B, nullptr, hid_s, MTOK, MIDC, CCH,
        nullptr, nullptr, nullptr, nullptr, nullptr, nullptr, nullptr, nullptr);
    gemm_k<0,1,1,96,0,0><<<dim3(1, MTOK/GBM), blk, 0, stream>>>(
        ch_out, wc2s1B, nullptr, hid_c, MTOK, MIDC, CCH,
        nullptr, nullptr, nullptr, nullptr, nullptr, nullptr, nullptr, nullptr);
    gemm_k<0,4,1,192,0,0><<<dim3(1, MTOK/GBM), blk, 0, stream>>>(
        hid_s, ws2c2B, b_s2c2, ch_out, MTOK, CCH, MIDC,
        nullptr, nullptr, nullptr, nullptr, gate_s, nullptr, nullptr, nullptr);
    gemm_k<0,4,1,192,0,0><<<dim3(1, MTOK/GBM), blk, 0, stream>>>(
        hid_c, wc2s2B, b_c2s2, sp_out, MTOK, CCH, MIDC,
        nullptr, nullptr, nullptr, nullptr, gate_c, nullptr, nullptr, nullptr);

    // ---- f = relu(bn1(concat @ w_f1^T)) -> PADDED fpad ----
    zb_k<<<(8*516*24+255)/256, blk, 0, stream>>>(fpad);
    gemm_k<2,3,1,192,1,0><<<dim3(1, MTOK/GBM), blk, 0, stream>>>(
        sp_out, wf1B, nullptr, fpad, MTOK, CCH, 2*CCH,
        nullptr, nullptr, nullptr, ch_out, bn1_g, bn1_b, bn1_m, bn1_v);

    // ---- f2 = relu(bn2(conv3x3(f))) -> PADDED f2pad ----
    zb_k<<<(8*516*24+255)/256, blk, 0, stream>>>(f2pad);
    gemm_k<3,3,1,192,1,0><<<dim3(1, MTOK/GBM), blk, 0, stream>>>(
        fpad, wf2cB, nullptr, f2pad, MTOK, CCH, 9*CCH,
        nullptr, nullptr, nullptr, nullptr, bn2_g, bn2_b, bn2_m, bn2_v);

    // ---- gpre = conv3x3(f2) (96 ch) ----
    gemm_k<3,0,1,96,0,0><<<dim3(1, MTOK/GBM), blk, 0, stream>>>(
        f2pad, wsg1cB, nullptr, gpre, MTOK, 96, 9*CCH,
        nullptr, nullptr, nullptr, nullptr, nullptr, nullptr, nullptr, nullptr);

    // ---- xnew = x + f2*(1+g) -> d_out ----
    fuse_k<<<MTOK/4, blk, 0, stream>>>(x, f2pad, gpre, w_sg2, b_sg2, out);

    // ---- LN2 + MLP (2 chunks; hidden over dead A0 region) ----
    ln_stats_k<<<MTOK/4, blk, 0, stream>>>(out, stats);
    const int CHM = MTOK / 2;
    for (int c0 = 0; c0 < MTOK; c0 += CHM) {
        gemm_k<1,5,1,192,0,0><<<dim3(4, CHM/GBM), blk, 0, stream>>>(
            out + (size_t)c0*CCH, wfc1B, b_fc1, hidden, CHM, 4*CCH, CCH,
            stats + (size_t)c0*2, ln2_g, ln2_b, nullptr,
            nullptr, nullptr, nullptr, nullptr);
        gemm_k<0,6,0,192,0,0><<<dim3(1, CHM/GBM), blk, 0, stream>>>(
            hidden, wfc2B, b_fc2, out + (size_t)c0*CCH, CHM, CCH, 4*CCH,
            nullptr, nullptr, nullptr, nullptr, out + (size_t)c0*CCH,
            nullptr, nullptr, nullptr);
    }
}

// Round 14
// 1317.458 us; speedup vs baseline: 1.2547x; 1.0139x over previous
//
#include <hip/hip_runtime.h>
#include <hip/hip_bf16.h>
#include <cstddef>

typedef __hip_bfloat16 bf16;
typedef unsigned short u16;
typedef unsigned int u32;
typedef short s16x8 __attribute__((ext_vector_type(8)));
typedef float f32x4 __attribute__((ext_vector_type(4)));

// ---------------- problem constants ----------------
#define BATCH 8
#define HR 128
#define WR 128
#define CCH 192
#define HW (HR*WR)            // 16384
#define MTOK (BATCH*HW)       // 131072
#define SPH 6
#define SPC 432               // spatial qkv channels (heads 0..5)
#define CHC 144               // channel-head qkv channels (heads 6,7)
#define NWIN 256
#define MIDC 48
#define PH 130                // padded conv H/W
#define PHW (PH*PH)           // 16900
#define LOGMAX 4.6051701859880914f

// ---------------- ws layout (BYTE offsets; peak ~193 MB) ----------------
static const size_t OFF_A0    = 0;
static const size_t OFF_B0    = 113246208;
static const size_t OFF_C0    = 150994944;
static const size_t OFF_SMALL = 188743680;
static const size_t SO_STATS  = 0;          // fp32 2*M
static const size_t SO_PGRAM  = 1048576;    // fp32 [8][2][16][576]
static const size_t SO_PSS    = 1638400;    // fp32 [8][2][16][48]
static const size_t SO_ATTNB  = 1687552;    // fp32 [8][2][24][24]
static const size_t SO_MEANSP = 1724416;
static const size_t SO_MEANCH = 1732608;
static const size_t SO_GATES  = 1740800;
static const size_t SO_GATEC  = 1748992;
static const size_t SO_BCSP   = 1757184;    // fp32 192
static const size_t SO_WCCH   = 1758208;    // fp32 192*48
static const size_t SO_BCCH   = 1795072;    // fp32 192
static const size_t SO_WFUSE  = 1796096;    // bf16 [8][192][48]
static const size_t SO_WCSPB  = 1943552;    // bf16 192*144
static const size_t SO_WQB    = 1998848;    // bf16 576*192
static const size_t SO_WS2C1B = 2220032;    // bf16 48*192
static const size_t SO_WC2S1B = 2238464;
static const size_t SO_WS2C2B = 2256896;    // bf16 192*48
static const size_t SO_WC2S2B = 2275328;
static const size_t SO_WF1B   = 2293760;    // bf16 192*384
static const size_t SO_WF2CB  = 2441216;    // bf16 192*1728
static const size_t SO_WSG1CB = 3104768;    // bf16 96*1728
static const size_t SO_WFC1B  = 3436544;    // bf16 768*192
static const size_t SO_WFC2B  = 3731456;    // bf16 192*768

__device__ __forceinline__ float b2f(bf16 x) { return __bfloat162float(x); }
__device__ __forceinline__ bf16  f2b(float x){ return __float2bfloat16(x); }
__device__ __forceinline__ u16   f2u(float x){
    bf16 h = __float2bfloat16(x);
    union { bf16 b; u16 u; } c; c.b = h; return c.u;
}
__device__ __forceinline__ float s2f(short s){
    union { u16 u; bf16 b; } c; c.u = (u16)s; return b2f(c.b);
}
__device__ __forceinline__ float u2f(u16 u){
    union { u16 u; bf16 b; } c; c.u = u; return b2f(c.b);
}
// bijective XCD-aware remap (m204 variant)
__device__ __forceinline__ int xcdswz(int b, int n){
    const int q = n >> 3, r = n & 7, x = b & 7, o = b >> 3;
    return (x < r) ? (x * (q + 1) + o) : (r * (q + 1) + (x - r) * q + o);
}

// =====================================================================
// MFMA bf16 GEMM: double-buffered LDS (1 barrier/K-step), register
// prefetch, LDS-staged vectorized epilogues, XCD-swizzled M-blocks.
// block 256 thr = 4 waves (2x2), tile 128 x BNT, BK=32.
// LDA=40 (80B row stride) -> fragment ds_read_b128 hits all 8 bank-groups.
// AMODE: 0 plain bf16, 1 LN-fused (A fp32 + stats), 2 concat(A|A2 bf16),
//        3 implicit 3x3 conv over PADDED input, 4 V-extract from chqkv
// EPI: 0 bias, 1 relu, 2 roll-store, 3 BN+relu, 4 gated residual,
//      5 gelu, 6 residual add (fp32 ep0, CBF=0, N==BNT), 7 qkv split store
// =====================================================================
#define GBM 128
#define GBK 32
#define LDA 40   // padded LDS row length in ushorts (80 B)

struct SegRaw { union { uint4 v; struct { float4 lo, hi; } f; } d; };

template<int AMODE, int EPI, int CBF, int BNT, int CPAD, int WPB>
__global__ __launch_bounds__(256)
void gemm_k(const void* __restrict__ A, const u16* __restrict__ W,
            const float* __restrict__ bias, void* __restrict__ Cv,
            int M, int N, int K,
            const float* __restrict__ stats, const float* __restrict__ lng,
            const float* __restrict__ lnb, const void* __restrict__ A2,
            const float* __restrict__ ep0, const float* __restrict__ ep1,
            const float* __restrict__ ep2, const float* __restrict__ ep3)
{
    constexpr int NF = BNT / 32;
    constexpr int NB = (BNT * 4 + 255) / 256;
    constexpr int ATILE = GBM * LDA;      // u16 units
    constexpr int BTILE = BNT * LDA;
    constexpr int BUFSZ = ATILE + BTILE;
    constexpr int CST   = BNT + 8;        // padded bf16 C-staging stride (u16)
    __shared__ __align__(16) u16 smem[2 * BUFSZ];  // reused for C staging

    const int tid  = threadIdx.x;
    const int lane = tid & 63;
    const int wid  = tid >> 6;
    const int wm   = (wid >> 1) * 64;
    const int wn   = (wid & 1) * (BNT / 2);
    const int m0   = xcdswz(blockIdx.y, gridDim.y) * GBM;
    const int n0   = blockIdx.x * BNT;
    const int row16 = lane & 15;
    const int hi    = lane >> 4;
    const int koff  = hi * 8;

    const int arow[2] = { tid >> 2, (tid + 256) >> 2 };
    const int akk     = (tid & 3) * 8;

    const u16* Wb = W;
    if constexpr (WPB) Wb = W + (size_t)(m0 >> 14) * 9216;

    float meanA[2], rstdA[2];
    if constexpr (AMODE == 1) {
        #pragma unroll
        for (int it = 0; it < 2; ++it) {
            const int m = m0 + arow[it];
            meanA[it] = stats[2*m]; rstdA[it] = stats[2*m+1];
        }
    }

    f32x4 acc[4][NF];
    #pragma unroll
    for (int mf = 0; mf < 4; ++mf)
        #pragma unroll
        for (int nf = 0; nf < NF; ++nf)
            acc[mf][nf] = (f32x4){0.f, 0.f, 0.f, 0.f};

    const int nsteps = (K + GBK - 1) / GBK;

    auto loadA = [&](int step, SegRaw seg[2]) {
        const int k0 = step * GBK;
        #pragma unroll
        for (int it = 0; it < 2; ++it) {
            const int m = m0 + arow[it];
            const int k = k0 + akk;
            SegRaw& s = seg[it];
            if (k >= K) { s.d.v = (uint4){0u,0u,0u,0u}; continue; }
            if constexpr (AMODE == 0) {
                s.d.v = *(const uint4*)((const u16*)A + (size_t)m * K + k);
            } else if constexpr (AMODE == 1) {
                const float* p = (const float*)A + (size_t)m * K + k;
                s.d.f.lo = *(const float4*)p; s.d.f.hi = *(const float4*)(p+4);
            } else if constexpr (AMODE == 2) {
                const u16* src = (k < CCH) ? (const u16*)A  + (size_t)m * CCH + k
                                           : (const u16*)A2 + (size_t)m * CCH + (k - CCH);
                s.d.v = *(const uint4*)src;
            } else if constexpr (AMODE == 3) {
                const int tap = k / CCH, c = k - tap * CCH;
                const int ky = tap / 3, kx = tap - ky * 3;
                const int b = m >> 14, pix = m & 16383;
                const int h = pix >> 7, w = pix & 127;
                s.d.v = *(const uint4*)((const u16*)A +
                        ((size_t)b * PHW + (size_t)(h + ky) * PH + (w + kx)) * CCH + c);
            } else {
                const int col = (k < 24) ? (48 + k) : (96 + k);
                s.d.v = *(const uint4*)((const u16*)A + (size_t)m * CHC + col);
            }
        }
    };
    auto loadB = [&](int step, SegRaw seg[NB]) {
        const int k0 = step * GBK;
        #pragma unroll
        for (int it = 0; it < NB; ++it) {
            const int s = tid + it * 256;
            const int n = n0 + (s >> 2);
            const int k = k0 + (s & 3) * 8;
            seg[it].d.v = (uint4){0u,0u,0u,0u};
            if (s < BNT*4 && k < K && n < N)
                seg[it].d.v = *(const uint4*)(Wb + (size_t)n * K + k);
        }
    };
    auto writeA = [&](int step, SegRaw seg[2], u16* Ab) {
        const int k0 = step * GBK;
        #pragma unroll
        for (int it = 0; it < 2; ++it) {
            if constexpr (AMODE == 1) {
                const int k = k0 + akk;
                union { u16 u[8]; uint4 v; } pk;
                #pragma unroll
                for (int j = 0; j < 8; ++j) {
                    float xx = (j < 4) ? seg[it].d.f.lo[j] : seg[it].d.f.hi[j-4];
                    xx = (xx - meanA[it]) * rstdA[it] * lng[k+j] + lnb[k+j];
                    pk.u[j] = f2u(xx);
                }
                *(uint4*)&Ab[arow[it] * LDA + akk] = pk.v;
            } else {
                *(uint4*)&Ab[arow[it] * LDA + akk] = seg[it].d.v;
            }
        }
    };
    auto writeB = [&](SegRaw seg[NB], u16* Bb) {
        #pragma unroll
        for (int it = 0; it < NB; ++it) {
            const int s = tid + it * 256;
            if (s < BNT*4)
                *(uint4*)&Bb[(s >> 2) * LDA + (s & 3) * 8] = seg[it].d.v;
        }
    };

    SegRaw segA[2], segB[NB];
    loadA(0, segA); loadB(0, segB);
    writeA(0, segA, smem); writeB(segB, smem + ATILE);
    __syncthreads();

    int cur = 0;
    for (int step = 0; step < nsteps; ++step) {
        const bool more = (step + 1 < nsteps);
        if (more) { loadA(step+1, segA); loadB(step+1, segB); }
        u16* Ab = smem + cur * BUFSZ;
        u16* Bb = Ab + ATILE;
        s16x8 af[4], bfr[NF];
        #pragma unroll
        for (int mf = 0; mf < 4; ++mf)
            af[mf] = *(const s16x8*)&Ab[(wm + mf*16 + row16) * LDA + koff];
        #pragma unroll
        for (int nf = 0; nf < NF; ++nf)
            bfr[nf] = *(const s16x8*)&Bb[(wn + nf*16 + row16) * LDA + koff];
        __builtin_amdgcn_s_setprio(1);
        #pragma unroll
        for (int mf = 0; mf < 4; ++mf)
            #pragma unroll
            for (int nf = 0; nf < NF; ++nf)
                acc[mf][nf] = __builtin_amdgcn_mfma_f32_16x16x32_bf16(
                    af[mf], bfr[nf], acc[mf][nf], 0, 0, 0);
        __builtin_amdgcn_s_setprio(0);
        if (more) {
            u16* An = smem + (cur ^ 1) * BUFSZ;
            writeA(step+1, segA, An); writeB(segB, An + ATILE);
        }
        __syncthreads();
        cur ^= 1;
    }

    // ================= epilogue =================
    if constexpr (CBF == 1) {
        // ---- stage bf16 C tile into LDS (padded stride CST) ----
        #pragma unroll
        for (int mf = 0; mf < 4; ++mf) {
            #pragma unroll
            for (int nf = 0; nf < NF; ++nf) {
                const int n = n0 + wn + nf*16 + row16;
                #pragma unroll
                for (int r = 0; r < 4; ++r) {
                    const int m_loc = wm + mf*16 + hi*4 + r;
                    float v = acc[mf][nf][r];
                    if (n < N) {
                        v += (bias ? bias[n] : 0.f);
                        if constexpr (EPI == 1) {
                            v = fmaxf(v, 0.f);
                        } else if constexpr (EPI == 3) {
                            v = (v - ep2[n]) * rsqrtf(ep3[n] + 1e-5f) * ep0[n] + ep1[n];
                            v = fmaxf(v, 0.f);
                        } else if constexpr (EPI == 4) {
                            const int b = (m0 + m_loc) >> 14;
                            v = v * ep0[b * N + n];
                        } else if constexpr (EPI == 5) {
                            v = 0.5f * v * (1.f + erff(v * 0.70710678118654752f));
                        }
                    }
                    smem[m_loc * CST + (wn + nf*16 + row16)] = f2u(v);
                }
            }
        }
        __syncthreads();
        // ---- vectorized store: 8 bf16 (16B) per task ----
        constexpr int CHUNKS = BNT / 8;
        constexpr int TASKS  = GBM * CHUNKS / 256;
        #pragma unroll
        for (int t2 = 0; t2 < TASKS; ++t2) {
            const int task  = tid + t2 * 256;
            const int rloc  = task / CHUNKS;
            const int chunk = task - rloc * CHUNKS;
            const int m  = m0 + rloc;
            const int nn = n0 + chunk * 8;
            if (nn >= N) continue;
            uint4 val = *(const uint4*)&smem[rloc * CST + chunk * 8];
            if constexpr (EPI == 7) {
                if (nn < SPC) {
                    *(uint4*)((u16*)Cv + (size_t)m * SPC + nn) = val;
                } else {
                    u16* chq = (u16*)ep0;
                    *(uint4*)(chq + (size_t)m * CHC + (nn - SPC)) = val;
                }
                continue;
            }
            size_t outIdx;
            if constexpr (CPAD == 1) {
                const int b = m >> 14, pix = m & 16383;
                const int h = pix >> 7, w = pix & 127;
                outIdx = ((size_t)b * PHW + (size_t)(h+1) * PH + (w+1)) * (size_t)N + nn;
            } else if constexpr (EPI == 2) {
                const int b = m >> 14, pix = m & 16383;
                const int h2 = ((pix >> 7) + 4) & 127;
                const int w2 = ((pix & 127) + 4) & 127;
                outIdx = ((size_t)(b * HW) + h2 * WR + w2) * (size_t)N + nn;
            } else {
                outIdx = (size_t)m * N + nn;
            }
            if constexpr (EPI == 4) {
                union { uint4 v; u16 u[8]; } sv, ov;
                sv.v = val;
                ov.v = *(const uint4*)((const u16*)Cv + outIdx);
                #pragma unroll
                for (int j = 0; j < 8; ++j)
                    sv.u[j] = f2u(u2f(ov.u[j]) + u2f(sv.u[j]));
                *(uint4*)((u16*)Cv + outIdx) = sv.v;
            } else {
                *(uint4*)((u16*)Cv + outIdx) = val;
            }
        }
    } else {
        // ---- fp32 path (fc2, EPI6, N==BNT): LDS-staged float4 stores,
        //      32-row quarters, stride BNT+16 (2-way-free banks) ----
        float* fs = (float*)smem;
        constexpr int FST = BNT + 16;
        #pragma unroll
        for (int q = 0; q < 4; ++q) {
            __syncthreads();
            if ((wid >> 1) == (q >> 1)) {
                #pragma unroll
                for (int mfi = 0; mfi < 2; ++mfi) {
                    const int mf = (q & 1) * 2 + mfi;
                    #pragma unroll
                    for (int nf = 0; nf < NF; ++nf) {
                        const int n = wn + nf*16 + row16;
                        #pragma unroll
                        for (int r = 0; r < 4; ++r) {
                            const int mloc = mfi*16 + hi*4 + r;   // 0..31
                            fs[mloc * FST + n] = acc[mf][nf][r] + (bias ? bias[n0 + n] : 0.f);
                        }
                    }
                }
            }
            __syncthreads();
            const int TOT = 32 * (BNT/4);
            for (int task = tid; task < TOT; task += 256) {
                const int rloc = task / (BNT/4);
                const int cc = (task - rloc*(BNT/4)) * 4;
                const int m = m0 + q*32 + rloc;
                const int nn = n0 + cc;
                if (nn >= N) continue;
                float4 v4 = *(const float4*)&fs[rloc*FST + cc];
                const size_t oi = (size_t)m * N + nn;
                if constexpr (EPI == 6) {
                    const float4 o4 = *(const float4*)&ep0[oi];
                    v4.x += o4.x; v4.y += o4.y; v4.z += o4.z; v4.w += o4.w;
                }
                *(float4*)&((float*)Cv)[oi] = v4;
            }
        }
    }
}

// =====================================================================
// weight prep
// =====================================================================
__global__ __launch_bounds__(256)
void wprep_lin_k(const float* __restrict__ in, bf16* __restrict__ outb, int n)
{
    const int i = blockIdx.x * 256 + threadIdx.x;
    if (i < n) outb[i] = f2b(in[i]);
}

__global__ __launch_bounds__(256)
void wprep_conv_k(const float* __restrict__ in, bf16* __restrict__ outb, int total)
{
    const int i = blockIdx.x * 256 + threadIdx.x;
    if (i >= total) return;
    const int n = i / 1728, r = i - n * 1728;
    const int tap = r / CCH, c = r - tap * CCH;
    outb[i] = f2b(in[((size_t)n * CCH + c) * 9 + tap]);
}

__global__ __launch_bounds__(256)
void zb_k(bf16* __restrict__ buf)
{
    const int i = blockIdx.x * 256 + threadIdx.x;
    if (i >= 8 * 516 * 24) return;
    const int chunk = i % 24;
    const int p = (i / 24) % 516;
    const int b = i / (24 * 516);
    int h, w;
    if (p < 130)      { h = 0;   w = p; }
    else if (p < 260) { h = 129; w = p - 130; }
    else { const int q = p - 260; h = 1 + (q >> 1); w = (q & 1) ? 129 : 0; }
    *(uint4*)((u16*)buf + ((size_t)b * PHW + (size_t)h * PH + w) * CCH + chunk * 8)
        = (uint4){0u,0u,0u,0u};
}

__global__ __launch_bounds__(256)
void zerof_k(float* __restrict__ p, int n)
{
    const int i = blockIdx.x * 256 + threadIdx.x;
    if (i < n) p[i] = 0.f;
}

// =====================================================================
// LN stats (used only for LN1; LN2 stats are fused into fuse_k)
// =====================================================================
__global__ __launch_bounds__(256)
void ln_stats_k(const float* __restrict__ x, float* __restrict__ stats)
{
    const int tok = blockIdx.x * 4 + (threadIdx.x >> 6);
    const int lane = threadIdx.x & 63;
    const float* r = x + (size_t)tok * CCH;
    float s = 0.f, sq = 0.f;
    for (int c = lane; c < CCH; c += 64) { float v = r[c]; s += v; sq += v*v; }
    for (int m = 1; m < 64; m <<= 1) { s += __shfl_xor(s, m); sq += __shfl_xor(sq, m); }
    if (lane == 0) {
        const float mean = s / (float)CCH;
        const float var = sq / (float)CCH - mean * mean;
        stats[(size_t)tok*2]   = mean;
        stats[(size_t)tok*2+1] = rsqrtf(var + 1e-5f);
    }
}

// =====================================================================
// MFMA spatial shifted-window cosine attention (6 waves = 6 heads/window)
// =====================================================================
__global__ __launch_bounds__(384)
void sp_attn_k(const bf16* __restrict__ spqkv, const float* __restrict__ rpb,
               const float* __restrict__ logit_sp, bf16* __restrict__ osp)
{
    const int b    = blockIdx.x >> 8;
    const int win  = blockIdx.x & 255;
    const int wh = win >> 4, ww = win & 15;
    const int head = threadIdx.x >> 6;
    const int lane = threadIdx.x & 63;
    const int row16 = lane & 15;
    const int hi   = lane >> 4;
    const int koff = hi * 8;

    __shared__ float rpbS[1350];
    __shared__ u16 vT[SPH][32][72];

    for (int i = threadIdx.x; i < 1350; i += 384) rpbS[i] = rpb[i];

    const u16* base = (const u16*)spqkv + (size_t)b * HW * SPC;

    s16x8 qf[4], kf[4];
    const int wcol = (ww*8 + (row16 & 7) + 4) & 127;
    #pragma unroll
    for (int t = 0; t < 4; ++t) {
        const int pos = t*16 + row16;
        const int h = (wh*8 + (pos >> 3) + 4) & 127;
        const u16* rowp = base + ((size_t)(h * WR + wcol)) * SPC + head * 72;
        if (koff < 24) {
            qf[t] = *(const s16x8*)(rowp + koff);
            kf[t] = *(const s16x8*)(rowp + 24 + koff);
        } else {
            qf[t] = (s16x8){0,0,0,0,0,0,0,0};
            kf[t] = (s16x8){0,0,0,0,0,0,0,0};
        }
    }

    {
        const int h = (wh*8 + (lane >> 3) + 4) & 127;
        const int w = (ww*8 + (lane & 7) + 4) & 127;
        const u16* vrow = base + ((size_t)(h * WR + w)) * SPC + head * 72 + 48;
        union { uint4 v; u16 u[8]; } seg[3];
        seg[0].v = *(const uint4*)(vrow);
        seg[1].v = *(const uint4*)(vrow + 8);
        seg[2].v = *(const uint4*)(vrow + 16);
        #pragma unroll
        for (int d = 0; d < 24; ++d) vT[head][d][lane] = seg[d>>3].u[d&7];
        #pragma unroll
        for (int d = 24; d < 32; ++d) vT[head][d][lane] = 0;
    }
    __syncthreads();

    float rq[4], rk[4];
    #pragma unroll
    for (int t = 0; t < 4; ++t) {
        float sq = 0.f, sk = 0.f;
        #pragma unroll
        for (int e = 0; e < 8; ++e) {
            const float a = s2f(qf[t][e]); sq += a*a;
            const float c = s2f(kf[t][e]); sk += c*c;
        }
        sq += __shfl_xor(sq, 16); sq += __shfl_xor(sq, 32);
        sk += __shfl_xor(sk, 16); sk += __shfl_xor(sk, 32);
        rq[t] = 1.f / fmaxf(sqrtf(sq), 1e-12f);
        rk[t] = 1.f / fmaxf(sqrtf(sk), 1e-12f);
    }
    const float scale_h = __expf(fminf(logit_sp[head], LOGMAX));

    f32x4 acc[4][4];
    #pragma unroll
    for (int mfk = 0; mfk < 4; ++mfk)
        #pragma unroll
        for (int nfq = 0; nfq < 4; ++nfq)
            acc[mfk][nfq] = (f32x4){0.f,0.f,0.f,0.f};
    #pragma unroll
    for (int mfk = 0; mfk < 4; ++mfk)
        #pragma unroll
        for (int nfq = 0; nfq < 4; ++nfq)
            acc[mfk][nfq] = __builtin_amdgcn_mfma_f32_16x16x32_bf16(
                kf[mfk], qf[nfq], acc[mfk][nfq], 0, 0, 0);

    f32x4 rkj[4];
    #pragma unroll
    for (int mfk = 0; mfk < 4; ++mfk)
        #pragma unroll
        for (int r = 0; r < 4; ++r)
            rkj[mfk][r] = __shfl(rk[mfk], hi*4 + r);

    int ip3[4], iw7[4], labi[4];
    #pragma unroll
    for (int t = 0; t < 4; ++t) {
        const int pos = t*16 + row16;
        ip3[t] = pos >> 3; iw7[t] = pos & 7;
        const int hh = wh*8 + ip3[t], w0 = ww*8 + iw7[t];
        const int rh = hh < 120 ? 0 : (hh < 124 ? 1 : 2);
        const int rw = w0 < 120 ? 0 : (w0 < 124 ? 1 : 2);
        labi[t] = rh*3 + rw;
    }

    #pragma unroll
    for (int mfk = 0; mfk < 4; ++mfk) {
        #pragma unroll
        for (int r = 0; r < 4; ++r) {
            const int j = hi*4 + r + 16*mfk;
            const int jp3 = j >> 3, jw7 = j & 7;
            const int hh = wh*8 + jp3, w0 = ww*8 + jw7;
            const int rh = hh < 120 ? 0 : (hh < 124 ? 1 : 2);
            const int rw = w0 < 120 ? 0 : (w0 < 124 ? 1 : 2);
            const int labj = rh*3 + rw;
            const float rkv = rkj[mfk][r];
            #pragma unroll
            for (int nfq = 0; nfq < 4; ++nfq) {
                float s = acc[mfk][nfq][r] * rq[nfq] * rkv * scale_h;
                s += rpbS[((ip3[nfq]-jp3+7)*15 + (iw7[nfq]-jw7+7))*SPH + head];
                if (labi[nfq] != labj) s -= 100.f;
                acc[mfk][nfq][r] = s;
            }
        }
    }

    float inv[4];
    #pragma unroll
    for (int nfq = 0; nfq < 4; ++nfq) {
        float m = -1e30f;
        #pragma unroll
        for (int mfk = 0; mfk < 4; ++mfk)
            #pragma unroll
            for (int r = 0; r < 4; ++r)
                m = fmaxf(m, acc[mfk][nfq][r]);
        m = fmaxf(m, __shfl_xor(m, 16));
        m = fmaxf(m, __shfl_xor(m, 32));
        float s = 0.f;
        #pragma unroll
        for (int mfk = 0; mfk < 4; ++mfk)
            #pragma unroll
            for (int r = 0; r < 4; ++r) {
                const float p = __expf(acc[mfk][nfq][r] - m);
                acc[mfk][nfq][r] = p;
                s += p;
            }
        s += __shfl_xor(s, 16);
        s += __shfl_xor(s, 32);
        inv[nfq] = 1.f / s;
    }

    u32 pk01[4][4], pk23[4][4];
    #pragma unroll
    for (int mfk = 0; mfk < 4; ++mfk)
        #pragma unroll
        for (int nfq = 0; nfq < 4; ++nfq) {
            pk01[mfk][nfq] = (u32)f2u(acc[mfk][nfq][0] * inv[nfq])
                           | ((u32)f2u(acc[mfk][nfq][1] * inv[nfq]) << 16);
            pk23[mfk][nfq] = (u32)f2u(acc[mfk][nfq][2] * inv[nfq])
                           | ((u32)f2u(acc[mfk][nfq][3] * inv[nfq]) << 16);
        }

    s16x8 vf[2][2];
    #pragma unroll
    for (int nf = 0; nf < 2; ++nf)
        #pragma unroll
        for (int ks = 0; ks < 2; ++ks)
            vf[nf][ks] = *(const s16x8*)&vT[head][row16 + 16*nf][32*ks + koff];

    f32x4 accO[4][2];
    #pragma unroll
    for (int MF = 0; MF < 4; ++MF)
        #pragma unroll
        for (int nf = 0; nf < 2; ++nf)
            accO[MF][nf] = (f32x4){0.f,0.f,0.f,0.f};

    const int g0 = 2*(hi & 1);
    const int src0 = g0*16 + row16, src1 = src0 + 16;
    const bool selhi = (hi >> 1) != 0;
    #pragma unroll
    for (int ks = 0; ks < 2; ++ks) {
        #pragma unroll
        for (int MF = 0; MF < 4; ++MF) {
            const u32 e01a = __shfl(pk01[2*ks][MF],   src0);
            const u32 e01b = __shfl(pk01[2*ks+1][MF], src0);
            const u32 e23a = __shfl(pk23[2*ks][MF],   src0);
            const u32 e23b = __shfl(pk23[2*ks+1][MF], src0);
            const u32 e45a = __shfl(pk01[2*ks][MF],   src1);
            const u32 e45b = __shfl(pk01[2*ks+1][MF], src1);
            const u32 e67a = __shfl(pk23[2*ks][MF],   src1);
            const u32 e67b = __shfl(pk23[2*ks+1][MF], src1);
            union { u32 w[4]; s16x8 v; } af;
            af.w[0] = selhi ? e01b : e01a;
            af.w[1] = selhi ? e23b : e23a;
            af.w[2] = selhi ? e45b : e45a;
            af.w[3] = selhi ? e67b : e67a;
            accO[MF][0] = __builtin_amdgcn_mfma_f32_16x16x32_bf16(
                af.v, vf[0][ks], accO[MF][0], 0, 0, 0);
            accO[MF][1] = __builtin_amdgcn_mfma_f32_16x16x32_bf16(
                af.v, vf[1][ks], accO[MF][1], 0, 0, 0);
        }
    }

    #pragma unroll
    for (int MF = 0; MF < 4; ++MF) {
        #pragma unroll
        for (int nf = 0; nf < 2; ++nf) {
            const int d = row16 + 16*nf;
            if (d >= 24) continue;
            #pragma unroll
            for (int r = 0; r < 4; ++r) {
                const int qrow = hi*4 + r + 16*MF;
                const int h = wh*8 + (qrow >> 3);
                const int w = ww*8 + (qrow & 7);
                osp[((size_t)b*HW + h*WR + w)*144 + head*24 + d] = f2b(accO[MF][nf][r]);
            }
        }
    }
}

// =====================================================================
// Channel attention: partial gram + column sum-squares, softmax, W-fuse
// =====================================================================
__global__ __launch_bounds__(256)
void ch_part_k(const bf16* __restrict__ chqkv, float* __restrict__ pgram,
               float* __restrict__ pss)
{
    const int ci = blockIdx.x, head = blockIdx.y, b = blockIdx.z;
    const int tid = threadIdx.x;
    __shared__ u16 tile[256][48];
    float g[3] = {0.f, 0.f, 0.f};
    float ss = 0.f;
    const u16* src = (const u16*)chqkv + (size_t)b * HW * CHC + head * 72;
    const int rbase = ci * 1024;

    for (int t0 = 0; t0 < 1024; t0 += 256) {
        __syncthreads();
        for (int idx = tid; idx < 256*6; idx += 256) {
            const int row = idx / 6, seg = idx - (idx/6)*6;
            *(uint4*)&tile[row][seg*8] =
                *(const uint4*)(src + (size_t)(rbase + t0 + row) * CHC + seg*8);
        }
        __syncthreads();
        #pragma unroll
        for (int i = 0; i < 3; ++i) {
            const int e = tid + i*256;
            if (e < 576) {
                const int c = e / 24, d = e - (e/24)*24;
                float s = 0.f;
                for (int r = 0; r < 256; ++r)
                    s += b2f(*(const bf16*)&tile[r][c]) * b2f(*(const bf16*)&tile[r][24+d]);
                g[i] += s;
            }
        }
        if (tid < 48) {
            float s = 0.f;
            for (int r = 0; r < 256; ++r) { const float v = b2f(*(const bf16*)&tile[r][tid]); s += v*v; }
            ss += s;
        }
    }
    float* pg = pgram + ((size_t)(b*2+head)*16 + ci) * 576;
    #pragma unroll
    for (int i = 0; i < 3; ++i) { const int e = tid + i*256; if (e < 576) pg[e] = g[i]; }
    if (tid < 48) pss[((size_t)(b*2+head)*16 + ci) * 48 + tid] = ss;
}

__global__ __launch_bounds__(256)
void ch_soft_k(const float* __restrict__ pgram, const float* __restrict__ pss,
               const float* __restrict__ logit_ch, float* __restrict__ attn)
{
    const int head = blockIdx.x, b = blockIdx.y;
    const int tid = threadIdx.x;
    __shared__ float gs[576], rn[48];
    for (int e = tid; e < 576; e += 256) {
        float s = 0.f;
        const float* pg = pgram + (size_t)(b*2+head)*16*576 + e;
        for (int c = 0; c < 16; ++c) s += pg[c*576];
        gs[e] = s;
    }
    if (tid < 48) {
        float s = 0.f;
        const float* ps = pss + (size_t)(b*2+head)*16*48 + tid;
        for (int c = 0; c < 16; ++c) s += ps[c*48];
        rn[tid] = 1.f / fmaxf(sqrtf(s), 1e-12f);
    }
    __syncthreads();
    if (tid < 24) {
        const float scale = expf(fminf(logit_ch[head], LOGMAX));
        float vals[24], mx = -1e30f;
        #pragma unroll
        for (int d = 0; d < 24; ++d) {
            vals[d] = gs[tid*24+d] * rn[tid] * rn[24+d] * scale;
            mx = fmaxf(mx, vals[d]);
        }
        float sum = 0.f;
        #pragma unroll
        for (int d = 0; d < 24; ++d) { vals[d] = expf(vals[d]-mx); sum += vals[d]; }
        const float inv = 1.f / sum;
        float* o = attn + ((size_t)(b*2+head)*24 + tid)*24;
        #pragma unroll
        for (int d = 0; d < 24; ++d) o[d] = vals[d]*inv;
    }
}

__global__ __launch_bounds__(192)
void fuse_chw_k(const float* __restrict__ Wc, const float* __restrict__ attn,
                bf16* __restrict__ Wf)
{
    const int b = blockIdx.x;
    const int n = threadIdx.x;
    __shared__ float As_[2][24][24];
    for (int e = n; e < 1152; e += 192) {
        const int h = e / 576, r = e - h*576;
        As_[h][r/24][r%24] = attn[(size_t)b*1152 + e];
    }
    __syncthreads();
    const float* wr = Wc + n*48;
    bf16* o = Wf + ((size_t)b*192 + n) * 48;
    for (int h = 0; h < 2; ++h)
        for (int d = 0; d < 24; ++d) {
            float s = 0.f;
            #pragma unroll
            for (int cc = 0; cc < 24; ++cc) s += wr[h*24+cc] * As_[h][cc][d];
            o[h*24+d] = f2b(s);
        }
}

// =====================================================================
// weight combiners
// =====================================================================
__global__ void combine_sp_k(const float* __restrict__ w_sp_proj, const float* __restrict__ w_spp,
                             const float* __restrict__ b_spp, bf16* __restrict__ Wc, float* __restrict__ bc)
{
    const int n = blockIdx.x;
    for (int i = threadIdx.x; i < 144; i += blockDim.x) {
        float s = 0.f;
        for (int j = 0; j < 144; ++j) s += w_sp_proj[n*144 + j] * w_spp[j*144 + i];
        Wc[n*144 + i] = f2b(s);
    }
    if (threadIdx.x == 0) {
        float s = 0.f;
        for (int j = 0; j < 144; ++j) s += w_sp_proj[n*144 + j] * b_spp[j];
        bc[n] = s;
    }
}

__global__ void combine_ch_k(const float* __restrict__ w_ch_proj, const float* __restrict__ w_chp,
                             const float* __restrict__ b_chp, float* __restrict__ Wc, float* __restrict__ bc)
{
    const int n = blockIdx.x;
    for (int c = threadIdx.x; c < 48; c += blockDim.x) {
        float s = 0.f;
        for (int j = 0; j < 48; ++j) s += w_ch_proj[n*48 + j] * w_chp[j*48 + c];
        Wc[n*48 + c] = s;
    }
    if (threadIdx.x == 0) {
        float s = 0.f;
        for (int j = 0; j < 48; ++j) s += w_ch_proj[n*48 + j] * b_chp[j];
        bc[n] = s;
    }
}

// =====================================================================
// coalesced per-(b,c) SUM over H,W (bf16 src), atomic accumulate
// =====================================================================
__global__ __launch_bounds__(256)
void mean2_k(const bf16* __restrict__ src, float* __restrict__ dst)
{
    const int b = blockIdx.y;
    const int r0 = blockIdx.x * 256;
    const int t = threadIdx.x;
    const int chunk = t & 31;
    const int rg = t >> 5;
    float acc[8] = {0.f,0.f,0.f,0.f,0.f,0.f,0.f,0.f};
    if (chunk < 24) {
        for (int r = rg; r < 256; r += 8) {
            const u16* p = (const u16*)src + ((size_t)(b*HW) + r0 + r) * CCH + chunk*8;
            union { uint4 v; u16 u[8]; } s; s.v = *(const uint4*)p;
            #pragma unroll
            for (int j = 0; j < 8; ++j) acc[j] += u2f(s.u[j]);
        }
    }
    __shared__ float red[8][24][8];
    if (chunk < 24) {
        #pragma unroll
        for (int j = 0; j < 8; ++j) red[rg][chunk][j] = acc[j];
    }
    __syncthreads();
    if (t < 192) {
        const int ch = t >> 3, j = t & 7;
        float s = 0.f;
        #pragma unroll
        for (int g = 0; g < 8; ++g) s += red[g][ch][j];
        atomicAdd(&dst[b*CCH + ch*8 + j], s);
    }
}

// gate = sigmoid(relu((sum/HW) @ w1^T) @ w2^T + b2)
__global__ __launch_bounds__(192)
void gates_k(const float* __restrict__ sumv, const float* __restrict__ w1,
             const float* __restrict__ w2, const float* __restrict__ b2,
             float* __restrict__ gate)
{
    const int b = blockIdx.x;
    __shared__ float mv[192], hid[48];
    const int t = threadIdx.x;
    mv[t] = sumv[b*CCH + t] * (1.f / (float)HW);
    __syncthreads();
    if (t < 48) {
        float s = 0.f;
        for (int c = 0; c < 192; ++c) s += w1[t*192 + c] * mv[c];
        hid[t] = fmaxf(s, 0.f);
    }
    __syncthreads();
    float s = b2[t];
    for (int j = 0; j < 48; ++j) s += hid[j] * w2[t*48 + j];
    gate[b*CCH + t] = 1.f / (1.f + expf(-s));
}

// =====================================================================
// out = x + f2(padded) * (1 + sigmoid(relu(gpre)@w_sg2 + b))
// + fused LN2 stats (bit-identical to ln_stats_k on `out`)
// =====================================================================
__global__ __launch_bounds__(256)
void fuse_k(const float* __restrict__ x, const bf16* __restrict__ f2pad,
            const bf16* __restrict__ gpre, const float* __restrict__ w_sg2,
            const float* __restrict__ b_sg2, float* __restrict__ out,
            float* __restrict__ stats)
{
    const int pix = blockIdx.x * 4 + (threadIdx.x >> 6);
    const int lane = threadIdx.x & 63;
    const bf16* gp = gpre + (size_t)pix * 96;
    float s = fmaxf(b2f(gp[lane]), 0.f) * w_sg2[lane];
    if (lane < 32) s += fmaxf(b2f(gp[lane + 64]), 0.f) * w_sg2[lane + 64];
    for (int m = 1; m < 64; m <<= 1) s += __shfl_xor(s, m);
    const float g1 = 1.f + 1.f / (1.f + expf(-(s + b_sg2[0])));
    const int b = pix >> 14, p = pix & 16383;
    const int h = p >> 7, w = p & 127;
    const bf16* fr = f2pad + ((size_t)b * PHW + (size_t)(h+1) * PH + (w+1)) * CCH;
    const float* xr = x + (size_t)pix * CCH;
    float* orow = out + (size_t)pix * CCH;
    float ssum = 0.f, ssq = 0.f;
    for (int c = lane; c < CCH; c += 64) {
        const float o = xr[c] + b2f(fr[c]) * g1;
        orow[c] = o;
        ssum += o; ssq += o * o;
    }
    for (int m = 1; m < 64; m <<= 1) {
        ssum += __shfl_xor(ssum, m);
        ssq  += __shfl_xor(ssq, m);
    }
    if (lane == 0) {
        const float mean = ssum / (float)CCH;
        const float var  = ssq / (float)CCH - mean * mean;
        stats[(size_t)pix*2]   = mean;
        stats[(size_t)pix*2+1] = rsqrtf(var + 1e-5f);
    }
}

// =====================================================================
// launcher
// =====================================================================
extern "C" void kernel_launch(void* const* d_in, const int* in_sizes, int n_in,
                              void* d_out, int out_size, void* d_ws, size_t ws_size,
                              hipStream_t stream)
{
    const float* x        = (const float*)d_in[0];
    const float* ln1_g    = (const float*)d_in[1];
    const float* ln1_b    = (const float*)d_in[2];
    const float* w_qkv    = (const float*)d_in[3];
    const float* b_qkv    = (const float*)d_in[4];
    const float* logit_sp = (const float*)d_in[5];
    const float* rpb      = (const float*)d_in[6];
    const float* w_spp    = (const float*)d_in[7];
    const float* b_spp    = (const float*)d_in[8];
    const float* logit_ch = (const float*)d_in[9];
    const float* w_chp    = (const float*)d_in[10];
    const float* b_chp    = (const float*)d_in[11];
    const float* w_sp_proj= (const float*)d_in[12];
    const float* w_ch_proj= (const float*)d_in[13];
    const float* w_s2c1   = (const float*)d_in[14];
    const float* w_s2c2   = (const float*)d_in[15];
    const float* b_s2c2   = (const float*)d_in[16];
    const float* w_c2s1   = (const float*)d_in[17];
    const float* w_c2s2   = (const float*)d_in[18];
    const float* b_c2s2   = (const float*)d_in[19];
    const float* w_gs1    = (const float*)d_in[20];
    const float* w_gs2    = (const float*)d_in[21];
    const float* b_gs2    = (const float*)d_in[22];
    const float* w_gc1    = (const float*)d_in[23];
    const float* w_gc2    = (const float*)d_in[24];
    const float* b_gc2    = (const float*)d_in[25];
    const float* w_f1     = (const float*)d_in[26];
    const float* bn1_g    = (const float*)d_in[27];
    const float* bn1_b    = (const float*)d_in[28];
    const float* bn1_m    = (const float*)d_in[29];
    const float* bn1_v    = (const float*)d_in[30];
    const float* w_f2     = (const float*)d_in[31];
    const float* bn2_g    = (const float*)d_in[32];
    const float* bn2_b    = (const float*)d_in[33];
    const float* bn2_m    = (const float*)d_in[34];
    const float* bn2_v    = (const float*)d_in[35];
    const float* w_sg1    = (const float*)d_in[36];
    const float* w_sg2    = (const float*)d_in[37];
    const float* b_sg2    = (const float*)d_in[38];
    const float* ln2_g    = (const float*)d_in[39];
    const float* ln2_b    = (const float*)d_in[40];
    const float* w_fc1    = (const float*)d_in[41];
    const float* b_fc1    = (const float*)d_in[42];
    const float* w_fc2    = (const float*)d_in[43];
    const float* b_fc2    = (const float*)d_in[44];

    char* wsb = (char*)d_ws;
    char* sm  = wsb + OFF_SMALL;
    float* out = (float*)d_out;

    bf16*  spqkv  = (bf16*)(wsb + OFF_A0);
    bf16*  sp_out = (bf16*)(wsb + OFF_A0);
    bf16*  ch_out = (bf16*)(wsb + OFF_A0 + 50331648);
    bf16*  f2pad  = (bf16*)(wsb + OFF_A0);
    bf16*  gpre   = (bf16*)(wsb + OFF_A0 + 51916800);
    bf16*  chqkv  = (bf16*)(wsb + OFF_B0);
    bf16*  hid_s  = (bf16*)(wsb + OFF_B0);
    bf16*  hid_c  = (bf16*)(wsb + OFF_B0 + 12582912);
    bf16*  fpad   = (bf16*)(wsb + OFF_B0);
    bf16*  hidden = (bf16*)(wsb + OFF_A0);   // fc1 out: A0 dead after fuse_k
    bf16*  osp    = (bf16*)(wsb + OFF_C0);

    float* stats  = (float*)(sm + SO_STATS);
    float* pgram  = (float*)(sm + SO_PGRAM);
    float* pss    = (float*)(sm + SO_PSS);
    float* attn_b = (float*)(sm + SO_ATTNB);
    float* mean_sp= (float*)(sm + SO_MEANSP);
    float* mean_ch= (float*)(sm + SO_MEANCH);
    float* gate_s = (float*)(sm + SO_GATES);
    float* gate_c = (float*)(sm + SO_GATEC);
    float* bc_sp  = (float*)(sm + SO_BCSP);
    float* Wc_ch  = (float*)(sm + SO_WCCH);
    float* bc_ch  = (float*)(sm + SO_BCCH);
    bf16*  Wfuse  = (bf16*)(sm + SO_WFUSE);
    bf16*  Wc_spB = (bf16*)(sm + SO_WCSPB);
    u16*   wqB    = (u16*)(sm + SO_WQB);
    u16*   ws2c1B = (u16*)(sm + SO_WS2C1B);
    u16*   wc2s1B = (u16*)(sm + SO_WC2S1B);
    u16*   ws2c2B = (u16*)(sm + SO_WS2C2B);
    u16*   wc2s2B = (u16*)(sm + SO_WC2S2B);
    u16*   wf1B   = (u16*)(sm + SO_WF1B);
    u16*   wf2cB  = (u16*)(sm + SO_WF2CB);
    u16*   wsg1cB = (u16*)(sm + SO_WSG1CB);
    u16*   wfc1B  = (u16*)(sm + SO_WFC1B);
    u16*   wfc2B  = (u16*)(sm + SO_WFC2B);

    const dim3 blk(256);

    // ---- weight prep ----
    wprep_lin_k<<<(110592+255)/256, blk, 0, stream>>>(w_qkv,  (bf16*)wqB,    110592);
    wprep_lin_k<<<(9216+255)/256,   blk, 0, stream>>>(w_s2c1, (bf16*)ws2c1B, 9216);
    wprep_lin_k<<<(9216+255)/256,   blk, 0, stream>>>(w_c2s1, (bf16*)wc2s1B, 9216);
    wprep_lin_k<<<(9216+255)/256,   blk, 0, stream>>>(w_s2c2, (bf16*)ws2c2B, 9216);
    wprep_lin_k<<<(9216+255)/256,   blk, 0, stream>>>(w_c2s2, (bf16*)wc2s2B, 9216);
    wprep_lin_k<<<(73728+255)/256,  blk, 0, stream>>>(w_f1,   (bf16*)wf1B,   73728);
    wprep_lin_k<<<(147456+255)/256, blk, 0, stream>>>(w_fc1,  (bf16*)wfc1B,  147456);
    wprep_lin_k<<<(147456+255)/256, blk, 0, stream>>>(w_fc2,  (bf16*)wfc2B,  147456);
    wprep_conv_k<<<(331776+255)/256, blk, 0, stream>>>(w_f2,  (bf16*)wf2cB,  331776);
    wprep_conv_k<<<(165888+255)/256, blk, 0, stream>>>(w_sg1, (bf16*)wsg1cB, 165888);
    combine_sp_k<<<192, 128, 0, stream>>>(w_sp_proj, w_spp, b_spp, Wc_spB, bc_sp);
    combine_ch_k<<<192, 64, 0, stream>>>(w_ch_proj, w_chp, b_chp, Wc_ch, bc_ch);
    zerof_k<<<6, blk, 0, stream>>>(mean_sp, 1536);
    zerof_k<<<6, blk, 0, stream>>>(mean_ch, 1536);

    // ---- LN1 stats + full-M qkv GEMM (split store) ----
    ln_stats_k<<<MTOK/4, blk, 0, stream>>>(x, stats);
    gemm_k<1,7,1,192,0,0><<<dim3(3, MTOK/GBM), blk, 0, stream>>>(
        x, wqB, b_qkv, spqkv, MTOK, 576, CCH,
        stats, ln1_g, ln1_b, nullptr,
        (const float*)chqkv, nullptr, nullptr, nullptr);

    // ---- MFMA spatial attention + sp proj (roll store) ----
    sp_attn_k<<<dim3(BATCH*NWIN), dim3(384), 0, stream>>>(spqkv, rpb, logit_sp, osp);
    gemm_k<0,2,1,192,0,0><<<dim3(1, MTOK/GBM), blk, 0, stream>>>(
        osp, (const u16*)Wc_spB, bc_sp, sp_out, MTOK, CCH, 144,
        nullptr, nullptr, nullptr, nullptr,
        nullptr, nullptr, nullptr, nullptr);

    // ---- channel attention: partial gram -> softmax -> fused W -> GEMM ----
    ch_part_k<<<dim3(16, 2, BATCH), blk, 0, stream>>>(chqkv, pgram, pss);
    ch_soft_k<<<dim3(2, BATCH), blk, 0, stream>>>(pgram, pss, logit_ch, attn_b);
    fuse_chw_k<<<BATCH, 192, 0, stream>>>(Wc_ch, attn_b, Wfuse);
    gemm_k<4,0,1,192,0,1><<<dim3(1, MTOK/GBM), blk, 0, stream>>>(
        chqkv, (const u16*)Wfuse, bc_ch, ch_out, MTOK, CCH, 48,
        nullptr, nullptr, nullptr, nullptr,
        nullptr, nullptr, nullptr, nullptr);

    // ---- CFCA means/gates ----
    mean2_k<<<dim3(HW/256, BATCH), blk, 0, stream>>>(sp_out, mean_sp);
    mean2_k<<<dim3(HW/256, BATCH), blk, 0, stream>>>(ch_out, mean_ch);
    gates_k<<<BATCH, 192, 0, stream>>>(mean_sp, w_gs1, w_gs2, b_gs2, gate_s);
    gates_k<<<BATCH, 192, 0, stream>>>(mean_ch, w_gc1, w_gc2, b_gc2, gate_c);

    // ---- CFCA hiddens + gated residual adds ----
    gemm_k<0,1,1,96,0,0><<<dim3(1, MTOK/GBM), blk, 0, stream>>>(
        sp_out, ws2c1B, nullptr, hid_s, MTOK, MIDC, CCH,
        nullptr, nullptr, nullptr, nullptr, nullptr, nullptr, nullptr, nullptr);
    gemm_k<0,1,1,96,0,0><<<dim3(1, MTOK/GBM), blk, 0, stream>>>(
        ch_out, wc2s1B, nullptr, hid_c, MTOK, MIDC, CCH,
        nullptr, nullptr, nullptr, nullptr, nullptr, nullptr, nullptr, nullptr);
    gemm_k<0,4,1,192,0,0><<<dim3(1, MTOK/GBM), blk, 0, stream>>>(
        hid_s, ws2c2B, b_s2c2, ch_out, MTOK, CCH, MIDC,
        nullptr, nullptr, nullptr, nullptr, gate_s, nullptr, nullptr, nullptr);
    gemm_k<0,4,1,192,0,0><<<dim3(1, MTOK/GBM), blk, 0, stream>>>(
        hid_c, wc2s2B, b_c2s2, sp_out, MTOK, CCH, MIDC,
        nullptr, nullptr, nullptr, nullptr, gate_c, nullptr, nullptr, nullptr);

    // ---- f = relu(bn1(concat @ w_f1^T)) -> PADDED fpad ----
    zb_k<<<(8*516*24+255)/256, blk, 0, stream>>>(fpad);
    gemm_k<2,3,1,192,1,0><<<dim3(1, MTOK/GBM), blk, 0, stream>>>(
        sp_out, wf1B, nullptr, fpad, MTOK, CCH, 2*CCH,
        nullptr, nullptr, nullptr, ch_out, bn1_g, bn1_b, bn1_m, bn1_v);

    // ---- f2 = relu(bn2(conv3x3(f))) -> PADDED f2pad ----
    zb_k<<<(8*516*24+255)/256, blk, 0, stream>>>(f2pad);
    gemm_k<3,3,1,192,1,0><<<dim3(1, MTOK/GBM), blk, 0, stream>>>(
        fpad, wf2cB, nullptr, f2pad, MTOK, CCH, 9*CCH,
        nullptr, nullptr, nullptr, nullptr, bn2_g, bn2_b, bn2_m, bn2_v);

    // ---- gpre = conv3x3(f2) (96 ch) ----
    gemm_k<3,0,1,96,0,0><<<dim3(1, MTOK/GBM), blk, 0, stream>>>(
        f2pad, wsg1cB, nullptr, gpre, MTOK, 96, 9*CCH,
        nullptr, nullptr, nullptr, nullptr, nullptr, nullptr, nullptr, nullptr);

    // ---- xnew = x + f2*(1+g) -> d_out  (+ fused LN2 stats) ----
    fuse_k<<<MTOK/4, blk, 0, stream>>>(x, f2pad, gpre, w_sg2, b_sg2, out, stats);

    // ---- MLP (2 chunks; hidden over dead A0 region) ----
    const int CHM = MTOK / 2;
    for (int c0 = 0; c0 < MTOK; c0 += CHM) {
        gemm_k<1,5,1,192,0,0><<<dim3(4, CHM/GBM), blk, 0, stream>>>(
            out + (size_t)c0*CCH, wfc1B, b_fc1, hidden, CHM, 4*CCH, CCH,
            stats + (size_t)c0*2, ln2_g, ln2_b, nullptr,
            nullptr, nullptr, nullptr, nullptr);
        gemm_k<0,6,0,192,0,0><<<dim3(1, CHM/GBM), blk, 0, stream>>>(
            hidden, wfc2B, b_fc2, out + (size_t)c0*CCH, CHM, CCH, 4*CCH,
            nullptr, nullptr, nullptr, nullptr, out + (size_t)c0*CCH,
            nullptr, nullptr, nullptr);
    }
}

// Round 15
// 1303.154 us; speedup vs baseline: 1.2685x; 1.0110x over previous
//
#include <hip/hip_runtime.h>
#include <hip/hip_bf16.h>
#include <cstddef>

typedef __hip_bfloat16 bf16;
typedef unsigned short u16;
typedef unsigned int u32;
typedef short s16x8 __attribute__((ext_vector_type(8)));
typedef float f32x4 __attribute__((ext_vector_type(4)));

// ---------------- problem constants ----------------
#define BATCH 8
#define HR 128
#define WR 128
#define CCH 192
#define HW (HR*WR)            // 16384
#define MTOK (BATCH*HW)       // 131072
#define SPH 6
#define SPC 432               // spatial qkv channels (heads 0..5)
#define CHC 144               // channel-head qkv channels (heads 6,7)
#define NWIN 256
#define MIDC 48
#define PH 130                // padded conv H/W
#define PHW (PH*PH)           // 16900
#define LOGMAX 4.6051701859880914f

// ---------------- ws layout (BYTE offsets; peak ~193 MB) ----------------
static const size_t OFF_A0    = 0;
static const size_t OFF_B0    = 113246208;
static const size_t OFF_C0    = 150994944;
static const size_t OFF_SMALL = 188743680;
static const size_t SO_STATS  = 0;          // fp32 2*M (LN1 only)
static const size_t SO_PGRAM  = 1048576;    // fp32 [8][2][16][576]
static const size_t SO_PSS    = 1638400;    // fp32 [8][2][16][48]
static const size_t SO_ATTNB  = 1687552;    // fp32 [8][2][24][24]
static const size_t SO_MEANSP = 1724416;
static const size_t SO_MEANCH = 1732608;
static const size_t SO_GATES  = 1740800;
static const size_t SO_GATEC  = 1748992;
static const size_t SO_BCSP   = 1757184;    // fp32 192
static const size_t SO_WCCH   = 1758208;    // fp32 192*48
static const size_t SO_BCCH   = 1795072;    // fp32 192
static const size_t SO_WFUSE  = 1796096;    // bf16 [8][192][48]
static const size_t SO_WCSPB  = 1943552;    // bf16 192*144
static const size_t SO_WQB    = 1998848;    // bf16 576*192
static const size_t SO_WS2C1B = 2220032;    // bf16 48*192
static const size_t SO_WC2S1B = 2238464;
static const size_t SO_WS2C2B = 2256896;    // bf16 192*48
static const size_t SO_WC2S2B = 2275328;
static const size_t SO_WF1B   = 2293760;    // bf16 192*384
static const size_t SO_WF2CB  = 2441216;    // bf16 192*1728
static const size_t SO_WSG1CB = 3104768;    // bf16 96*1728
static const size_t SO_WFC1B  = 3436544;    // bf16 768*192
static const size_t SO_WFC2B  = 3731456;    // bf16 192*768

__device__ __forceinline__ float b2f(bf16 x) { return __bfloat162float(x); }
__device__ __forceinline__ bf16  f2b(float x){ return __float2bfloat16(x); }
__device__ __forceinline__ u16   f2u(float x){
    bf16 h = __float2bfloat16(x);
    union { bf16 b; u16 u; } c; c.b = h; return c.u;
}
__device__ __forceinline__ float s2f(short s){
    union { u16 u; bf16 b; } c; c.u = (u16)s; return b2f(c.b);
}
__device__ __forceinline__ float u2f(u16 u){
    union { u16 u; bf16 b; } c; c.u = u; return b2f(c.b);
}
// bijective XCD-aware remap (m204 variant)
__device__ __forceinline__ int xcdswz(int b, int n){
    const int q = n >> 3, r = n & 7, x = b & 7, o = b >> 3;
    return (x < r) ? (x * (q + 1) + o) : (r * (q + 1) + (x - r) * q + o);
}

// =====================================================================
// MFMA bf16 GEMM: double-buffered LDS (1 barrier/K-step), register
// prefetch, LDS-staged vectorized epilogues, XCD-swizzled M-blocks.
// block 256 thr = 4 waves (2x2), tile 128 x BNT, BK=32.
// LDA=40 (80B row stride) -> fragment ds_read_b128 hits all 8 bank-groups.
// AMODE: 0 plain bf16, 1 LN-fused (A fp32 + stats), 2 concat(A|A2 bf16),
//        3 implicit 3x3 conv over PADDED input, 4 V-extract from chqkv
// EPI: 0 bias, 1 relu, 2 roll-store, 3 BN+relu, 4 gated residual,
//      5 gelu, 6 residual add (fp32 ep0, CBF=0, N==BNT), 7 qkv split store
// =====================================================================
#define GBM 128
#define GBK 32
#define LDA 40   // padded LDS row length in ushorts (80 B)

struct SegRaw { union { uint4 v; struct { float4 lo, hi; } f; } d; };

template<int AMODE, int EPI, int CBF, int BNT, int CPAD, int WPB>
__global__ __launch_bounds__(256)
void gemm_k(const void* __restrict__ A, const u16* __restrict__ W,
            const float* __restrict__ bias, void* __restrict__ Cv,
            int M, int N, int K,
            const float* __restrict__ stats, const float* __restrict__ lng,
            const float* __restrict__ lnb, const void* __restrict__ A2,
            const float* __restrict__ ep0, const float* __restrict__ ep1,
            const float* __restrict__ ep2, const float* __restrict__ ep3)
{
    constexpr int NF = BNT / 32;
    constexpr int NB = (BNT * 4 + 255) / 256;
    constexpr int ATILE = GBM * LDA;      // u16 units
    constexpr int BTILE = BNT * LDA;
    constexpr int BUFSZ = ATILE + BTILE;
    constexpr int CST   = BNT + 8;        // padded bf16 C-staging stride (u16)
    __shared__ __align__(16) u16 smem[2 * BUFSZ];  // reused for C staging

    const int tid  = threadIdx.x;
    const int lane = tid & 63;
    const int wid  = tid >> 6;
    const int wm   = (wid >> 1) * 64;
    const int wn   = (wid & 1) * (BNT / 2);
    const int m0   = xcdswz(blockIdx.y, gridDim.y) * GBM;
    const int n0   = blockIdx.x * BNT;
    const int row16 = lane & 15;
    const int hi    = lane >> 4;
    const int koff  = hi * 8;

    const int arow[2] = { tid >> 2, (tid + 256) >> 2 };
    const int akk     = (tid & 3) * 8;

    const u16* Wb = W;
    if constexpr (WPB) Wb = W + (size_t)(m0 >> 14) * 9216;

    float meanA[2], rstdA[2];
    if constexpr (AMODE == 1) {
        #pragma unroll
        for (int it = 0; it < 2; ++it) {
            const int m = m0 + arow[it];
            meanA[it] = stats[2*m]; rstdA[it] = stats[2*m+1];
        }
    }

    f32x4 acc[4][NF];
    #pragma unroll
    for (int mf = 0; mf < 4; ++mf)
        #pragma unroll
        for (int nf = 0; nf < NF; ++nf)
            acc[mf][nf] = (f32x4){0.f, 0.f, 0.f, 0.f};

    const int nsteps = (K + GBK - 1) / GBK;

    auto loadA = [&](int step, SegRaw seg[2]) {
        const int k0 = step * GBK;
        #pragma unroll
        for (int it = 0; it < 2; ++it) {
            const int m = m0 + arow[it];
            const int k = k0 + akk;
            SegRaw& s = seg[it];
            if (k >= K) { s.d.v = (uint4){0u,0u,0u,0u}; continue; }
            if constexpr (AMODE == 0) {
                s.d.v = *(const uint4*)((const u16*)A + (size_t)m * K + k);
            } else if constexpr (AMODE == 1) {
                const float* p = (const float*)A + (size_t)m * K + k;
                s.d.f.lo = *(const float4*)p; s.d.f.hi = *(const float4*)(p+4);
            } else if constexpr (AMODE == 2) {
                const u16* src = (k < CCH) ? (const u16*)A  + (size_t)m * CCH + k
                                           : (const u16*)A2 + (size_t)m * CCH + (k - CCH);
                s.d.v = *(const uint4*)src;
            } else if constexpr (AMODE == 3) {
                const int tap = k / CCH, c = k - tap * CCH;
                const int ky = tap / 3, kx = tap - ky * 3;
                const int b = m >> 14, pix = m & 16383;
                const int h = pix >> 7, w = pix & 127;
                s.d.v = *(const uint4*)((const u16*)A +
                        ((size_t)b * PHW + (size_t)(h + ky) * PH + (w + kx)) * CCH + c);
            } else {
                const int col = (k < 24) ? (48 + k) : (96 + k);
                s.d.v = *(const uint4*)((const u16*)A + (size_t)m * CHC + col);
            }
        }
    };
    auto loadB = [&](int step, SegRaw seg[NB]) {
        const int k0 = step * GBK;
        #pragma unroll
        for (int it = 0; it < NB; ++it) {
            const int s = tid + it * 256;
            const int n = n0 + (s >> 2);
            const int k = k0 + (s & 3) * 8;
            seg[it].d.v = (uint4){0u,0u,0u,0u};
            if (s < BNT*4 && k < K && n < N)
                seg[it].d.v = *(const uint4*)(Wb + (size_t)n * K + k);
        }
    };
    auto writeA = [&](int step, SegRaw seg[2], u16* Ab) {
        const int k0 = step * GBK;
        #pragma unroll
        for (int it = 0; it < 2; ++it) {
            if constexpr (AMODE == 1) {
                const int k = k0 + akk;
                union { u16 u[8]; uint4 v; } pk;
                #pragma unroll
                for (int j = 0; j < 8; ++j) {
                    float xx = (j < 4) ? seg[it].d.f.lo[j] : seg[it].d.f.hi[j-4];
                    xx = (xx - meanA[it]) * rstdA[it] * lng[k+j] + lnb[k+j];
                    pk.u[j] = f2u(xx);
                }
                *(uint4*)&Ab[arow[it] * LDA + akk] = pk.v;
            } else {
                *(uint4*)&Ab[arow[it] * LDA + akk] = seg[it].d.v;
            }
        }
    };
    auto writeB = [&](SegRaw seg[NB], u16* Bb) {
        #pragma unroll
        for (int it = 0; it < NB; ++it) {
            const int s = tid + it * 256;
            if (s < BNT*4)
                *(uint4*)&Bb[(s >> 2) * LDA + (s & 3) * 8] = seg[it].d.v;
        }
    };

    SegRaw segA[2], segB[NB];
    loadA(0, segA); loadB(0, segB);
    writeA(0, segA, smem); writeB(segB, smem + ATILE);
    __syncthreads();

    int cur = 0;
    for (int step = 0; step < nsteps; ++step) {
        const bool more = (step + 1 < nsteps);
        if (more) { loadA(step+1, segA); loadB(step+1, segB); }
        u16* Ab = smem + cur * BUFSZ;
        u16* Bb = Ab + ATILE;
        s16x8 af[4], bfr[NF];
        #pragma unroll
        for (int mf = 0; mf < 4; ++mf)
            af[mf] = *(const s16x8*)&Ab[(wm + mf*16 + row16) * LDA + koff];
        #pragma unroll
        for (int nf = 0; nf < NF; ++nf)
            bfr[nf] = *(const s16x8*)&Bb[(wn + nf*16 + row16) * LDA + koff];
        __builtin_amdgcn_s_setprio(1);
        #pragma unroll
        for (int mf = 0; mf < 4; ++mf)
            #pragma unroll
            for (int nf = 0; nf < NF; ++nf)
                acc[mf][nf] = __builtin_amdgcn_mfma_f32_16x16x32_bf16(
                    af[mf], bfr[nf], acc[mf][nf], 0, 0, 0);
        __builtin_amdgcn_s_setprio(0);
        if (more) {
            u16* An = smem + (cur ^ 1) * BUFSZ;
            writeA(step+1, segA, An); writeB(segB, An + ATILE);
        }
        __syncthreads();
        cur ^= 1;
    }

    // ================= epilogue =================
    if constexpr (CBF == 1) {
        // ---- stage bf16 C tile into LDS (padded stride CST) ----
        #pragma unroll
        for (int mf = 0; mf < 4; ++mf) {
            #pragma unroll
            for (int nf = 0; nf < NF; ++nf) {
                const int n = n0 + wn + nf*16 + row16;
                #pragma unroll
                for (int r = 0; r < 4; ++r) {
                    const int m_loc = wm + mf*16 + hi*4 + r;
                    float v = acc[mf][nf][r];
                    if (n < N) {
                        v += (bias ? bias[n] : 0.f);
                        if constexpr (EPI == 1) {
                            v = fmaxf(v, 0.f);
                        } else if constexpr (EPI == 3) {
                            v = (v - ep2[n]) * rsqrtf(ep3[n] + 1e-5f) * ep0[n] + ep1[n];
                            v = fmaxf(v, 0.f);
                        } else if constexpr (EPI == 4) {
                            const int b = (m0 + m_loc) >> 14;
                            v = v * ep0[b * N + n];
                        } else if constexpr (EPI == 5) {
                            v = 0.5f * v * (1.f + erff(v * 0.70710678118654752f));
                        }
                    }
                    smem[m_loc * CST + (wn + nf*16 + row16)] = f2u(v);
                }
            }
        }
        __syncthreads();
        // ---- vectorized store: 8 bf16 (16B) per task ----
        constexpr int CHUNKS = BNT / 8;
        constexpr int TASKS  = GBM * CHUNKS / 256;
        #pragma unroll
        for (int t2 = 0; t2 < TASKS; ++t2) {
            const int task  = tid + t2 * 256;
            const int rloc  = task / CHUNKS;
            const int chunk = task - rloc * CHUNKS;
            const int m  = m0 + rloc;
            const int nn = n0 + chunk * 8;
            if (nn >= N) continue;
            uint4 val = *(const uint4*)&smem[rloc * CST + chunk * 8];
            if constexpr (EPI == 7) {
                if (nn < SPC) {
                    *(uint4*)((u16*)Cv + (size_t)m * SPC + nn) = val;
                } else {
                    u16* chq = (u16*)ep0;
                    *(uint4*)(chq + (size_t)m * CHC + (nn - SPC)) = val;
                }
                continue;
            }
            size_t outIdx;
            if constexpr (CPAD == 1) {
                const int b = m >> 14, pix = m & 16383;
                const int h = pix >> 7, w = pix & 127;
                outIdx = ((size_t)b * PHW + (size_t)(h+1) * PH + (w+1)) * (size_t)N + nn;
            } else if constexpr (EPI == 2) {
                const int b = m >> 14, pix = m & 16383;
                const int h2 = ((pix >> 7) + 4) & 127;
                const int w2 = ((pix & 127) + 4) & 127;
                outIdx = ((size_t)(b * HW) + h2 * WR + w2) * (size_t)N + nn;
            } else {
                outIdx = (size_t)m * N + nn;
            }
            if constexpr (EPI == 4) {
                union { uint4 v; u16 u[8]; } sv, ov;
                sv.v = val;
                ov.v = *(const uint4*)((const u16*)Cv + outIdx);
                #pragma unroll
                for (int j = 0; j < 8; ++j)
                    sv.u[j] = f2u(u2f(ov.u[j]) + u2f(sv.u[j]));
                *(uint4*)((u16*)Cv + outIdx) = sv.v;
            } else {
                *(uint4*)((u16*)Cv + outIdx) = val;
            }
        }
    } else {
        // ---- fp32 path (fc2, EPI6, N==BNT): LDS-staged float4 stores,
        //      32-row quarters, stride BNT+16 (2-way-free banks) ----
        float* fs = (float*)smem;
        constexpr int FST = BNT + 16;
        #pragma unroll
        for (int q = 0; q < 4; ++q) {
            __syncthreads();
            if ((wid >> 1) == (q >> 1)) {
                #pragma unroll
                for (int mfi = 0; mfi < 2; ++mfi) {
                    const int mf = (q & 1) * 2 + mfi;
                    #pragma unroll
                    for (int nf = 0; nf < NF; ++nf) {
                        const int n = wn + nf*16 + row16;
                        #pragma unroll
                        for (int r = 0; r < 4; ++r) {
                            const int mloc = mfi*16 + hi*4 + r;   // 0..31
                            fs[mloc * FST + n] = acc[mf][nf][r] + (bias ? bias[n0 + n] : 0.f);
                        }
                    }
                }
            }
            __syncthreads();
            const int TOT = 32 * (BNT/4);
            for (int task = tid; task < TOT; task += 256) {
                const int rloc = task / (BNT/4);
                const int cc = (task - rloc*(BNT/4)) * 4;
                const int m = m0 + q*32 + rloc;
                const int nn = n0 + cc;
                if (nn >= N) continue;
                float4 v4 = *(const float4*)&fs[rloc*FST + cc];
                const size_t oi = (size_t)m * N + nn;
                if constexpr (EPI == 6) {
                    const float4 o4 = *(const float4*)&ep0[oi];
                    v4.x += o4.x; v4.y += o4.y; v4.z += o4.z; v4.w += o4.w;
                }
                *(float4*)&((float*)Cv)[oi] = v4;
            }
        }
    }
}

// =====================================================================
// weight prep
// =====================================================================
__global__ __launch_bounds__(256)
void wprep_lin_k(const float* __restrict__ in, bf16* __restrict__ outb, int n)
{
    const int i = blockIdx.x * 256 + threadIdx.x;
    if (i < n) outb[i] = f2b(in[i]);
}

__global__ __launch_bounds__(256)
void wprep_conv_k(const float* __restrict__ in, bf16* __restrict__ outb, int total)
{
    const int i = blockIdx.x * 256 + threadIdx.x;
    if (i >= total) return;
    const int n = i / 1728, r = i - n * 1728;
    const int tap = r / CCH, c = r - tap * CCH;
    outb[i] = f2b(in[((size_t)n * CCH + c) * 9 + tap]);
}

__global__ __launch_bounds__(256)
void zb_k(bf16* __restrict__ buf)
{
    const int i = blockIdx.x * 256 + threadIdx.x;
    if (i >= 8 * 516 * 24) return;
    const int chunk = i % 24;
    const int p = (i / 24) % 516;
    const int b = i / (24 * 516);
    int h, w;
    if (p < 130)      { h = 0;   w = p; }
    else if (p < 260) { h = 129; w = p - 130; }
    else { const int q = p - 260; h = 1 + (q >> 1); w = (q & 1) ? 129 : 0; }
    *(uint4*)((u16*)buf + ((size_t)b * PHW + (size_t)h * PH + w) * CCH + chunk * 8)
        = (uint4){0u,0u,0u,0u};
}

__global__ __launch_bounds__(256)
void zerof_k(float* __restrict__ p, int n)
{
    const int i = blockIdx.x * 256 + threadIdx.x;
    if (i < n) p[i] = 0.f;
}

// =====================================================================
// LN stats (LN1 only)
// =====================================================================
__global__ __launch_bounds__(256)
void ln_stats_k(const float* __restrict__ x, float* __restrict__ stats)
{
    const int tok = blockIdx.x * 4 + (threadIdx.x >> 6);
    const int lane = threadIdx.x & 63;
    const float* r = x + (size_t)tok * CCH;
    float s = 0.f, sq = 0.f;
    for (int c = lane; c < CCH; c += 64) { float v = r[c]; s += v; sq += v*v; }
    for (int m = 1; m < 64; m <<= 1) { s += __shfl_xor(s, m); sq += __shfl_xor(sq, m); }
    if (lane == 0) {
        const float mean = s / (float)CCH;
        const float var = sq / (float)CCH - mean * mean;
        stats[(size_t)tok*2]   = mean;
        stats[(size_t)tok*2+1] = rsqrtf(var + 1e-5f);
    }
}

// =====================================================================
// MFMA spatial shifted-window cosine attention (6 waves = 6 heads/window)
// =====================================================================
__global__ __launch_bounds__(384)
void sp_attn_k(const bf16* __restrict__ spqkv, const float* __restrict__ rpb,
               const float* __restrict__ logit_sp, bf16* __restrict__ osp)
{
    const int b    = blockIdx.x >> 8;
    const int win  = blockIdx.x & 255;
    const int wh = win >> 4, ww = win & 15;
    const int head = threadIdx.x >> 6;
    const int lane = threadIdx.x & 63;
    const int row16 = lane & 15;
    const int hi   = lane >> 4;
    const int koff = hi * 8;

    __shared__ float rpbS[1350];
    __shared__ u16 vT[SPH][32][72];

    for (int i = threadIdx.x; i < 1350; i += 384) rpbS[i] = rpb[i];

    const u16* base = (const u16*)spqkv + (size_t)b * HW * SPC;

    s16x8 qf[4], kf[4];
    const int wcol = (ww*8 + (row16 & 7) + 4) & 127;
    #pragma unroll
    for (int t = 0; t < 4; ++t) {
        const int pos = t*16 + row16;
        const int h = (wh*8 + (pos >> 3) + 4) & 127;
        const u16* rowp = base + ((size_t)(h * WR + wcol)) * SPC + head * 72;
        if (koff < 24) {
            qf[t] = *(const s16x8*)(rowp + koff);
            kf[t] = *(const s16x8*)(rowp + 24 + koff);
        } else {
            qf[t] = (s16x8){0,0,0,0,0,0,0,0};
            kf[t] = (s16x8){0,0,0,0,0,0,0,0};
        }
    }

    {
        const int h = (wh*8 + (lane >> 3) + 4) & 127;
        const int w = (ww*8 + (lane & 7) + 4) & 127;
        const u16* vrow = base + ((size_t)(h * WR + w)) * SPC + head * 72 + 48;
        union { uint4 v; u16 u[8]; } seg[3];
        seg[0].v = *(const uint4*)(vrow);
        seg[1].v = *(const uint4*)(vrow + 8);
        seg[2].v = *(const uint4*)(vrow + 16);
        #pragma unroll
        for (int d = 0; d < 24; ++d) vT[head][d][lane] = seg[d>>3].u[d&7];
        #pragma unroll
        for (int d = 24; d < 32; ++d) vT[head][d][lane] = 0;
    }
    __syncthreads();

    float rq[4], rk[4];
    #pragma unroll
    for (int t = 0; t < 4; ++t) {
        float sq = 0.f, sk = 0.f;
        #pragma unroll
        for (int e = 0; e < 8; ++e) {
            const float a = s2f(qf[t][e]); sq += a*a;
            const float c = s2f(kf[t][e]); sk += c*c;
        }
        sq += __shfl_xor(sq, 16); sq += __shfl_xor(sq, 32);
        sk += __shfl_xor(sk, 16); sk += __shfl_xor(sk, 32);
        rq[t] = 1.f / fmaxf(sqrtf(sq), 1e-12f);
        rk[t] = 1.f / fmaxf(sqrtf(sk), 1e-12f);
    }
    const float scale_h = __expf(fminf(logit_sp[head], LOGMAX));

    f32x4 acc[4][4];
    #pragma unroll
    for (int mfk = 0; mfk < 4; ++mfk)
        #pragma unroll
        for (int nfq = 0; nfq < 4; ++nfq)
            acc[mfk][nfq] = (f32x4){0.f,0.f,0.f,0.f};
    #pragma unroll
    for (int mfk = 0; mfk < 4; ++mfk)
        #pragma unroll
        for (int nfq = 0; nfq < 4; ++nfq)
            acc[mfk][nfq] = __builtin_amdgcn_mfma_f32_16x16x32_bf16(
                kf[mfk], qf[nfq], acc[mfk][nfq], 0, 0, 0);

    f32x4 rkj[4];
    #pragma unroll
    for (int mfk = 0; mfk < 4; ++mfk)
        #pragma unroll
        for (int r = 0; r < 4; ++r)
            rkj[mfk][r] = __shfl(rk[mfk], hi*4 + r);

    int ip3[4], iw7[4], labi[4];
    #pragma unroll
    for (int t = 0; t < 4; ++t) {
        const int pos = t*16 + row16;
        ip3[t] = pos >> 3; iw7[t] = pos & 7;
        const int hh = wh*8 + ip3[t], w0 = ww*8 + iw7[t];
        const int rh = hh < 120 ? 0 : (hh < 124 ? 1 : 2);
        const int rw = w0 < 120 ? 0 : (w0 < 124 ? 1 : 2);
        labi[t] = rh*3 + rw;
    }

    #pragma unroll
    for (int mfk = 0; mfk < 4; ++mfk) {
        #pragma unroll
        for (int r = 0; r < 4; ++r) {
            const int j = hi*4 + r + 16*mfk;
            const int jp3 = j >> 3, jw7 = j & 7;
            const int hh = wh*8 + jp3, w0 = ww*8 + jw7;
            const int rh = hh < 120 ? 0 : (hh < 124 ? 1 : 2);
            const int rw = w0 < 120 ? 0 : (w0 < 124 ? 1 : 2);
            const int labj = rh*3 + rw;
            const float rkv = rkj[mfk][r];
            #pragma unroll
            for (int nfq = 0; nfq < 4; ++nfq) {
                float s = acc[mfk][nfq][r] * rq[nfq] * rkv * scale_h;
                s += rpbS[((ip3[nfq]-jp3+7)*15 + (iw7[nfq]-jw7+7))*SPH + head];
                if (labi[nfq] != labj) s -= 100.f;
                acc[mfk][nfq][r] = s;
            }
        }
    }

    float inv[4];
    #pragma unroll
    for (int nfq = 0; nfq < 4; ++nfq) {
        float m = -1e30f;
        #pragma unroll
        for (int mfk = 0; mfk < 4; ++mfk)
            #pragma unroll
            for (int r = 0; r < 4; ++r)
                m = fmaxf(m, acc[mfk][nfq][r]);
        m = fmaxf(m, __shfl_xor(m, 16));
        m = fmaxf(m, __shfl_xor(m, 32));
        float s = 0.f;
        #pragma unroll
        for (int mfk = 0; mfk < 4; ++mfk)
            #pragma unroll
            for (int r = 0; r < 4; ++r) {
                const float p = __expf(acc[mfk][nfq][r] - m);
                acc[mfk][nfq][r] = p;
                s += p;
            }
        s += __shfl_xor(s, 16);
        s += __shfl_xor(s, 32);
        inv[nfq] = 1.f / s;
    }

    u32 pk01[4][4], pk23[4][4];
    #pragma unroll
    for (int mfk = 0; mfk < 4; ++mfk)
        #pragma unroll
        for (int nfq = 0; nfq < 4; ++nfq) {
            pk01[mfk][nfq] = (u32)f2u(acc[mfk][nfq][0] * inv[nfq])
                           | ((u32)f2u(acc[mfk][nfq][1] * inv[nfq]) << 16);
            pk23[mfk][nfq] = (u32)f2u(acc[mfk][nfq][2] * inv[nfq])
                           | ((u32)f2u(acc[mfk][nfq][3] * inv[nfq]) << 16);
        }

    s16x8 vf[2][2];
    #pragma unroll
    for (int nf = 0; nf < 2; ++nf)
        #pragma unroll
        for (int ks = 0; ks < 2; ++ks)
            vf[nf][ks] = *(const s16x8*)&vT[head][row16 + 16*nf][32*ks + koff];

    f32x4 accO[4][2];
    #pragma unroll
    for (int MF = 0; MF < 4; ++MF)
        #pragma unroll
        for (int nf = 0; nf < 2; ++nf)
            accO[MF][nf] = (f32x4){0.f,0.f,0.f,0.f};

    const int g0 = 2*(hi & 1);
    const int src0 = g0*16 + row16, src1 = src0 + 16;
    const bool selhi = (hi >> 1) != 0;
    #pragma unroll
    for (int ks = 0; ks < 2; ++ks) {
        #pragma unroll
        for (int MF = 0; MF < 4; ++MF) {
            const u32 e01a = __shfl(pk01[2*ks][MF],   src0);
            const u32 e01b = __shfl(pk01[2*ks+1][MF], src0);
            const u32 e23a = __shfl(pk23[2*ks][MF],   src0);
            const u32 e23b = __shfl(pk23[2*ks+1][MF], src0);
            const u32 e45a = __shfl(pk01[2*ks][MF],   src1);
            const u32 e45b = __shfl(pk01[2*ks+1][MF], src1);
            const u32 e67a = __shfl(pk23[2*ks][MF],   src1);
            const u32 e67b = __shfl(pk23[2*ks+1][MF], src1);
            union { u32 w[4]; s16x8 v; } af;
            af.w[0] = selhi ? e01b : e01a;
            af.w[1] = selhi ? e23b : e23a;
            af.w[2] = selhi ? e45b : e45a;
            af.w[3] = selhi ? e67b : e67a;
            accO[MF][0] = __builtin_amdgcn_mfma_f32_16x16x32_bf16(
                af.v, vf[0][ks], accO[MF][0], 0, 0, 0);
            accO[MF][1] = __builtin_amdgcn_mfma_f32_16x16x32_bf16(
                af.v, vf[1][ks], accO[MF][1], 0, 0, 0);
        }
    }

    #pragma unroll
    for (int MF = 0; MF < 4; ++MF) {
        #pragma unroll
        for (int nf = 0; nf < 2; ++nf) {
            const int d = row16 + 16*nf;
            if (d >= 24) continue;
            #pragma unroll
            for (int r = 0; r < 4; ++r) {
                const int qrow = hi*4 + r + 16*MF;
                const int h = wh*8 + (qrow >> 3);
                const int w = ww*8 + (qrow & 7);
                osp[((size_t)b*HW + h*WR + w)*144 + head*24 + d] = f2b(accO[MF][nf][r]);
            }
        }
    }
}

// =====================================================================
// Channel attention: partial gram + column sum-squares, softmax, W-fuse
// =====================================================================
__global__ __launch_bounds__(256)
void ch_part_k(const bf16* __restrict__ chqkv, float* __restrict__ pgram,
               float* __restrict__ pss)
{
    const int ci = blockIdx.x, head = blockIdx.y, b = blockIdx.z;
    const int tid = threadIdx.x;
    __shared__ u16 tile[256][48];
    float g[3] = {0.f, 0.f, 0.f};
    float ss = 0.f;
    const u16* src = (const u16*)chqkv + (size_t)b * HW * CHC + head * 72;
    const int rbase = ci * 1024;

    for (int t0 = 0; t0 < 1024; t0 += 256) {
        __syncthreads();
        for (int idx = tid; idx < 256*6; idx += 256) {
            const int row = idx / 6, seg = idx - (idx/6)*6;
            *(uint4*)&tile[row][seg*8] =
                *(const uint4*)(src + (size_t)(rbase + t0 + row) * CHC + seg*8);
        }
        __syncthreads();
        #pragma unroll
        for (int i = 0; i < 3; ++i) {
            const int e = tid + i*256;
            if (e < 576) {
                const int c = e / 24, d = e - (e/24)*24;
                float s = 0.f;
                for (int r = 0; r < 256; ++r)
                    s += b2f(*(const bf16*)&tile[r][c]) * b2f(*(const bf16*)&tile[r][24+d]);
                g[i] += s;
            }
        }
        if (tid < 48) {
            float s = 0.f;
            for (int r = 0; r < 256; ++r) { const float v = b2f(*(const bf16*)&tile[r][tid]); s += v*v; }
            ss += s;
        }
    }
    float* pg = pgram + ((size_t)(b*2+head)*16 + ci) * 576;
    #pragma unroll
    for (int i = 0; i < 3; ++i) { const int e = tid + i*256; if (e < 576) pg[e] = g[i]; }
    if (tid < 48) pss[((size_t)(b*2+head)*16 + ci) * 48 + tid] = ss;
}

__global__ __launch_bounds__(256)
void ch_soft_k(const float* __restrict__ pgram, const float* __restrict__ pss,
               const float* __restrict__ logit_ch, float* __restrict__ attn)
{
    const int head = blockIdx.x, b = blockIdx.y;
    const int tid = threadIdx.x;
    __shared__ float gs[576], rn[48];
    for (int e = tid; e < 576; e += 256) {
        float s = 0.f;
        const float* pg = pgram + (size_t)(b*2+head)*16*576 + e;
        for (int c = 0; c < 16; ++c) s += pg[c*576];
        gs[e] = s;
    }
    if (tid < 48) {
        float s = 0.f;
        const float* ps = pss + (size_t)(b*2+head)*16*48 + tid;
        for (int c = 0; c < 16; ++c) s += ps[c*48];
        rn[tid] = 1.f / fmaxf(sqrtf(s), 1e-12f);
    }
    __syncthreads();
    if (tid < 24) {
        const float scale = expf(fminf(logit_ch[head], LOGMAX));
        float vals[24], mx = -1e30f;
        #pragma unroll
        for (int d = 0; d < 24; ++d) {
            vals[d] = gs[tid*24+d] * rn[tid] * rn[24+d] * scale;
            mx = fmaxf(mx, vals[d]);
        }
        float sum = 0.f;
        #pragma unroll
        for (int d = 0; d < 24; ++d) { vals[d] = expf(vals[d]-mx); sum += vals[d]; }
        const float inv = 1.f / sum;
        float* o = attn + ((size_t)(b*2+head)*24 + tid)*24;
        #pragma unroll
        for (int d = 0; d < 24; ++d) o[d] = vals[d]*inv;
    }
}

__global__ __launch_bounds__(192)
void fuse_chw_k(const float* __restrict__ Wc, const float* __restrict__ attn,
                bf16* __restrict__ Wf)
{
    const int b = blockIdx.x;
    const int n = threadIdx.x;
    __shared__ float As_[2][24][24];
    for (int e = n; e < 1152; e += 192) {
        const int h = e / 576, r = e - h*576;
        As_[h][r/24][r%24] = attn[(size_t)b*1152 + e];
    }
    __syncthreads();
    const float* wr = Wc + n*48;
    bf16* o = Wf + ((size_t)b*192 + n) * 48;
    for (int h = 0; h < 2; ++h)
        for (int d = 0; d < 24; ++d) {
            float s = 0.f;
            #pragma unroll
            for (int cc = 0; cc < 24; ++cc) s += wr[h*24+cc] * As_[h][cc][d];
            o[h*24+d] = f2b(s);
        }
}

// =====================================================================
// weight combiners
// =====================================================================
__global__ void combine_sp_k(const float* __restrict__ w_sp_proj, const float* __restrict__ w_spp,
                             const float* __restrict__ b_spp, bf16* __restrict__ Wc, float* __restrict__ bc)
{
    const int n = blockIdx.x;
    for (int i = threadIdx.x; i < 144; i += blockDim.x) {
        float s = 0.f;
        for (int j = 0; j < 144; ++j) s += w_sp_proj[n*144 + j] * w_spp[j*144 + i];
        Wc[n*144 + i] = f2b(s);
    }
    if (threadIdx.x == 0) {
        float s = 0.f;
        for (int j = 0; j < 144; ++j) s += w_sp_proj[n*144 + j] * b_spp[j];
        bc[n] = s;
    }
}

__global__ void combine_ch_k(const float* __restrict__ w_ch_proj, const float* __restrict__ w_chp,
                             const float* __restrict__ b_chp, float* __restrict__ Wc, float* __restrict__ bc)
{
    const int n = blockIdx.x;
    for (int c = threadIdx.x; c < 48; c += blockDim.x) {
        float s = 0.f;
        for (int j = 0; j < 48; ++j) s += w_ch_proj[n*48 + j] * w_chp[j*48 + c];
        Wc[n*48 + c] = s;
    }
    if (threadIdx.x == 0) {
        float s = 0.f;
        for (int j = 0; j < 48; ++j) s += w_ch_proj[n*48 + j] * b_chp[j];
        bc[n] = s;
    }
}

// =====================================================================
// coalesced per-(b,c) SUM over H,W (bf16 src), atomic accumulate
// =====================================================================
__global__ __launch_bounds__(256)
void mean2_k(const bf16* __restrict__ src, float* __restrict__ dst)
{
    const int b = blockIdx.y;
    const int r0 = blockIdx.x * 256;
    const int t = threadIdx.x;
    const int chunk = t & 31;
    const int rg = t >> 5;
    float acc[8] = {0.f,0.f,0.f,0.f,0.f,0.f,0.f,0.f};
    if (chunk < 24) {
        for (int r = rg; r < 256; r += 8) {
            const u16* p = (const u16*)src + ((size_t)(b*HW) + r0 + r) * CCH + chunk*8;
            union { uint4 v; u16 u[8]; } s; s.v = *(const uint4*)p;
            #pragma unroll
            for (int j = 0; j < 8; ++j) acc[j] += u2f(s.u[j]);
        }
    }
    __shared__ float red[8][24][8];
    if (chunk < 24) {
        #pragma unroll
        for (int j = 0; j < 8; ++j) red[rg][chunk][j] = acc[j];
    }
    __syncthreads();
    if (t < 192) {
        const int ch = t >> 3, j = t & 7;
        float s = 0.f;
        #pragma unroll
        for (int g = 0; g < 8; ++g) s += red[g][ch][j];
        atomicAdd(&dst[b*CCH + ch*8 + j], s);
    }
}

// gate = sigmoid(relu((sum/HW) @ w1^T) @ w2^T + b2)
__global__ __launch_bounds__(192)
void gates_k(const float* __restrict__ sumv, const float* __restrict__ w1,
             const float* __restrict__ w2, const float* __restrict__ b2,
             float* __restrict__ gate)
{
    const int b = blockIdx.x;
    __shared__ float mv[192], hid[48];
    const int t = threadIdx.x;
    mv[t] = sumv[b*CCH + t] * (1.f / (float)HW);
    __syncthreads();
    if (t < 48) {
        float s = 0.f;
        for (int c = 0; c < 192; ++c) s += w1[t*192 + c] * mv[c];
        hid[t] = fmaxf(s, 0.f);
    }
    __syncthreads();
    float s = b2[t];
    for (int j = 0; j < 48; ++j) s += hid[j] * w2[t*48 + j];
    gate[b*CCH + t] = 1.f / (1.f + expf(-s));
}

// =====================================================================
// out = x + f2(padded) * (1 + sigmoid(relu(gpre)@w_sg2 + b))
// + fused LN2: writes normalized bf16 xnorm = (out-mean)*rstd*g+b
// (bit-identical to ln_stats_k + AMODE1 staging path it replaces)
// =====================================================================
__global__ __launch_bounds__(256)
void fuse_k(const float* __restrict__ x, const bf16* __restrict__ f2pad,
            const bf16* __restrict__ gpre, const float* __restrict__ w_sg2,
            const float* __restrict__ b_sg2, float* __restrict__ out,
            bf16* __restrict__ xnorm, const float* __restrict__ ln2_g,
            const float* __restrict__ ln2_b)
{
    const int pix = blockIdx.x * 4 + (threadIdx.x >> 6);
    const int lane = threadIdx.x & 63;
    const bf16* gp = gpre + (size_t)pix * 96;
    float s = fmaxf(b2f(gp[lane]), 0.f) * w_sg2[lane];
    if (lane < 32) s += fmaxf(b2f(gp[lane + 64]), 0.f) * w_sg2[lane + 64];
    for (int m = 1; m < 64; m <<= 1) s += __shfl_xor(s, m);
    const float g1 = 1.f + 1.f / (1.f + expf(-(s + b_sg2[0])));
    const int b = pix >> 14, p = pix & 16383;
    const int h = p >> 7, w = p & 127;
    const bf16* fr = f2pad + ((size_t)b * PHW + (size_t)(h+1) * PH + (w+1)) * CCH;
    const float* xr = x + (size_t)pix * CCH;
    float* orow = out + (size_t)pix * CCH;
    bf16* nrow = xnorm + (size_t)pix * CCH;
    float ov[3];
    float ssum = 0.f, ssq = 0.f;
    #pragma unroll
    for (int i = 0; i < 3; ++i) {
        const int c = lane + i * 64;
        const float o = xr[c] + b2f(fr[c]) * g1;
        orow[c] = o;
        ov[i] = o;
        ssum += o; ssq += o * o;
    }
    for (int m = 1; m < 64; m <<= 1) {
        ssum += __shfl_xor(ssum, m);
        ssq  += __shfl_xor(ssq, m);
    }
    const float mean = ssum / (float)CCH;
    const float rstd = rsqrtf(ssq / (float)CCH - mean * mean + 1e-5f);
    #pragma unroll
    for (int i = 0; i < 3; ++i) {
        const int c = lane + i * 64;
        nrow[c] = f2b((ov[i] - mean) * rstd * ln2_g[c] + ln2_b[c]);
    }
}

// =====================================================================
// launcher
// =====================================================================
extern "C" void kernel_launch(void* const* d_in, const int* in_sizes, int n_in,
                              void* d_out, int out_size, void* d_ws, size_t ws_size,
                              hipStream_t stream)
{
    const float* x        = (const float*)d_in[0];
    const float* ln1_g    = (const float*)d_in[1];
    const float* ln1_b    = (const float*)d_in[2];
    const float* w_qkv    = (const float*)d_in[3];
    const float* b_qkv    = (const float*)d_in[4];
    const float* logit_sp = (const float*)d_in[5];
    const float* rpb      = (const float*)d_in[6];
    const float* w_spp    = (const float*)d_in[7];
    const float* b_spp    = (const float*)d_in[8];
    const float* logit_ch = (const float*)d_in[9];
    const float* w_chp    = (const float*)d_in[10];
    const float* b_chp    = (const float*)d_in[11];
    const float* w_sp_proj= (const float*)d_in[12];
    const float* w_ch_proj= (const float*)d_in[13];
    const float* w_s2c1   = (const float*)d_in[14];
    const float* w_s2c2   = (const float*)d_in[15];
    const float* b_s2c2   = (const float*)d_in[16];
    const float* w_c2s1   = (const float*)d_in[17];
    const float* w_c2s2   = (const float*)d_in[18];
    const float* b_c2s2   = (const float*)d_in[19];
    const float* w_gs1    = (const float*)d_in[20];
    const float* w_gs2    = (const float*)d_in[21];
    const float* b_gs2    = (const float*)d_in[22];
    const float* w_gc1    = (const float*)d_in[23];
    const float* w_gc2    = (const float*)d_in[24];
    const float* b_gc2    = (const float*)d_in[25];
    const float* w_f1     = (const float*)d_in[26];
    const float* bn1_g    = (const float*)d_in[27];
    const float* bn1_b    = (const float*)d_in[28];
    const float* bn1_m    = (const float*)d_in[29];
    const float* bn1_v    = (const float*)d_in[30];
    const float* w_f2     = (const float*)d_in[31];
    const float* bn2_g    = (const float*)d_in[32];
    const float* bn2_b    = (const float*)d_in[33];
    const float* bn2_m    = (const float*)d_in[34];
    const float* bn2_v    = (const float*)d_in[35];
    const float* w_sg1    = (const float*)d_in[36];
    const float* w_sg2    = (const float*)d_in[37];
    const float* b_sg2    = (const float*)d_in[38];
    const float* ln2_g    = (const float*)d_in[39];
    const float* ln2_b    = (const float*)d_in[40];
    const float* w_fc1    = (const float*)d_in[41];
    const float* b_fc1    = (const float*)d_in[42];
    const float* w_fc2    = (const float*)d_in[43];
    const float* b_fc2    = (const float*)d_in[44];

    char* wsb = (char*)d_ws;
    char* sm  = wsb + OFF_SMALL;
    float* out = (float*)d_out;

    bf16*  spqkv  = (bf16*)(wsb + OFF_A0);
    bf16*  sp_out = (bf16*)(wsb + OFF_A0);
    bf16*  ch_out = (bf16*)(wsb + OFF_A0 + 50331648);
    bf16*  f2pad  = (bf16*)(wsb + OFF_A0);
    bf16*  gpre   = (bf16*)(wsb + OFF_A0 + 51916800);
    bf16*  chqkv  = (bf16*)(wsb + OFF_B0);
    bf16*  hid_s  = (bf16*)(wsb + OFF_B0);
    bf16*  hid_c  = (bf16*)(wsb + OFF_B0 + 12582912);
    bf16*  fpad   = (bf16*)(wsb + OFF_B0);
    bf16*  xnorm  = (bf16*)(wsb + OFF_B0);   // bf16 M*192 = 50.3MB (fpad/osp dead)
    bf16*  hidden = (bf16*)(wsb + OFF_A0);   // fc1 out: A0 dead after fuse_k
    bf16*  osp    = (bf16*)(wsb + OFF_C0);

    float* stats  = (float*)(sm + SO_STATS);
    float* pgram  = (float*)(sm + SO_PGRAM);
    float* pss    = (float*)(sm + SO_PSS);
    float* attn_b = (float*)(sm + SO_ATTNB);
    float* mean_sp= (float*)(sm + SO_MEANSP);
    float* mean_ch= (float*)(sm + SO_MEANCH);
    float* gate_s = (float*)(sm + SO_GATES);
    float* gate_c = (float*)(sm + SO_GATEC);
    float* bc_sp  = (float*)(sm + SO_BCSP);
    float* Wc_ch  = (float*)(sm + SO_WCCH);
    float* bc_ch  = (float*)(sm + SO_BCCH);
    bf16*  Wfuse  = (bf16*)(sm + SO_WFUSE);
    bf16*  Wc_spB = (bf16*)(sm + SO_WCSPB);
    u16*   wqB    = (u16*)(sm + SO_WQB);
    u16*   ws2c1B = (u16*)(sm + SO_WS2C1B);
    u16*   wc2s1B = (u16*)(sm + SO_WC2S1B);
    u16*   ws2c2B = (u16*)(sm + SO_WS2C2B);
    u16*   wc2s2B = (u16*)(sm + SO_WC2S2B);
    u16*   wf1B   = (u16*)(sm + SO_WF1B);
    u16*   wf2cB  = (u16*)(sm + SO_WF2CB);
    u16*   wsg1cB = (u16*)(sm + SO_WSG1CB);
    u16*   wfc1B  = (u16*)(sm + SO_WFC1B);
    u16*   wfc2B  = (u16*)(sm + SO_WFC2B);

    const dim3 blk(256);

    // ---- weight prep ----
    wprep_lin_k<<<(110592+255)/256, blk, 0, stream>>>(w_qkv,  (bf16*)wqB,    110592);
    wprep_lin_k<<<(9216+255)/256,   blk, 0, stream>>>(w_s2c1, (bf16*)ws2c1B, 9216);
    wprep_lin_k<<<(9216+255)/256,   blk, 0, stream>>>(w_c2s1, (bf16*)wc2s1B, 9216);
    wprep_lin_k<<<(9216+255)/256,   blk, 0, stream>>>(w_s2c2, (bf16*)ws2c2B, 9216);
    wprep_lin_k<<<(9216+255)/256,   blk, 0, stream>>>(w_c2s2, (bf16*)wc2s2B, 9216);
    wprep_lin_k<<<(73728+255)/256,  blk, 0, stream>>>(w_f1,   (bf16*)wf1B,   73728);
    wprep_lin_k<<<(147456+255)/256, blk, 0, stream>>>(w_fc1,  (bf16*)wfc1B,  147456);
    wprep_lin_k<<<(147456+255)/256, blk, 0, stream>>>(w_fc2,  (bf16*)wfc2B,  147456);
    wprep_conv_k<<<(331776+255)/256, blk, 0, stream>>>(w_f2,  (bf16*)wf2cB,  331776);
    wprep_conv_k<<<(165888+255)/256, blk, 0, stream>>>(w_sg1, (bf16*)wsg1cB, 165888);
    combine_sp_k<<<192, 128, 0, stream>>>(w_sp_proj, w_spp, b_spp, Wc_spB, bc_sp);
    combine_ch_k<<<192, 64, 0, stream>>>(w_ch_proj, w_chp, b_chp, Wc_ch, bc_ch);
    zerof_k<<<6, blk, 0, stream>>>(mean_sp, 1536);
    zerof_k<<<6, blk, 0, stream>>>(mean_ch, 1536);

    // ---- LN1 stats + full-M qkv GEMM (split store) ----
    ln_stats_k<<<MTOK/4, blk, 0, stream>>>(x, stats);
    gemm_k<1,7,1,192,0,0><<<dim3(3, MTOK/GBM), blk, 0, stream>>>(
        x, wqB, b_qkv, spqkv, MTOK, 576, CCH,
        stats, ln1_g, ln1_b, nullptr,
        (const float*)chqkv, nullptr, nullptr, nullptr);

    // ---- MFMA spatial attention + sp proj (roll store) ----
    sp_attn_k<<<dim3(BATCH*NWIN), dim3(384), 0, stream>>>(spqkv, rpb, logit_sp, osp);
    gemm_k<0,2,1,192,0,0><<<dim3(1, MTOK/GBM), blk, 0, stream>>>(
        osp, (const u16*)Wc_spB, bc_sp, sp_out, MTOK, CCH, 144,
        nullptr, nullptr, nullptr, nullptr,
        nullptr, nullptr, nullptr, nullptr);

    // ---- channel attention: partial gram -> softmax -> fused W -> GEMM ----
    ch_part_k<<<dim3(16, 2, BATCH), blk, 0, stream>>>(chqkv, pgram, pss);
    ch_soft_k<<<dim3(2, BATCH), blk, 0, stream>>>(pgram, pss, logit_ch, attn_b);
    fuse_chw_k<<<BATCH, 192, 0, stream>>>(Wc_ch, attn_b, Wfuse);
    gemm_k<4,0,1,192,0,1><<<dim3(1, MTOK/GBM), blk, 0, stream>>>(
        chqkv, (const u16*)Wfuse, bc_ch, ch_out, MTOK, CCH, 48,
        nullptr, nullptr, nullptr, nullptr,
        nullptr, nullptr, nullptr, nullptr);

    // ---- CFCA means/gates ----
    mean2_k<<<dim3(HW/256, BATCH), blk, 0, stream>>>(sp_out, mean_sp);
    mean2_k<<<dim3(HW/256, BATCH), blk, 0, stream>>>(ch_out, mean_ch);
    gates_k<<<BATCH, 192, 0, stream>>>(mean_sp, w_gs1, w_gs2, b_gs2, gate_s);
    gates_k<<<BATCH, 192, 0, stream>>>(mean_ch, w_gc1, w_gc2, b_gc2, gate_c);

    // ---- CFCA hiddens + gated residual adds ----
    gemm_k<0,1,1,96,0,0><<<dim3(1, MTOK/GBM), blk, 0, stream>>>(
        sp_out, ws2c1B, nullptr, hid_s, MTOK, MIDC, CCH,
        nullptr, nullptr, nullptr, nullptr, nullptr, nullptr, nullptr, nullptr);
    gemm_k<0,1,1,96,0,0><<<dim3(1, MTOK/GBM), blk, 0, stream>>>(
        ch_out, wc2s1B, nullptr, hid_c, MTOK, MIDC, CCH,
        nullptr, nullptr, nullptr, nullptr, nullptr, nullptr, nullptr, nullptr);
    gemm_k<0,4,1,192,0,0><<<dim3(1, MTOK/GBM), blk, 0, stream>>>(
        hid_s, ws2c2B, b_s2c2, ch_out, MTOK, CCH, MIDC,
        nullptr, nullptr, nullptr, nullptr, gate_s, nullptr, nullptr, nullptr);
    gemm_k<0,4,1,192,0,0><<<dim3(1, MTOK/GBM), blk, 0, stream>>>(
        hid_c, wc2s2B, b_c2s2, sp_out, MTOK, CCH, MIDC,
        nullptr, nullptr, nullptr, nullptr, gate_c, nullptr, nullptr, nullptr);

    // ---- f = relu(bn1(concat @ w_f1^T)) -> PADDED fpad ----
    zb_k<<<(8*516*24+255)/256, blk, 0, stream>>>(fpad);
    gemm_k<2,3,1,192,1,0><<<dim3(1, MTOK/GBM), blk, 0, stream>>>(
        sp_out, wf1B, nullptr, fpad, MTOK, CCH, 2*CCH,
        nullptr, nullptr, nullptr, ch_out, bn1_g, bn1_b, bn1_m, bn1_v);

    // ---- f2 = relu(bn2(conv3x3(f))) -> PADDED f2pad ----
    zb_k<<<(8*516*24+255)/256, blk, 0, stream>>>(f2pad);
    gemm_k<3,3,1,192,1,0><<<dim3(1, MTOK/GBM), blk, 0, stream>>>(
        fpad, wf2cB, nullptr, f2pad, MTOK, CCH, 9*CCH,
        nullptr, nullptr, nullptr, nullptr, bn2_g, bn2_b, bn2_m, bn2_v);

    // ---- gpre = conv3x3(f2) (96 ch) ----
    gemm_k<3,0,1,96,0,0><<<dim3(1, MTOK/GBM), blk, 0, stream>>>(
        f2pad, wsg1cB, nullptr, gpre, MTOK, 96, 9*CCH,
        nullptr, nullptr, nullptr, nullptr, nullptr, nullptr, nullptr, nullptr);

    // ---- xnew = x + f2*(1+g) -> d_out  (+ fused LN2 -> bf16 xnorm) ----
    fuse_k<<<MTOK/4, blk, 0, stream>>>(x, f2pad, gpre, w_sg2, b_sg2, out,
                                       xnorm, ln2_g, ln2_b);

    // ---- MLP (2 chunks; hidden over dead A0 region; A = pre-normed bf16) ----
    const int CHM = MTOK / 2;
    for (int c0 = 0; c0 < MTOK; c0 += CHM) {
        gemm_k<0,5,1,192,0,0><<<dim3(4, CHM/GBM), blk, 0, stream>>>(
            xnorm + (size_t)c0*CCH, wfc1B, b_fc1, hidden, CHM, 4*CCH, CCH,
            nullptr, nullptr, nullptr, nullptr,
            nullptr, nullptr, nullptr, nullptr);
        gemm_k<0,6,0,192,0,0><<<dim3(1, CHM/GBM), blk, 0, stream>>>(
            hidden, wfc2B, b_fc2, out + (size_t)c0*CCH, CHM, CCH, 4*CCH,
            nullptr, nullptr, nullptr, nullptr, out + (size_t)c0*CCH,
            nullptr, nullptr, nullptr);
    }
}